// Round 10
// baseline (2898.462 us; speedup 1.0000x reference)
//
#include <hip/hip_runtime.h>
#include <hip/hip_bf16.h>
#include <stdint.h>

// LevelReasoning on MI355X — round 10: row-split waves + 32x32x16 MFMA.
// sgemm: BM=128 BN=128, 4 waves each owning 32 ROWS x all 128 cols.
// A ds_reads: 4/wave/tile (vs 14). B per-wave direct from L2 (no LDS).
// MFMA 32x32x16 (2x FLOP/instr, 2382 TF ceiling), acc 4 x f32x16 = 64 AGPR,
// launch_bounds(256,3). Single barrier + vmcnt(0) per K-tile. 3-pass split
// everywhere except final (1-pass). Stats fused as in r8/r9.

using bf16 = __hip_bfloat16;
typedef __attribute__((ext_vector_type(8))) short short8;
typedef __attribute__((ext_vector_type(16))) float f32x16;

__device__ inline uint16_t f2b_bits(float f) {
  bf16 h = __float2bfloat16(f);
  return __builtin_bit_cast(uint16_t, h);
}
__device__ inline float b2f_bits(uint16_t u) { return __uint_as_float(((uint32_t)u) << 16); }
__device__ inline float bflo(uint32_t u) { return __uint_as_float((u & 0xffffu) << 16); }
__device__ inline float bfhi(uint32_t u) { return __uint_as_float(u & 0xffff0000u); }
__device__ inline void split2(float v, uint16_t& hi, uint16_t& lo) {
  hi = f2b_bits(v);
  lo = f2b_bits(v - b2f_bits(hi));
}
__device__ inline float h16(const uint4& u, int e) {
  uint32_t wrd = ((const uint32_t*)&u)[e >> 1];
  return (e & 1) ? bfhi(wrd) : bflo(wrd);
}

typedef const __attribute__((address_space(1))) void* gas_ptr;
typedef __attribute__((address_space(3))) void* las_ptr;
__device__ inline void gload16(const void* g, void* l) {
  __builtin_amdgcn_global_load_lds((gas_ptr)g, (las_ptr)l, 16, 0, 0);
}

// ---------------- fold weight to io-format: W' = g*W*diag(s), b' = g*(b + t@W.T) ----------------
__global__ __launch_bounds__(512) void fold_w_io(const float* __restrict__ Wsrc,
                                                 const float* __restrict__ bsrc,
                                                 const float* __restrict__ sv,
                                                 const float* __restrict__ tv,
                                                 const float* __restrict__ gamp,
                                                 char* __restrict__ Wio,
                                                 float* __restrict__ bout) {
  const int row = blockIdx.x, c = threadIdx.x;
  __shared__ float red[512];
  const float wv = Wsrc[(size_t)row * 512 + c];
  const float g = gamp ? gamp[0] : 1.0f;
  const float s = sv ? sv[c] : 1.0f;
  uint16_t hb, lb;
  split2(g * wv * s, hb, lb);
  char* p = Wio + (size_t)row * 2048 + (c >> 3) * 32 + (c & 7) * 2;
  *(uint16_t*)p = hb;
  *(uint16_t*)(p + 16) = lb;
  red[c] = tv ? wv * tv[c] : 0.0f;
  __syncthreads();
#pragma unroll
  for (int off = 256; off > 0; off >>= 1) {
    if (c < off) red[c] += red[c + off];
    __syncthreads();
  }
  if (c == 0) bout[row] = g * (bsrc[row] + red[0]);
}

// ---------------- 128x128-tile split GEMM, row-split waves, 32x32x16 MFMA ----------------
// AMODE 0: A io-format split bf16 (2KB rows). AMODE 1: A f32 (2KB rows), split in-reg.
// EPI 0: outf[row*N+col]=acc+bias. EPI 1: io out + stats partials. EPI 2: bf16, pitch 512.
// NPASS: 3 = hh+hl+lh, 1 = hi*hi.
template <int AMODE, int EPI, int NPASS>
__global__ __launch_bounds__(256, 3) void sgemm(const char* __restrict__ A,
                                                const char* __restrict__ Wio,
                                                const float* __restrict__ bias,
                                                float* __restrict__ outf,
                                                char* __restrict__ outb,
                                                float* __restrict__ part, int N) {
  constexpr int A_BYTES = 128 * 128;  // 16KB per buffer
  __shared__ __align__(16) char lds[2 * A_BYTES];
  __shared__ float smS[2][4][128];  // EPI==1 cross-wave stats
  const int tid = threadIdx.x, w = tid >> 6, l = tid & 63;

  // XCD-chunked bijective block swizzle (total blocks % 8 == 0 for all grids)
  const int nwgx = gridDim.x;
  const int raw = blockIdx.y * nwgx + blockIdx.x;
  const int cpx = (nwgx * gridDim.y) >> 3;
  const int work = (raw & 7) * cpx + (raw >> 3);
  const int bmidx = work / nwgx;
  const int bm = bmidx * 128;
  const int bn = (work % nwgx) * 128;

  // A staging: lane l covers row (i*8 + (l>>3)), inverse-swizzled 32B slot + 16B piece
  const int ssl = ((((l >> 1) & 3) ^ ((l >> 3) & 3)) << 5) | (((l & 1) ^ ((l >> 5) & 1)) << 4);
  const char* Asrc = A + (size_t)(bm + (l >> 3)) * 2048 + ssl;

  // fragment geometry: wave w owns rows [bm + w*32, +32), ALL 128 cols
  const int r = l & 31, hf = l >> 5;
  const int x03 = r & 3, b2 = ((r >> 2) & 1) << 4;
  const int abase = (w * 32 + r) * 128;
  const int aoff0 = abase + ((hf ^ x03) << 5);        // kh=0: logical slot = hf
  const int aoff1 = abase + (((2 + hf) ^ x03) << 5);  // kh=1: logical slot = 2+hf

  // B direct-from-L2: lane holds W-row (bn + nb*32 + r), k-octet hf
  const char* Bb = Wio + (size_t)(bn + r) * 2048 + hf * 32;

  f32x16 acc[4] = {};

  auto stage_a = [&](int buf, int t) {
    char* dst = lds + buf * A_BYTES;
    const char* src = Asrc + (size_t)t * 128;
#pragma unroll
    for (int k = 0; k < 4; ++k) {
      const int i = w * 4 + k;  // 16 chunks of 8 rows
      gload16(src + (size_t)i * 16384, dst + i * 1024);
    }
  };

  stage_a(0, 0);
  int cur = 0;
  for (int t = 0; t < 16; ++t) {
    asm volatile("s_waitcnt vmcnt(0)" ::: "memory");  // A tile t landed
    __builtin_amdgcn_s_barrier();
    asm volatile("" ::: "memory");
    const char* bp = lds + cur * A_BYTES;

    // B kh=0 fragments from L2
    short8 bh0[4], bl0[4], bh1[4], bl1[4];
#pragma unroll
    for (int nb = 0; nb < 4; ++nb) {
      const char* p = Bb + (size_t)nb * 65536 + t * 128;
      bh0[nb] = *(const short8*)p;
      if constexpr (NPASS == 3) bl0[nb] = *(const short8*)(p + 16);
    }
    if (t < 15) stage_a(cur ^ 1, t + 1);

    // A fragments (both k-halves)
    short8 ah[2], al[2];
    if constexpr (AMODE == 0) {
      ah[0] = *(const short8*)(bp + aoff0 + b2);
      al[0] = *(const short8*)(bp + aoff0 + (b2 ^ 16));
      ah[1] = *(const short8*)(bp + aoff1 + b2);
      al[1] = *(const short8*)(bp + aoff1 + (b2 ^ 16));
    } else {
#pragma unroll
      for (int kh = 0; kh < 2; ++kh) {
        const int ao = kh ? aoff1 : aoff0;
        float4 f0 = *(const float4*)(bp + ao + b2);          // logical piece0: e0..3
        float4 f1 = *(const float4*)(bp + ao + (b2 ^ 16));   // logical piece1: e4..7
        const float fv[8] = {f0.x, f0.y, f0.z, f0.w, f1.x, f1.y, f1.z, f1.w};
#pragma unroll
        for (int e = 0; e < 8; ++e) {
          uint16_t hb, lb;
          split2(fv[e], hb, lb);
          ah[kh][e] = (short)hb;
          al[kh][e] = (short)lb;
        }
      }
    }

    // B kh=1 fragments
#pragma unroll
    for (int nb = 0; nb < 4; ++nb) {
      const char* p = Bb + (size_t)nb * 65536 + t * 128 + 64;
      bh1[nb] = *(const short8*)p;
      if constexpr (NPASS == 3) bl1[nb] = *(const short8*)(p + 16);
    }

    __builtin_amdgcn_s_setprio(1);
    // kh=0: pass-major hh, hl, lh
#pragma unroll
    for (int nb = 0; nb < 4; ++nb)
      acc[nb] = __builtin_amdgcn_mfma_f32_32x32x16_bf16(ah[0], bh0[nb], acc[nb], 0, 0, 0);
    if constexpr (NPASS == 3) {
#pragma unroll
      for (int nb = 0; nb < 4; ++nb)
        acc[nb] = __builtin_amdgcn_mfma_f32_32x32x16_bf16(ah[0], bl0[nb], acc[nb], 0, 0, 0);
#pragma unroll
      for (int nb = 0; nb < 4; ++nb)
        acc[nb] = __builtin_amdgcn_mfma_f32_32x32x16_bf16(al[0], bh0[nb], acc[nb], 0, 0, 0);
    }
    // kh=1
#pragma unroll
    for (int nb = 0; nb < 4; ++nb)
      acc[nb] = __builtin_amdgcn_mfma_f32_32x32x16_bf16(ah[1], bh1[nb], acc[nb], 0, 0, 0);
    if constexpr (NPASS == 3) {
#pragma unroll
      for (int nb = 0; nb < 4; ++nb)
        acc[nb] = __builtin_amdgcn_mfma_f32_32x32x16_bf16(ah[1], bl1[nb], acc[nb], 0, 0, 0);
#pragma unroll
      for (int nb = 0; nb < 4; ++nb)
        acc[nb] = __builtin_amdgcn_mfma_f32_32x32x16_bf16(al[1], bh1[nb], acc[nb], 0, 0, 0);
    }
    __builtin_amdgcn_s_setprio(0);
    cur ^= 1;
  }

  // epilogue: C/D 32x32 layout col=lane&31, row=(reg&3)+8*(reg>>2)+4*(lane>>5)
  float sni[4] = {}, qni[4] = {};
#pragma unroll
  for (int nb = 0; nb < 4; ++nb) {
    const int col = bn + nb * 32 + r;
    const float bc = bias[col];
#pragma unroll
    for (int reg = 0; reg < 16; ++reg) {
      const int row = bm + w * 32 + (reg & 3) + 8 * (reg >> 2) + 4 * hf;
      const float vv = acc[nb][reg] + bc;
      if constexpr (EPI == 0) {
        outf[(size_t)row * N + col] = vv;
      } else if constexpr (EPI == 1) {
        uint16_t hb, lb;
        split2(vv, hb, lb);
        char* p = outb + (size_t)row * 2048 + (col >> 3) * 32 + (col & 7) * 2;
        *(uint16_t*)p = hb;
        *(uint16_t*)(p + 16) = lb;
        sni[nb] += vv;
        qni[nb] += vv * vv;
      } else {
        ((bf16*)outb)[(size_t)row * 512 + col] = __float2bfloat16(vv);
      }
    }
  }

  if constexpr (EPI == 1) {
#pragma unroll
    for (int nb = 0; nb < 4; ++nb) {
      float s = sni[nb] + __shfl_xor(sni[nb], 32);
      float q = qni[nb] + __shfl_xor(qni[nb], 32);
      if (hf == 0) {
        smS[0][w][nb * 32 + r] = s;
        smS[1][w][nb * 32 + r] = q;
      }
    }
    __syncthreads();
    if (tid < 128) {
      part[(size_t)bmidx * 1024 + bn + tid] =
          smS[0][0][tid] + smS[0][1][tid] + smS[0][2][tid] + smS[0][3][tid];
      part[(size_t)bmidx * 1024 + 512 + bn + tid] =
          smS[1][0][tid] + smS[1][1][tid] + smS[1][2][tid] + smS[1][3][tid];
    }
  }
}

// ---------------- stats reduce: part[n][1024] -> sv, tv ----------------
__global__ __launch_bounds__(64) void reduce_stats(const float* __restrict__ part, int n,
                                                   const float* __restrict__ g,
                                                   const float* __restrict__ bb,
                                                   float* __restrict__ sv,
                                                   float* __restrict__ tv) {
  const int c = blockIdx.x, k = threadIdx.x;
  float sum = 0.f, sq = 0.f;
  for (int i = k; i < n; i += 64) {
    const float* p = part + (size_t)i * 1024;
    sum += p[c];
    sq += p[512 + c];
  }
#pragma unroll
  for (int o = 32; o; o >>= 1) {
    sum += __shfl_xor(sum, o);
    sq += __shfl_xor(sq, o);
  }
  if (k == 0) {
    const float mean = sum * (1.0f / 114688.0f);
    const float var = sq * (1.0f / 114688.0f) - mean * mean;
    const float sc = g[c] * rsqrtf(var + 1e-5f);
    sv[c] = sc;
    tv[c] = bb[c] - mean * sc;
  }
}

// ---------------- fused attention + residual + relu (+ stats), in place on h ----------------
template <bool STATS>
__global__ __launch_bounds__(256) void attn_relu(const float* __restrict__ qkf,
                                                 const bf16* __restrict__ V,
                                                 char* __restrict__ Hio,
                                                 const float* __restrict__ sv,
                                                 const float* __restrict__ tv,
                                                 float* __restrict__ part) {
  __shared__ float smS[4][512], smQ[4][512];
  const int w = threadIdx.x >> 6, l = threadIdx.x & 63;
  const int b = blockIdx.x * 4 + w;
  const size_t base = (size_t)b * 7;

  float qv[7], kv[7];
#pragma unroll
  for (int i = 0; i < 7; ++i) {
    qv[i] = qkf[(base + i) * 128 + l];
    kv[i] = qkf[(base + i) * 128 + 64 + l];
  }
  float att[7][7];
#pragma unroll
  for (int i = 0; i < 7; ++i)
#pragma unroll
    for (int j = 0; j < 7; ++j) {
      float p = qv[i] * kv[j];
#pragma unroll
      for (int o = 32; o; o >>= 1) p += __shfl_xor(p, o);
      att[i][j] = p;
    }
#pragma unroll
  for (int i = 0; i < 7; ++i) {
    float m = att[i][0];
#pragma unroll
    for (int j = 1; j < 7; ++j) m = fmaxf(m, att[i][j]);
    float sum = 0.f;
#pragma unroll
    for (int j = 0; j < 7; ++j) {
      att[i][j] = expf(att[i][j] - m);
      sum += att[i][j];
    }
    const float inv = 1.0f / sum;
#pragma unroll
    for (int j = 0; j < 7; ++j) att[i][j] *= inv;
  }

  const float4 s0 = *(const float4*)&sv[l * 8], s1 = *(const float4*)&sv[l * 8 + 4];
  const float4 t0 = *(const float4*)&tv[l * 8], t1 = *(const float4*)&tv[l * 8 + 4];
  const float sarr[8] = {s0.x, s0.y, s0.z, s0.w, s1.x, s1.y, s1.z, s1.w};
  const float tarr[8] = {t0.x, t0.y, t0.z, t0.w, t1.x, t1.y, t1.z, t1.w};

  uint4 vpk[7];
#pragma unroll
  for (int j = 0; j < 7; ++j)
    vpk[j] = *(const uint4*)((const char*)V + (base + j) * 1024 + l * 16);

  float s8[8] = {}, q8[8] = {};
#pragma unroll
  for (int i = 0; i < 7; ++i) {
    char* hp = Hio + (base + i) * 2048 + l * 32;
    uint4 hh = *(const uint4*)hp;
    uint4 hl = *(const uint4*)(hp + 16);
    float o[8] = {};
#pragma unroll
    for (int j = 0; j < 7; ++j) {
      const float a = att[i][j];
#pragma unroll
      for (int e = 0; e < 8; ++e) o[e] += a * h16(vpk[j], e);
    }
    uint16_t oh[8], ol[8];
#pragma unroll
    for (int e = 0; e < 8; ++e) {
      const float hval = h16(hh, e) + h16(hl, e);
      const float rr = fmaxf(o[e] + hval * sarr[e] + tarr[e], 0.f);
      if constexpr (STATS) { s8[e] += rr; q8[e] += rr * rr; }
      split2(rr, oh[e], ol[e]);
    }
    uint4 ph, pl;
#pragma unroll
    for (int k2 = 0; k2 < 4; ++k2) {
      ((uint32_t*)&ph)[k2] = (uint32_t)oh[2 * k2] | ((uint32_t)oh[2 * k2 + 1] << 16);
      ((uint32_t*)&pl)[k2] = (uint32_t)ol[2 * k2] | ((uint32_t)ol[2 * k2 + 1] << 16);
    }
    *(uint4*)hp = ph;
    *(uint4*)(hp + 16) = pl;
  }

  if constexpr (STATS) {
#pragma unroll
    for (int e = 0; e < 8; ++e) {
      smS[w][l * 8 + e] = s8[e];
      smQ[w][l * 8 + e] = q8[e];
    }
    __syncthreads();
    const int c = threadIdx.x * 2;
#pragma unroll
    for (int cc = 0; cc < 2; ++cc) {
      const int c2 = c + cc;
      part[(size_t)blockIdx.x * 1024 + c2] =
          smS[0][c2] + smS[1][c2] + smS[2][c2] + smS[3][c2];
      part[(size_t)blockIdx.x * 1024 + 512 + c2] =
          smQ[0][c2] + smQ[1][c2] + smQ[2][c2] + smQ[3][c2];
    }
  }
}

extern "C" void kernel_launch(void* const* d_in, const int* in_sizes, int n_in,
                              void* d_out, int out_size, void* d_ws, size_t ws_size,
                              hipStream_t stream) {
  const float* x  = (const float*)d_in[0];
  const float* Wt = (const float*)d_in[1];
  const float* bt = (const float*)d_in[2];
  const float *bng[3], *bnb[3], *Wq[3], *bq[3], *Wk[3], *bk[3], *Wv[3], *bv[3], *gam[3];
  for (int i = 0; i < 3; ++i) {
    int o = 3 + 9 * i;
    bng[i] = (const float*)d_in[o + 0];
    bnb[i] = (const float*)d_in[o + 1];
    Wq[i]  = (const float*)d_in[o + 2];
    bq[i]  = (const float*)d_in[o + 3];
    Wk[i]  = (const float*)d_in[o + 4];
    bk[i]  = (const float*)d_in[o + 5];
    Wv[i]  = (const float*)d_in[o + 6];
    bv[i]  = (const float*)d_in[o + 7];
    gam[i] = (const float*)d_in[o + 8];
  }
  const float* Wb = (const float*)d_in[30];
  const float* bb = (const float*)d_in[31];

  char* ws = (char*)d_ws;
  char*  Hio   = ws;                               // 235,929,600 (114688 x 2048B)
  char*  V     = ws + 235929600;                   // 117,440,512 (plain bf16)
  float* part  = (float*)(ws + 353370112);         // 16,777,216 (4096 x 1024 f32)
  float* sv    = (float*)(ws + 370147328);         // 2,048
  float* tv    = (float*)(ws + 370149376);         // 2,048
  char*  WqkIo = ws + 370151424;                   // 262,144
  float* bqkf  = (float*)(ws + 370413568);         // 2,048
  char*  WvIo  = ws + 370415616;                   // 1,048,576
  float* bvf   = (float*)(ws + 371464192);         // 2,048
  char*  WtIo  = ws + 371466240;                   // 1,048,576
  float* btf   = (float*)(ws + 372514816);         // 2,048
  char*  WbIo  = ws + 372516864;                   // 524,288 (256 rows io)
  float* bbf   = (float*)(ws + 373041152);         // 1,024
  float* qkf   = (float*)d_out;                    // 58.7 MB <= out bytes (117MB)

  // weight prep
  fold_w_io<<<512, 512, 0, stream>>>(Wt, bt, nullptr, nullptr, nullptr, WtIo, btf);
  fold_w_io<<<256, 512, 0, stream>>>(Wb, bb, nullptr, nullptr, nullptr, WbIo, bbf);

  // h0 = x @ Wt.T + bt  (split 3-pass; io out + stats partials)
  sgemm<1, 1, 3><<<dim3(4, 896), 256, 0, stream>>>((const char*)x, WtIo, btf,
                                                   nullptr, Hio, part, 512);

  for (int i = 0; i < 3; ++i) {
    reduce_stats<<<512, 64, 0, stream>>>(part, i == 0 ? 896 : 4096,
                                         bng[i], bnb[i], sv, tv);
    fold_w_io<<<64, 512, 0, stream>>>(Wq[i], bq[i], sv, tv, nullptr, WqkIo, bqkf);
    fold_w_io<<<64, 512, 0, stream>>>(Wk[i], bk[i], sv, tv, nullptr,
                                      WqkIo + (size_t)64 * 2048, bqkf + 64);
    fold_w_io<<<512, 512, 0, stream>>>(Wv[i], bv[i], sv, tv, gam[i], WvIo, bvf);
    // q|k = h @ Wqk'.T + b'  (split 3-pass; f32 out on d_out)
    sgemm<0, 0, 3><<<dim3(1, 896), 256, 0, stream>>>(Hio, WqkIo, bqkf, qkf,
                                                     nullptr, nullptr, 128);
    // v' = h @ (gam*Wv*s)'.T + b''  (split 3-pass; plain bf16 out)
    sgemm<0, 2, 3><<<dim3(4, 896), 256, 0, stream>>>(Hio, WvIo, bvf, nullptr,
                                                     V, nullptr, 512);
    // h = relu(att@v' + h*s + t) in place (+ stats partials for next layer)
    if (i < 2)
      attn_relu<true><<<4096, 256, 0, stream>>>(qkf, (const bf16*)V, Hio, sv, tv, part);
    else
      attn_relu<false><<<4096, 256, 0, stream>>>(qkf, (const bf16*)V, Hio, sv, tv, nullptr);
  }

  // out = h3_hi @ Wb.T + bb  (1-pass; f32 out)
  sgemm<0, 0, 1><<<dim3(2, 896), 256, 0, stream>>>(Hio, WbIo, bbf, (float*)d_out,
                                                   nullptr, nullptr, 256);
}

// Round 11
// 1581.115 us; speedup vs baseline: 1.8332x; 1.8332x over previous
//
#include <hip/hip_runtime.h>
#include <hip/hip_bf16.h>
#include <stdint.h>

// LevelReasoning on MI355X — round 11: r8 structure + true counted-vmcnt pipeline.
// sgemm: BM=256, BN=128, 8 waves (2x4, wave=128x32), TRIPLE-buffered A+B (144KB),
// stage(t+2) after top barrier (WAR-safe: writes buffer consumed at t-1),
// steady vmcnt(6) (2-tile latency cover), ONE barrier per K-tile.
// Uniform 6 loads/wave/tile -> exact per-wave vmcnt count. r8 swizzle (0 conflicts).
// 3-pass split everywhere except final (1-pass). Stats fused. Numerics == r8.

using bf16 = __hip_bfloat16;
typedef __attribute__((ext_vector_type(8))) short short8;
typedef __attribute__((ext_vector_type(4))) float f32x4;

__device__ inline uint16_t f2b_bits(float f) {
  bf16 h = __float2bfloat16(f);
  return __builtin_bit_cast(uint16_t, h);
}
__device__ inline float b2f_bits(uint16_t u) { return __uint_as_float(((uint32_t)u) << 16); }
__device__ inline float bflo(uint32_t u) { return __uint_as_float((u & 0xffffu) << 16); }
__device__ inline float bfhi(uint32_t u) { return __uint_as_float(u & 0xffff0000u); }
__device__ inline void split2(float v, uint16_t& hi, uint16_t& lo) {
  hi = f2b_bits(v);
  lo = f2b_bits(v - b2f_bits(hi));
}
__device__ inline float h16(const uint4& u, int e) {
  uint32_t wrd = ((const uint32_t*)&u)[e >> 1];
  return (e & 1) ? bfhi(wrd) : bflo(wrd);
}

typedef const __attribute__((address_space(1))) void* gas_ptr;
typedef __attribute__((address_space(3))) void* las_ptr;
__device__ inline void gload16(const void* g, void* l) {
  __builtin_amdgcn_global_load_lds((gas_ptr)g, (las_ptr)l, 16, 0, 0);
}

// ---------------- fold weight to io-format: W' = g*W*diag(s), b' = g*(b + t@W.T) ----------------
__global__ __launch_bounds__(512) void fold_w_io(const float* __restrict__ Wsrc,
                                                 const float* __restrict__ bsrc,
                                                 const float* __restrict__ sv,
                                                 const float* __restrict__ tv,
                                                 const float* __restrict__ gamp,
                                                 char* __restrict__ Wio,
                                                 float* __restrict__ bout) {
  const int row = blockIdx.x, c = threadIdx.x;
  __shared__ float red[512];
  const float wv = Wsrc[(size_t)row * 512 + c];
  const float g = gamp ? gamp[0] : 1.0f;
  const float s = sv ? sv[c] : 1.0f;
  uint16_t hb, lb;
  split2(g * wv * s, hb, lb);
  char* p = Wio + (size_t)row * 2048 + (c >> 3) * 32 + (c & 7) * 2;
  *(uint16_t*)p = hb;
  *(uint16_t*)(p + 16) = lb;
  red[c] = tv ? wv * tv[c] : 0.0f;
  __syncthreads();
#pragma unroll
  for (int off = 256; off > 0; off >>= 1) {
    if (c < off) red[c] += red[c + off];
    __syncthreads();
  }
  if (c == 0) bout[row] = g * (bsrc[row] + red[0]);
}

// ---------------- 256x128-tile split GEMM, 8 waves, 3-buf counted-vmcnt ----------------
// AMODE 0: A io-format split bf16 (2KB rows). AMODE 1: A f32 (2KB rows), split in-reg.
// EPI 0: outf[row*N+col]=acc+bias. EPI 1: io out + stats partials. EPI 2: bf16, pitch 512.
// NPASS: 3 = hh+hl+lh, 1 = hi*hi.
template <int AMODE, int EPI, int NPASS>
__global__ __launch_bounds__(512, 1) void sgemm(const char* __restrict__ A,
                                                const char* __restrict__ Wio,
                                                const float* __restrict__ bias,
                                                float* __restrict__ outf,
                                                char* __restrict__ outb,
                                                float* __restrict__ part, int N) {
  constexpr int A_BYTES = 256 * 128;            // 32768
  constexpr int PER_BUF = A_BYTES + 128 * 128;  // 49152 (A | B)
  __shared__ __align__(16) char lds[3 * PER_BUF];
  __shared__ float sred[2][2][128];             // [s|q][wr][col_local] (EPI==1)
  const int tid = threadIdx.x, w = tid >> 6, l = tid & 63;

  // XCD-chunked bijective block swizzle (total blocks % 8 == 0 for all grids)
  const int nwgx = gridDim.x;
  const int raw = blockIdx.y * nwgx + blockIdx.x;
  const int cpx = (nwgx * gridDim.y) >> 3;
  const int work = (raw & 7) * cpx + (raw >> 3);
  const int bmidx = work / nwgx;
  const int bm = bmidx * 256;
  const int bn = (work % nwgx) * 128;

  // staging lane geometry: lane l covers row (i*8 + (l>>3)), swizzled 32B slot + 16B piece
  const int ssl = ((((l >> 1) & 3) ^ ((l >> 3) & 3)) << 5) | (((l & 1) ^ ((l >> 5) & 1)) << 4);
  const char* Asrc = A + (size_t)(bm + (l >> 3)) * 2048 + ssl;
  const char* Bsrc = Wio + (size_t)(bn + (l >> 3)) * 2048 + ssl;

  // fragment geometry: 2x4 wave grid; wave tile 128 rows x 32 cols
  const int lrow = l & 15, lk = l >> 4;
  const int wr = w >> 2, wc = w & 3;
  const int sw32 = (lk ^ (lrow & 3)) * 32;
  const int hi16 = ((lrow >> 2) & 1) * 16;      // piece-swizzle un-XOR (logical piece 0)
  const int afr = (wr * 128 + lrow) * 128 + sw32;            // + mi*2048
  const int bfr = A_BYTES + (wc * 32 + lrow) * 128 + sw32;   // + ni*2048

  f32x4 acc[8][2] = {};

  auto stage_a = [&](int buf, int t) {
    char* dst = lds + buf * PER_BUF;
    const char* src = Asrc + (size_t)t * 128;
#pragma unroll
    for (int k = 0; k < 4; ++k) {
      const int i = w + k * 8;  // 32 chunks of 8 rows, 4 per wave
      gload16(src + (size_t)i * 16384, dst + i * 1024);
    }
  };
  auto stage_b = [&](int buf, int t) {
    char* dst = lds + buf * PER_BUF + A_BYTES;
    const char* src = Bsrc + (size_t)t * 128;
#pragma unroll
    for (int k = 0; k < 2; ++k) {
      const int i = w + k * 8;  // 16 chunks, 2 per wave
      gload16(src + (size_t)i * 16384, dst + i * 1024);
    }
  };

#define LOADA(BASE)                                                              \
  {                                                                              \
    _Pragma("unroll") for (int u = 0; u < 4; ++u) {                              \
      const int mi = (BASE) + u;                                                 \
      if constexpr (AMODE == 0) {                                                \
        ah[u] = *(const short8*)(bp + afr + mi * 2048 + hi16);                   \
        if constexpr (NPASS == 3)                                                \
          al[u] = *(const short8*)(bp + afr + mi * 2048 + (hi16 ^ 16));          \
      } else {                                                                   \
        float4 f0 = *(const float4*)(bp + afr + mi * 2048 + hi16);               \
        float4 f1 = *(const float4*)(bp + afr + mi * 2048 + (hi16 ^ 16));        \
        const float fv[8] = {f0.x, f0.y, f0.z, f0.w, f1.x, f1.y, f1.z, f1.w};    \
        _Pragma("unroll") for (int e = 0; e < 8; ++e) {                          \
          uint16_t hb, lb;                                                       \
          split2(fv[e], hb, lb);                                                 \
          ah[u][e] = (short)hb;                                                  \
          al[u][e] = (short)lb;                                                  \
        }                                                                        \
      }                                                                          \
    }                                                                            \
  }

#define MFMAC(BASE)                                                              \
  {                                                                              \
    __builtin_amdgcn_s_setprio(1);                                               \
    _Pragma("unroll") for (int u = 0; u < 4; ++u)                                \
      _Pragma("unroll") for (int ni = 0; ni < 2; ++ni)                           \
        acc[(BASE) + u][ni] = __builtin_amdgcn_mfma_f32_16x16x32_bf16(           \
            ah[u], bh[ni], acc[(BASE) + u][ni], 0, 0, 0);                        \
    if constexpr (NPASS == 3) {                                                  \
      _Pragma("unroll") for (int u = 0; u < 4; ++u)                              \
        _Pragma("unroll") for (int ni = 0; ni < 2; ++ni)                         \
          acc[(BASE) + u][ni] = __builtin_amdgcn_mfma_f32_16x16x32_bf16(         \
              ah[u], bl[ni], acc[(BASE) + u][ni], 0, 0, 0);                      \
      _Pragma("unroll") for (int u = 0; u < 4; ++u)                              \
        _Pragma("unroll") for (int ni = 0; ni < 2; ++ni)                         \
          acc[(BASE) + u][ni] = __builtin_amdgcn_mfma_f32_16x16x32_bf16(         \
              al[u], bh[ni], acc[(BASE) + u][ni], 0, 0, 0);                      \
    }                                                                            \
    __builtin_amdgcn_s_setprio(0);                                               \
  }

  // prologue: tiles 0 and 1 in flight (queue: A0 B0 A1 B1 = 12 loads/wave)
  stage_a(0, 0);
  stage_b(0, 0);
  stage_a(1, 1);
  stage_b(1, 1);

  for (int t = 0; t < 16; ++t) {
    // counted wait: tile t's 6 loads are the oldest; keep t+1 (and t+2 after issue) in flight
    if (t < 15) {
      asm volatile("s_waitcnt vmcnt(6)" ::: "memory");
    } else {
      asm volatile("s_waitcnt vmcnt(0)" ::: "memory");
    }
    __builtin_amdgcn_s_barrier();
    asm volatile("" ::: "memory");

    const char* bp = lds + (t % 3) * PER_BUF;
    if (t <= 13) {  // stage tile t+2 into buffer (t+2)%3 == (t-1)%3 (consumed last iter)
      stage_a((t + 2) % 3, t + 2);
      stage_b((t + 2) % 3, t + 2);
    }

    short8 bh[2], bl[2];
#pragma unroll
    for (int ni = 0; ni < 2; ++ni) {
      bh[ni] = *(const short8*)(bp + bfr + ni * 2048 + hi16);
      if constexpr (NPASS == 3)
        bl[ni] = *(const short8*)(bp + bfr + ni * 2048 + (hi16 ^ 16));
    }
    short8 ah[4], al[4];
    LOADA(0)
    MFMAC(0)
    LOADA(4)
    MFMAC(4)
  }
#undef LOADA
#undef MFMAC

  float sni[2] = {}, qni[2] = {};
#pragma unroll
  for (int mi = 0; mi < 8; ++mi) {
    const int row = bm + wr * 128 + mi * 16 + lk * 4;
#pragma unroll
    for (int ni = 0; ni < 2; ++ni) {
      const int col = bn + wc * 32 + ni * 16 + lrow;
      const float bc = bias[col];
#pragma unroll
      for (int j = 0; j < 4; ++j) {
        const float vv = acc[mi][ni][j] + bc;
        if constexpr (EPI == 0) {
          outf[(size_t)(row + j) * N + col] = vv;
        } else if constexpr (EPI == 1) {
          uint16_t hb, lb;
          split2(vv, hb, lb);
          char* p = outb + (size_t)(row + j) * 2048 + (col >> 3) * 32 + (col & 7) * 2;
          *(uint16_t*)p = hb;
          *(uint16_t*)(p + 16) = lb;
          sni[ni] += vv;
          qni[ni] += vv * vv;
        } else {
          ((bf16*)outb)[(size_t)(row + j) * 512 + col] = __float2bfloat16(vv);
        }
      }
    }
  }

  if constexpr (EPI == 1) {
    // reduce over lk lanes within wave, then across the two wr waves via LDS
#pragma unroll
    for (int ni = 0; ni < 2; ++ni) {
      float s = sni[ni], q = qni[ni];
      s += __shfl_xor(s, 16); q += __shfl_xor(q, 16);
      s += __shfl_xor(s, 32); q += __shfl_xor(q, 32);
      if (lk == 0) {
        sred[0][wr][wc * 32 + ni * 16 + lrow] = s;
        sred[1][wr][wc * 32 + ni * 16 + lrow] = q;
      }
    }
    __syncthreads();
    if (tid < 128) {
      part[(size_t)bmidx * 1024 + bn + tid] = sred[0][0][tid] + sred[0][1][tid];
      part[(size_t)bmidx * 1024 + 512 + bn + tid] = sred[1][0][tid] + sred[1][1][tid];
    }
  }
}

// ---------------- stats reduce: part[n][1024] -> sv, tv ----------------
__global__ __launch_bounds__(64) void reduce_stats(const float* __restrict__ part, int n,
                                                   const float* __restrict__ g,
                                                   const float* __restrict__ bb,
                                                   float* __restrict__ sv,
                                                   float* __restrict__ tv) {
  const int c = blockIdx.x, k = threadIdx.x;
  float sum = 0.f, sq = 0.f;
  for (int i = k; i < n; i += 64) {
    const float* p = part + (size_t)i * 1024;
    sum += p[c];
    sq += p[512 + c];
  }
#pragma unroll
  for (int o = 32; o; o >>= 1) {
    sum += __shfl_xor(sum, o);
    sq += __shfl_xor(sq, o);
  }
  if (k == 0) {
    const float mean = sum * (1.0f / 114688.0f);
    const float var = sq * (1.0f / 114688.0f) - mean * mean;
    const float sc = g[c] * rsqrtf(var + 1e-5f);
    sv[c] = sc;
    tv[c] = bb[c] - mean * sc;
  }
}

// ---------------- fused attention + residual + relu (+ stats), in place on h ----------------
template <bool STATS>
__global__ __launch_bounds__(256) void attn_relu(const float* __restrict__ qkf,
                                                 const bf16* __restrict__ V,
                                                 char* __restrict__ Hio,
                                                 const float* __restrict__ sv,
                                                 const float* __restrict__ tv,
                                                 float* __restrict__ part) {
  __shared__ float smS[4][512], smQ[4][512];
  const int w = threadIdx.x >> 6, l = threadIdx.x & 63;
  const int b = blockIdx.x * 4 + w;
  const size_t base = (size_t)b * 7;

  float qv[7], kv[7];
#pragma unroll
  for (int i = 0; i < 7; ++i) {
    qv[i] = qkf[(base + i) * 128 + l];
    kv[i] = qkf[(base + i) * 128 + 64 + l];
  }
  float att[7][7];
#pragma unroll
  for (int i = 0; i < 7; ++i)
#pragma unroll
    for (int j = 0; j < 7; ++j) {
      float p = qv[i] * kv[j];
#pragma unroll
      for (int o = 32; o; o >>= 1) p += __shfl_xor(p, o);
      att[i][j] = p;
    }
#pragma unroll
  for (int i = 0; i < 7; ++i) {
    float m = att[i][0];
#pragma unroll
    for (int j = 1; j < 7; ++j) m = fmaxf(m, att[i][j]);
    float sum = 0.f;
#pragma unroll
    for (int j = 0; j < 7; ++j) {
      att[i][j] = expf(att[i][j] - m);
      sum += att[i][j];
    }
    const float inv = 1.0f / sum;
#pragma unroll
    for (int j = 0; j < 7; ++j) att[i][j] *= inv;
  }

  const float4 s0 = *(const float4*)&sv[l * 8], s1 = *(const float4*)&sv[l * 8 + 4];
  const float4 t0 = *(const float4*)&tv[l * 8], t1 = *(const float4*)&tv[l * 8 + 4];
  const float sarr[8] = {s0.x, s0.y, s0.z, s0.w, s1.x, s1.y, s1.z, s1.w};
  const float tarr[8] = {t0.x, t0.y, t0.z, t0.w, t1.x, t1.y, t1.z, t1.w};

  uint4 vpk[7];
#pragma unroll
  for (int j = 0; j < 7; ++j)
    vpk[j] = *(const uint4*)((const char*)V + (base + j) * 1024 + l * 16);

  float s8[8] = {}, q8[8] = {};
#pragma unroll
  for (int i = 0; i < 7; ++i) {
    char* hp = Hio + (base + i) * 2048 + l * 32;
    uint4 hh = *(const uint4*)hp;
    uint4 hl = *(const uint4*)(hp + 16);
    float o[8] = {};
#pragma unroll
    for (int j = 0; j < 7; ++j) {
      const float a = att[i][j];
#pragma unroll
      for (int e = 0; e < 8; ++e) o[e] += a * h16(vpk[j], e);
    }
    uint16_t oh[8], ol[8];
#pragma unroll
    for (int e = 0; e < 8; ++e) {
      const float hval = h16(hh, e) + h16(hl, e);
      const float rr = fmaxf(o[e] + hval * sarr[e] + tarr[e], 0.f);
      if constexpr (STATS) { s8[e] += rr; q8[e] += rr * rr; }
      split2(rr, oh[e], ol[e]);
    }
    uint4 ph, pl;
#pragma unroll
    for (int k2 = 0; k2 < 4; ++k2) {
      ((uint32_t*)&ph)[k2] = (uint32_t)oh[2 * k2] | ((uint32_t)oh[2 * k2 + 1] << 16);
      ((uint32_t*)&pl)[k2] = (uint32_t)ol[2 * k2] | ((uint32_t)ol[2 * k2 + 1] << 16);
    }
    *(uint4*)hp = ph;
    *(uint4*)(hp + 16) = pl;
  }

  if constexpr (STATS) {
#pragma unroll
    for (int e = 0; e < 8; ++e) {
      smS[w][l * 8 + e] = s8[e];
      smQ[w][l * 8 + e] = q8[e];
    }
    __syncthreads();
    const int c = threadIdx.x * 2;
#pragma unroll
    for (int cc = 0; cc < 2; ++cc) {
      const int c2 = c + cc;
      part[(size_t)blockIdx.x * 1024 + c2] =
          smS[0][c2] + smS[1][c2] + smS[2][c2] + smS[3][c2];
      part[(size_t)blockIdx.x * 1024 + 512 + c2] =
          smQ[0][c2] + smQ[1][c2] + smQ[2][c2] + smQ[3][c2];
    }
  }
}

extern "C" void kernel_launch(void* const* d_in, const int* in_sizes, int n_in,
                              void* d_out, int out_size, void* d_ws, size_t ws_size,
                              hipStream_t stream) {
  const float* x  = (const float*)d_in[0];
  const float* Wt = (const float*)d_in[1];
  const float* bt = (const float*)d_in[2];
  const float *bng[3], *bnb[3], *Wq[3], *bq[3], *Wk[3], *bk[3], *Wv[3], *bv[3], *gam[3];
  for (int i = 0; i < 3; ++i) {
    int o = 3 + 9 * i;
    bng[i] = (const float*)d_in[o + 0];
    bnb[i] = (const float*)d_in[o + 1];
    Wq[i]  = (const float*)d_in[o + 2];
    bq[i]  = (const float*)d_in[o + 3];
    Wk[i]  = (const float*)d_in[o + 4];
    bk[i]  = (const float*)d_in[o + 5];
    Wv[i]  = (const float*)d_in[o + 6];
    bv[i]  = (const float*)d_in[o + 7];
    gam[i] = (const float*)d_in[o + 8];
  }
  const float* Wb = (const float*)d_in[30];
  const float* bb = (const float*)d_in[31];

  char* ws = (char*)d_ws;
  char*  Hio   = ws;                               // 235,929,600 (114688 x 2048B)
  char*  V     = ws + 235929600;                   // 117,440,512 (plain bf16)
  float* part  = (float*)(ws + 353370112);         // 16,777,216 (4096 x 1024 f32)
  float* sv    = (float*)(ws + 370147328);         // 2,048
  float* tv    = (float*)(ws + 370149376);         // 2,048
  char*  WqkIo = ws + 370151424;                   // 262,144
  float* bqkf  = (float*)(ws + 370413568);         // 2,048
  char*  WvIo  = ws + 370415616;                   // 1,048,576
  float* bvf   = (float*)(ws + 371464192);         // 2,048
  char*  WtIo  = ws + 371466240;                   // 1,048,576
  float* btf   = (float*)(ws + 372514816);         // 2,048
  char*  WbIo  = ws + 372516864;                   // 524,288 (256 rows io)
  float* bbf   = (float*)(ws + 373041152);         // 1,024
  float* qkf   = (float*)d_out;                    // 58.7 MB <= out bytes (117MB)

  // weight prep
  fold_w_io<<<512, 512, 0, stream>>>(Wt, bt, nullptr, nullptr, nullptr, WtIo, btf);
  fold_w_io<<<256, 512, 0, stream>>>(Wb, bb, nullptr, nullptr, nullptr, WbIo, bbf);

  // h0 = x @ Wt.T + bt  (split 3-pass; io out + stats partials)
  sgemm<1, 1, 3><<<dim3(4, 448), 512, 0, stream>>>((const char*)x, WtIo, btf,
                                                   nullptr, Hio, part, 512);

  for (int i = 0; i < 3; ++i) {
    reduce_stats<<<512, 64, 0, stream>>>(part, i == 0 ? 448 : 4096,
                                         bng[i], bnb[i], sv, tv);
    fold_w_io<<<64, 512, 0, stream>>>(Wq[i], bq[i], sv, tv, nullptr, WqkIo, bqkf);
    fold_w_io<<<64, 512, 0, stream>>>(Wk[i], bk[i], sv, tv, nullptr,
                                      WqkIo + (size_t)64 * 2048, bqkf + 64);
    fold_w_io<<<512, 512, 0, stream>>>(Wv[i], bv[i], sv, tv, gam[i], WvIo, bvf);
    // q|k = h @ Wqk'.T + b'  (split 3-pass; f32 out on d_out)
    sgemm<0, 0, 3><<<dim3(1, 448), 512, 0, stream>>>(Hio, WqkIo, bqkf, qkf,
                                                     nullptr, nullptr, 128);
    // v' = h @ (gam*Wv*s)'.T + b''  (split 3-pass; plain bf16 out)
    sgemm<0, 2, 3><<<dim3(4, 448), 512, 0, stream>>>(Hio, WvIo, bvf, nullptr,
                                                     V, nullptr, 512);
    // h = relu(att@v' + h*s + t) in place (+ stats partials for next layer)
    if (i < 2)
      attn_relu<true><<<4096, 256, 0, stream>>>(qkf, (const bf16*)V, Hio, sv, tv, part);
    else
      attn_relu<false><<<4096, 256, 0, stream>>>(qkf, (const bf16*)V, Hio, sv, tv, nullptr);
  }

  // out = h3_hi @ Wb.T + bb  (1-pass; f32 out)
  sgemm<0, 0, 1><<<dim3(2, 448), 512, 0, stream>>>(Hio, WbIo, bbf, (float*)d_out,
                                                   nullptr, nullptr, 256);
}

// Round 12
// 1428.158 us; speedup vs baseline: 2.0295x; 1.1071x over previous
//
#include <hip/hip_runtime.h>
#include <hip/hip_bf16.h>
#include <stdint.h>

// LevelReasoning on MI355X — round 12: r8 structure + fp16-pair numerics.
// h/V stored as fp16 (hi,lo) io pairs (21-bit effective). v-GEMM: 2-pass f16
// (a@Wh exact-in-A; dropped a@Wl ~2^-11 one-sided; r7-calibrated +0.018 absmax).
// qk: 3-pass f16 with Wl pre-scaled x1024 into separate acc2 (subnormal-proof).
// gemm1: bf16 3-pass in-reg split (unchanged, exact-grade), fp16-io output.
// final: 1-pass f16. GEMM structure byte-identical to r8 (proven 1477us).

using bf16 = __hip_bfloat16;
typedef __attribute__((ext_vector_type(8))) short short8;
typedef __attribute__((ext_vector_type(4))) float f32x4;
typedef _Float16 f16x8 __attribute__((ext_vector_type(8)));

__device__ inline uint16_t f2b_bits(float f) {
  bf16 h = __float2bfloat16(f);
  return __builtin_bit_cast(uint16_t, h);
}
__device__ inline float b2f_bits(uint16_t u) { return __uint_as_float(((uint32_t)u) << 16); }
__device__ inline void split2(float v, uint16_t& hi, uint16_t& lo) {
  hi = f2b_bits(v);
  lo = f2b_bits(v - b2f_bits(hi));
}
__device__ inline uint16_t f2h_bits(float f) {
  _Float16 h = (_Float16)f;
  return __builtin_bit_cast(uint16_t, h);
}
__device__ inline float h2f_bits(uint16_t u) {
  return (float)__builtin_bit_cast(_Float16, u);
}
__device__ inline void split2h(float v, uint16_t& hi, uint16_t& lo) {
  hi = f2h_bits(v);
  lo = f2h_bits(v - h2f_bits(hi));
}
__device__ inline float g16(const uint4& u, int e) {  // fp16 decode from packed
  uint32_t wrd = ((const uint32_t*)&u)[e >> 1];
  return h2f_bits((uint16_t)((e & 1) ? (wrd >> 16) : (wrd & 0xffffu)));
}

typedef const __attribute__((address_space(1))) void* gas_ptr;
typedef __attribute__((address_space(3))) void* las_ptr;
__device__ inline void gload16(const void* g, void* l) {
  __builtin_amdgcn_global_load_lds((gas_ptr)g, (las_ptr)l, 16, 0, 0);
}

// ---------------- f32 -> fp16 (plain, for Wb) ----------------
__global__ __launch_bounds__(256) void cvt4h(const float* __restrict__ in,
                                             uint16_t* __restrict__ out, int n4) {
  int i = blockIdx.x * 256 + threadIdx.x;
  const int stride = gridDim.x * 256;
  for (; i < n4; i += stride) {
    float4 v = ((const float4*)in)[i];
    uint32_t lo = (uint32_t)f2h_bits(v.x) | ((uint32_t)f2h_bits(v.y) << 16);
    uint32_t hi = (uint32_t)f2h_bits(v.z) | ((uint32_t)f2h_bits(v.w) << 16);
    ((uint2*)out)[i] = make_uint2(lo, hi);
  }
}

// ------- fold weight to io-format: W' = g*W*diag(s), b' = g*(b + t@W.T) -------
// DT 0 = bf16 pair; DT 1 = fp16 pair with lo stored *WLS (subnormal-proofing)
template <int DT, int WLS>
__global__ __launch_bounds__(512) void fold_w_io(const float* __restrict__ Wsrc,
                                                 const float* __restrict__ bsrc,
                                                 const float* __restrict__ sv,
                                                 const float* __restrict__ tv,
                                                 const float* __restrict__ gamp,
                                                 char* __restrict__ Wio,
                                                 float* __restrict__ bout) {
  const int row = blockIdx.x, c = threadIdx.x;
  __shared__ float red[512];
  const float wv = Wsrc[(size_t)row * 512 + c];
  const float g = gamp ? gamp[0] : 1.0f;
  const float s = sv ? sv[c] : 1.0f;
  const float fv = g * wv * s;
  uint16_t hb, lb;
  if constexpr (DT == 0) {
    split2(fv, hb, lb);
  } else {
    hb = f2h_bits(fv);
    lb = f2h_bits((fv - h2f_bits(hb)) * (float)WLS);
  }
  char* p = Wio + (size_t)row * 2048 + (c >> 3) * 32 + (c & 7) * 2;
  *(uint16_t*)p = hb;
  *(uint16_t*)(p + 16) = lb;
  red[c] = tv ? wv * tv[c] : 0.0f;
  __syncthreads();
#pragma unroll
  for (int off = 256; off > 0; off >>= 1) {
    if (c < off) red[c] += red[c + off];
    __syncthreads();
  }
  if (c == 0) bout[row] = g * (bsrc[row] + red[0]);
}

// ---------------- 224-row-tile split GEMM (r8 structure) ----------------
// AMODE 0: A fp16-io; f16 MFMA. AMODE 1: A f32, in-reg bf16 split; bf16 MFMA.
// EPI 0: outf=acc(+acc2/1024)+bias. EPI 1: fp16-io out + stats. EPI 2: fp16 out pitch 512.
// NPASS (AMODE 0): 2 = hh+lh; 3 = hh+lh(acc) + hl(acc2, W-lo prescaled x1024).
template <int AMODE, int EPI, int BN, int NPASS>
__global__ __launch_bounds__(512, 1) void sgemm(const char* __restrict__ A,
                                                const char* __restrict__ Wio,
                                                const float* __restrict__ bias,
                                                float* __restrict__ outf,
                                                char* __restrict__ outb,
                                                float* __restrict__ part, int N) {
  constexpr int NFR = BN / 64;
  constexpr int A_BYTES = 224 * 128;  // 28672
  constexpr int PER_BUF = A_BYTES + BN * 128;
  constexpr int NB_K = BN / 64;
  constexpr bool QACC2 = (AMODE == 0 && NPASS == 3);
  __shared__ __align__(16) char lds[2 * PER_BUF];
  __shared__ float sred[2][2][256];
  const int tid = threadIdx.x, w = tid >> 6, l = tid & 63;

  const int nwgx = gridDim.x;
  const int raw = blockIdx.y * nwgx + blockIdx.x;
  const int cpx = (nwgx * gridDim.y) >> 3;
  const int work = (raw & 7) * cpx + (raw >> 3);
  const int bmidx = work / nwgx;
  const int bm = bmidx * 224;
  const int bn = (work % nwgx) * BN;

  const int ssl = ((((l >> 1) & 3) ^ ((l >> 3) & 3)) << 5) | (((l & 1) ^ ((l >> 5) & 1)) << 4);
  const char* Asrc = A + (size_t)(bm + (l >> 3)) * 2048 + ssl;
  const char* Bsrc = Wio + (size_t)(bn + (l >> 3)) * 2048 + ssl;

  const int lrow = l & 15, lk = l >> 4;
  const int wr = w >> 2, wc = w & 3;
  const int sw32 = (lk ^ (lrow & 3)) * 32;
  const int hi16 = ((lrow >> 2) & 1) * 16;
  const int afr = (wr * 112 + lrow) * 128 + sw32;
  const int bfr = A_BYTES + (wc * (BN / 4) + lrow) * 128 + sw32;

  f32x4 acc[7][NFR] = {};
  f32x4 acc2[QACC2 ? 7 : 1][NFR] = {};

  auto stage_a = [&](int buf, int t) {
    char* dst = lds + buf * PER_BUF;
    const char* src = Asrc + (size_t)t * 128;
#pragma unroll
    for (int k = 0; k < 4; ++k) {
      const int i = w + k * 8;
      if (k < 3 || w < 4) gload16(src + (size_t)i * 16384, dst + i * 1024);
    }
  };
  auto stage_b = [&](int buf, int t) {
    char* dst = lds + buf * PER_BUF + A_BYTES;
    const char* src = Bsrc + (size_t)t * 128;
#pragma unroll
    for (int k = 0; k < NB_K; ++k) {
      const int i = w + k * 8;
      gload16(src + (size_t)i * 16384, dst + i * 1024);
    }
  };

#define LOADA(BASE, CNT)                                                         \
  {                                                                              \
    _Pragma("unroll") for (int u = 0; u < (CNT); ++u) {                          \
      const int mi = (BASE) + u;                                                 \
      if constexpr (AMODE == 0) {                                                \
        ah[u] = *(const short8*)(bp + afr + mi * 2048 + hi16);                   \
        if constexpr (NPASS >= 2)                                                \
          al[u] = *(const short8*)(bp + afr + mi * 2048 + (hi16 ^ 16));          \
      } else {                                                                   \
        float4 f0 = *(const float4*)(bp + afr + mi * 2048 + hi16);               \
        float4 f1 = *(const float4*)(bp + afr + mi * 2048 + (hi16 ^ 16));        \
        const float fv[8] = {f0.x, f0.y, f0.z, f0.w, f1.x, f1.y, f1.z, f1.w};    \
        _Pragma("unroll") for (int e = 0; e < 8; ++e) {                          \
          uint16_t hb, lb;                                                       \
          split2(fv[e], hb, lb);                                                 \
          ah[u][e] = (short)hb;                                                  \
          al[u][e] = (short)lb;                                                  \
        }                                                                        \
      }                                                                          \
    }                                                                            \
  }

#define MFMAC(BASE, CNT)                                                         \
  {                                                                              \
    __builtin_amdgcn_s_setprio(1);                                               \
    if constexpr (AMODE == 1) {                                                  \
      _Pragma("unroll") for (int u = 0; u < (CNT); ++u)                          \
        _Pragma("unroll") for (int ni = 0; ni < NFR; ++ni)                       \
          acc[(BASE) + u][ni] = __builtin_amdgcn_mfma_f32_16x16x32_bf16(         \
              ah[u], bh[ni], acc[(BASE) + u][ni], 0, 0, 0);                      \
      _Pragma("unroll") for (int u = 0; u < (CNT); ++u)                          \
        _Pragma("unroll") for (int ni = 0; ni < NFR; ++ni)                       \
          acc[(BASE) + u][ni] = __builtin_amdgcn_mfma_f32_16x16x32_bf16(         \
              ah[u], bl[ni], acc[(BASE) + u][ni], 0, 0, 0);                      \
      _Pragma("unroll") for (int u = 0; u < (CNT); ++u)                          \
        _Pragma("unroll") for (int ni = 0; ni < NFR; ++ni)                       \
          acc[(BASE) + u][ni] = __builtin_amdgcn_mfma_f32_16x16x32_bf16(         \
              al[u], bh[ni], acc[(BASE) + u][ni], 0, 0, 0);                      \
    } else {                                                                     \
      _Pragma("unroll") for (int u = 0; u < (CNT); ++u)                          \
        _Pragma("unroll") for (int ni = 0; ni < NFR; ++ni)                       \
          acc[(BASE) + u][ni] = __builtin_amdgcn_mfma_f32_16x16x32_f16(          \
              __builtin_bit_cast(f16x8, ah[u]), __builtin_bit_cast(f16x8, bh[ni]), \
              acc[(BASE) + u][ni], 0, 0, 0);                                     \
      if constexpr (NPASS >= 2) {                                                \
        _Pragma("unroll") for (int u = 0; u < (CNT); ++u)                        \
          _Pragma("unroll") for (int ni = 0; ni < NFR; ++ni)                     \
            acc[(BASE) + u][ni] = __builtin_amdgcn_mfma_f32_16x16x32_f16(        \
                __builtin_bit_cast(f16x8, al[u]), __builtin_bit_cast(f16x8, bh[ni]), \
                acc[(BASE) + u][ni], 0, 0, 0);                                   \
      }                                                                          \
      if constexpr (QACC2) {                                                     \
        _Pragma("unroll") for (int u = 0; u < (CNT); ++u)                        \
          _Pragma("unroll") for (int ni = 0; ni < NFR; ++ni)                     \
            acc2[(BASE) + u][ni] = __builtin_amdgcn_mfma_f32_16x16x32_f16(       \
                __builtin_bit_cast(f16x8, ah[u]), __builtin_bit_cast(f16x8, bl[ni]), \
                acc2[(BASE) + u][ni], 0, 0, 0);                                  \
      }                                                                          \
    }                                                                            \
    __builtin_amdgcn_s_setprio(0);                                               \
  }

  stage_a(0, 0);
  stage_b(0, 0);
  int cur = 0;
#pragma unroll 2
  for (int t = 0; t < 16; ++t) {
    asm volatile("s_waitcnt vmcnt(0)" ::: "memory");
    __builtin_amdgcn_s_barrier();
    asm volatile("" ::: "memory");

    const char* bp = lds + cur * PER_BUF;
    if (t < 15) stage_a(cur ^ 1, t + 1);

    short8 bh[NFR], bl[NFR];
#pragma unroll
    for (int ni = 0; ni < NFR; ++ni) {
      bh[ni] = *(const short8*)(bp + bfr + ni * 2048 + hi16);
      if constexpr (NPASS == 3)
        bl[ni] = *(const short8*)(bp + bfr + ni * 2048 + (hi16 ^ 16));
    }
    short8 ah[4], al[4];
    LOADA(0, 4)
    MFMAC(0, 4)
    if (t < 15) stage_b(cur ^ 1, t + 1);
    LOADA(4, 3)
    MFMAC(4, 3)
    cur ^= 1;
  }
#undef LOADA
#undef MFMAC

  float sni[NFR] = {}, qni[NFR] = {};
#pragma unroll
  for (int mi = 0; mi < 7; ++mi) {
    const int row = bm + wr * 112 + mi * 16 + lk * 4;
#pragma unroll
    for (int ni = 0; ni < NFR; ++ni) {
      const int col = bn + wc * (BN / 4) + ni * 16 + lrow;
      const float bc = bias[col];
#pragma unroll
      for (int j = 0; j < 4; ++j) {
        float vv = acc[mi][ni][j] + bc;
        if constexpr (QACC2) vv += acc2[mi][ni][j] * (1.0f / 1024.0f);
        if constexpr (EPI == 0) {
          outf[(size_t)(row + j) * N + col] = vv;
        } else if constexpr (EPI == 1) {
          uint16_t hb, lb;
          split2h(vv, hb, lb);
          char* p = outb + (size_t)(row + j) * 2048 + (col >> 3) * 32 + (col & 7) * 2;
          *(uint16_t*)p = hb;
          *(uint16_t*)(p + 16) = lb;
          sni[ni] += vv;
          qni[ni] += vv * vv;
        } else {
          *(uint16_t*)(outb + ((size_t)(row + j) * 512 + col) * 2) = f2h_bits(vv);
        }
      }
    }
  }

  if constexpr (EPI == 1) {
#pragma unroll
    for (int ni = 0; ni < NFR; ++ni) {
      float s = sni[ni], q = qni[ni];
      s += __shfl_xor(s, 16); q += __shfl_xor(q, 16);
      s += __shfl_xor(s, 32); q += __shfl_xor(q, 32);
      if (lk == 0) {
        sred[0][wr][wc * 64 + ni * 16 + lrow] = s;
        sred[1][wr][wc * 64 + ni * 16 + lrow] = q;
      }
    }
    __syncthreads();
    if (tid < 256) {
      part[(size_t)bmidx * 1024 + bn + tid] = sred[0][0][tid] + sred[0][1][tid];
      part[(size_t)bmidx * 1024 + 512 + bn + tid] = sred[1][0][tid] + sred[1][1][tid];
    }
  }
}

// ---------------- final plain GEMM: out[M,256] = h_hi @ Wb.T + bb (f16) ----------------
__global__ __launch_bounds__(256) void gemm_final(const char* __restrict__ Aio,
                                                  const uint16_t* __restrict__ Wb,
                                                  const float* __restrict__ bias,
                                                  float* __restrict__ out) {
  __shared__ __align__(16) char lds[32768];
  const int tid = threadIdx.x, w = tid >> 6, l = tid & 63;
  const int bn = blockIdx.x * 128, bm = blockIdx.y * 128;

  const int srow = l >> 2;
  const int ss = (l & 3) ^ (srow & 3);
  const char* Asrc = Aio + (size_t)(bm + srow) * 2048 + ss * 32;
  const char* Bsrc = (const char*)Wb + (size_t)(bn + srow) * 1024 + ss * 16;

  const int lrow = l & 15, lk = l >> 4;
  const int wr = w >> 1, wc = w & 1;
  const int abase = (wr * 64 + lrow) * 64;
  const int bbase = 8192 + (wc * 64 + lrow) * 64;
  const int sf = (lk ^ (lrow & 3)) * 16;

  f32x4 acc[4][4] = {};
  auto stage = [&](int buf, int t) {
#pragma unroll
    for (int c = 0; c < 2; ++c) {
      const int i = w * 2 + c;
      gload16(Asrc + (size_t)i * 16 * 2048 + (size_t)t * 128, lds + buf * 16384 + i * 1024);
      gload16(Bsrc + (size_t)i * 16 * 1024 + (size_t)t * 64, lds + buf * 16384 + 8192 + i * 1024);
    }
  };
  stage(0, 0);
  __syncthreads();
  int cur = 0;
  for (int t = 0; t < 16; ++t) {
    if (t < 15) stage(cur ^ 1, t + 1);
    const char* bp = lds + cur * 16384;
    short8 af[4], bf_[4];
#pragma unroll
    for (int i = 0; i < 4; ++i) {
      af[i] = *(const short8*)(bp + abase + i * 1024 + sf);
      bf_[i] = *(const short8*)(bp + bbase + i * 1024 + sf);
    }
#pragma unroll
    for (int mi = 0; mi < 4; ++mi)
#pragma unroll
      for (int ni = 0; ni < 4; ++ni)
        acc[mi][ni] = __builtin_amdgcn_mfma_f32_16x16x32_f16(
            __builtin_bit_cast(f16x8, af[mi]), __builtin_bit_cast(f16x8, bf_[ni]),
            acc[mi][ni], 0, 0, 0);
    __syncthreads();
    cur ^= 1;
  }
#pragma unroll
  for (int mi = 0; mi < 4; ++mi) {
    const int row = bm + wr * 64 + mi * 16 + lk * 4;
#pragma unroll
    for (int ni = 0; ni < 4; ++ni) {
      const int col = bn + wc * 64 + ni * 16 + lrow;
      const float bc = bias[col];
#pragma unroll
      for (int j = 0; j < 4; ++j)
        out[(size_t)(row + j) * 256 + col] = acc[mi][ni][j] + bc;
    }
  }
}

// ---------------- stats reduce: part[n][1024] -> sv, tv ----------------
__global__ __launch_bounds__(64) void reduce_stats(const float* __restrict__ part, int n,
                                                   const float* __restrict__ g,
                                                   const float* __restrict__ bb,
                                                   float* __restrict__ sv,
                                                   float* __restrict__ tv) {
  const int c = blockIdx.x, k = threadIdx.x;
  float sum = 0.f, sq = 0.f;
  for (int i = k; i < n; i += 64) {
    const float* p = part + (size_t)i * 1024;
    sum += p[c];
    sq += p[512 + c];
  }
#pragma unroll
  for (int o = 32; o; o >>= 1) {
    sum += __shfl_xor(sum, o);
    sq += __shfl_xor(sq, o);
  }
  if (k == 0) {
    const float mean = sum * (1.0f / 114688.0f);
    const float var = sq * (1.0f / 114688.0f) - mean * mean;
    const float sc = g[c] * rsqrtf(var + 1e-5f);
    sv[c] = sc;
    tv[c] = bb[c] - mean * sc;
  }
}

// ---------------- fused attention + residual + relu (+ stats), in place on h ----------------
template <bool STATS>
__global__ __launch_bounds__(256) void attn_relu(const float* __restrict__ qkf,
                                                 const uint16_t* __restrict__ V,
                                                 char* __restrict__ Hio,
                                                 const float* __restrict__ sv,
                                                 const float* __restrict__ tv,
                                                 float* __restrict__ part) {
  __shared__ float smS[4][512], smQ[4][512];
  const int w = threadIdx.x >> 6, l = threadIdx.x & 63;
  const int b = blockIdx.x * 4 + w;
  const size_t base = (size_t)b * 7;

  float qv[7], kv[7];
#pragma unroll
  for (int i = 0; i < 7; ++i) {
    qv[i] = qkf[(base + i) * 128 + l];
    kv[i] = qkf[(base + i) * 128 + 64 + l];
  }
  float att[7][7];
#pragma unroll
  for (int i = 0; i < 7; ++i)
#pragma unroll
    for (int j = 0; j < 7; ++j) {
      float p = qv[i] * kv[j];
#pragma unroll
      for (int o = 32; o; o >>= 1) p += __shfl_xor(p, o);
      att[i][j] = p;
    }
#pragma unroll
  for (int i = 0; i < 7; ++i) {
    float m = att[i][0];
#pragma unroll
    for (int j = 1; j < 7; ++j) m = fmaxf(m, att[i][j]);
    float sum = 0.f;
#pragma unroll
    for (int j = 0; j < 7; ++j) {
      att[i][j] = expf(att[i][j] - m);
      sum += att[i][j];
    }
    const float inv = 1.0f / sum;
#pragma unroll
    for (int j = 0; j < 7; ++j) att[i][j] *= inv;
  }

  const float4 s0 = *(const float4*)&sv[l * 8], s1 = *(const float4*)&sv[l * 8 + 4];
  const float4 t0 = *(const float4*)&tv[l * 8], t1 = *(const float4*)&tv[l * 8 + 4];
  const float sarr[8] = {s0.x, s0.y, s0.z, s0.w, s1.x, s1.y, s1.z, s1.w};
  const float tarr[8] = {t0.x, t0.y, t0.z, t0.w, t1.x, t1.y, t1.z, t1.w};

  uint4 vpk[7];
#pragma unroll
  for (int j = 0; j < 7; ++j)
    vpk[j] = *(const uint4*)((const char*)V + (base + j) * 1024 + l * 16);

  float s8[8] = {}, q8[8] = {};
#pragma unroll
  for (int i = 0; i < 7; ++i) {
    char* hp = Hio + (base + i) * 2048 + l * 32;
    uint4 hh = *(const uint4*)hp;
    uint4 hl = *(const uint4*)(hp + 16);
    float o[8] = {};
#pragma unroll
    for (int j = 0; j < 7; ++j) {
      const float a = att[i][j];
#pragma unroll
      for (int e = 0; e < 8; ++e) o[e] += a * g16(vpk[j], e);
    }
    uint16_t oh[8], ol[8];
#pragma unroll
    for (int e = 0; e < 8; ++e) {
      const float hval = g16(hh, e) + g16(hl, e);
      const float rr = fmaxf(o[e] + hval * sarr[e] + tarr[e], 0.f);
      if constexpr (STATS) { s8[e] += rr; q8[e] += rr * rr; }
      split2h(rr, oh[e], ol[e]);
    }
    uint4 ph, pl;
#pragma unroll
    for (int k2 = 0; k2 < 4; ++k2) {
      ((uint32_t*)&ph)[k2] = (uint32_t)oh[2 * k2] | ((uint32_t)oh[2 * k2 + 1] << 16);
      ((uint32_t*)&pl)[k2] = (uint32_t)ol[2 * k2] | ((uint32_t)ol[2 * k2 + 1] << 16);
    }
    *(uint4*)hp = ph;
    *(uint4*)(hp + 16) = pl;
  }

  if constexpr (STATS) {
#pragma unroll
    for (int e = 0; e < 8; ++e) {
      smS[w][l * 8 + e] = s8[e];
      smQ[w][l * 8 + e] = q8[e];
    }
    __syncthreads();
    const int c = threadIdx.x * 2;
#pragma unroll
    for (int cc = 0; cc < 2; ++cc) {
      const int c2 = c + cc;
      part[(size_t)blockIdx.x * 1024 + c2] =
          smS[0][c2] + smS[1][c2] + smS[2][c2] + smS[3][c2];
      part[(size_t)blockIdx.x * 1024 + 512 + c2] =
          smQ[0][c2] + smQ[1][c2] + smQ[2][c2] + smQ[3][c2];
    }
  }
}

extern "C" void kernel_launch(void* const* d_in, const int* in_sizes, int n_in,
                              void* d_out, int out_size, void* d_ws, size_t ws_size,
                              hipStream_t stream) {
  const float* x  = (const float*)d_in[0];
  const float* Wt = (const float*)d_in[1];
  const float* bt = (const float*)d_in[2];
  const float *bng[3], *bnb[3], *Wq[3], *bq[3], *Wk[3], *bk[3], *Wv[3], *bv[3], *gam[3];
  for (int i = 0; i < 3; ++i) {
    int o = 3 + 9 * i;
    bng[i] = (const float*)d_in[o + 0];
    bnb[i] = (const float*)d_in[o + 1];
    Wq[i]  = (const float*)d_in[o + 2];
    bq[i]  = (const float*)d_in[o + 3];
    Wk[i]  = (const float*)d_in[o + 4];
    bk[i]  = (const float*)d_in[o + 5];
    Wv[i]  = (const float*)d_in[o + 6];
    bv[i]  = (const float*)d_in[o + 7];
    gam[i] = (const float*)d_in[o + 8];
  }
  const float* Wb = (const float*)d_in[30];
  const float* bb = (const float*)d_in[31];

  char* ws = (char*)d_ws;
  char*     Hio   = ws;                               // 235,929,600 (114688 x 2048B)
  uint16_t* V     = (uint16_t*)(ws + 235929600);      // 117,440,512 (fp16)
  float*    part  = (float*)(ws + 353370112);         // 16,777,216
  float*    sv    = (float*)(ws + 370147328);         // 2,048
  float*    tv    = (float*)(ws + 370149376);         // 2,048
  char*     WqkIo = ws + 370151424;                   // 262,144
  float*    bqkf  = (float*)(ws + 370413568);         // 2,048
  char*     WvIo  = ws + 370415616;                   // 1,048,576
  float*    bvf   = (float*)(ws + 371464192);         // 2,048
  char*     WtIo  = ws + 371466240;                   // 1,048,576
  float*    btf   = (float*)(ws + 372514816);         // 2,048
  uint16_t* Wbbf  = (uint16_t*)(ws + 372516864);      // 262,144
  float*    qkf   = (float*)d_out;                    // 58.7 MB <= out bytes

  // weight prep
  cvt4h<<<128, 256, 0, stream>>>(Wb, Wbbf, 32768);
  fold_w_io<0, 1><<<512, 512, 0, stream>>>(Wt, bt, nullptr, nullptr, nullptr, WtIo, btf);

  // h0 = x @ Wt.T + bt  (bf16 3-pass in-reg split; fp16-io out + stats partials)
  sgemm<1, 1, 256, 3><<<dim3(2, 512), 512, 0, stream>>>((const char*)x, WtIo, btf,
                                                        nullptr, Hio, part, 512);

  for (int i = 0; i < 3; ++i) {
    reduce_stats<<<512, 64, 0, stream>>>(part, i == 0 ? 512 : 4096,
                                         bng[i], bnb[i], sv, tv);
    fold_w_io<1, 1024><<<64, 512, 0, stream>>>(Wq[i], bq[i], sv, tv, nullptr, WqkIo, bqkf);
    fold_w_io<1, 1024><<<64, 512, 0, stream>>>(Wk[i], bk[i], sv, tv, nullptr,
                                               WqkIo + (size_t)64 * 2048, bqkf + 64);
    fold_w_io<1, 1><<<512, 512, 0, stream>>>(Wv[i], bv[i], sv, tv, gam[i], WvIo, bvf);
    // q|k = h @ Wqk'.T + b'  (f16 3-pass, Wl x1024 -> acc2; f32 out on d_out)
    sgemm<0, 0, 128, 3><<<dim3(1, 512), 512, 0, stream>>>(Hio, WqkIo, bqkf, qkf,
                                                          nullptr, nullptr, 128);
    // v' = h @ (gam*Wv*s)'.T + b''  (f16 2-pass; fp16 out)
    sgemm<0, 2, 256, 2><<<dim3(2, 512), 512, 0, stream>>>(Hio, WvIo, bvf, nullptr,
                                                          (char*)V, nullptr, 512);
    // h = relu(att@v' + h*s + t) in place (+ stats partials for next layer)
    if (i < 2)
      attn_relu<true><<<4096, 256, 0, stream>>>(qkf, V, Hio, sv, tv, part);
    else
      attn_relu<false><<<4096, 256, 0, stream>>>(qkf, V, Hio, sv, tv, nullptr);
  }

  // out = h3_hi @ Wb.T + bb  (f16 1-pass; f32 out)
  gemm_final<<<dim3(2, 896), 256, 0, stream>>>(Hio, Wbbf, bb, (float*)d_out);
}

// Round 13
// 1155.300 us; speedup vs baseline: 2.5088x; 1.2362x over previous
//
#include <hip/hip_runtime.h>
#include <hip/hip_bf16.h>
#include <stdint.h>

// LevelReasoning on MI355X — round 13: single-fp16 h + BK=64 (half the barriers).
// Diagnosis r12: v-2pass == gemm1-3pass == 247us -> per-tile fixed overhead (~72%)
// dominates, not MFMA. Fix: halve tiles (BK=64 -> 8 barriers) and halve staged
// bytes (h single fp16, 1KB rows). qk keeps W-side exact via fp16-pair W with
// lo x1024 -> acc2 (r12-proven). gemm1 unchanged (f32 A), writes fp16 plane.

using bf16 = __hip_bfloat16;
typedef __attribute__((ext_vector_type(8))) short short8;
typedef __attribute__((ext_vector_type(4))) float f32x4;
typedef _Float16 f16x8 __attribute__((ext_vector_type(8)));

__device__ inline uint16_t f2b_bits(float f) {
  bf16 h = __float2bfloat16(f);
  return __builtin_bit_cast(uint16_t, h);
}
__device__ inline float b2f_bits(uint16_t u) { return __uint_as_float(((uint32_t)u) << 16); }
__device__ inline void split2(float v, uint16_t& hi, uint16_t& lo) {
  hi = f2b_bits(v);
  lo = f2b_bits(v - b2f_bits(hi));
}
__device__ inline uint16_t f2h_bits(float f) {
  _Float16 h = (_Float16)f;
  return __builtin_bit_cast(uint16_t, h);
}
__device__ inline float h2f_bits(uint16_t u) {
  return (float)__builtin_bit_cast(_Float16, u);
}
__device__ inline float g16(const uint4& u, int e) {
  uint32_t wrd = ((const uint32_t*)&u)[e >> 1];
  return h2f_bits((uint16_t)((e & 1) ? (wrd >> 16) : (wrd & 0xffffu)));
}

typedef const __attribute__((address_space(1))) void* gas_ptr;
typedef __attribute__((address_space(3))) void* las_ptr;
__device__ inline void gload16(const void* g, void* l) {
  __builtin_amdgcn_global_load_lds((gas_ptr)g, (las_ptr)l, 16, 0, 0);
}

// ---------------- f32 -> fp16 plain (Wb) ----------------
__global__ __launch_bounds__(256) void cvt4h(const float* __restrict__ in,
                                             uint16_t* __restrict__ out, int n4) {
  int i = blockIdx.x * 256 + threadIdx.x;
  const int stride = gridDim.x * 256;
  for (; i < n4; i += stride) {
    float4 v = ((const float4*)in)[i];
    uint32_t lo = (uint32_t)f2h_bits(v.x) | ((uint32_t)f2h_bits(v.y) << 16);
    uint32_t hi = (uint32_t)f2h_bits(v.z) | ((uint32_t)f2h_bits(v.w) << 16);
    ((uint2*)out)[i] = make_uint2(lo, hi);
  }
}

// ------- fold Wt to bf16-pair io (2KB rows) for gemm1 -------
__global__ __launch_bounds__(512) void fold_w_io(const float* __restrict__ Wsrc,
                                                 const float* __restrict__ bsrc,
                                                 char* __restrict__ Wio,
                                                 float* __restrict__ bout) {
  const int row = blockIdx.x, c = threadIdx.x;
  const float wv = Wsrc[(size_t)row * 512 + c];
  uint16_t hb, lb;
  split2(wv, hb, lb);
  char* p = Wio + (size_t)row * 2048 + (c >> 3) * 32 + (c & 7) * 2;
  *(uint16_t*)p = hb;
  *(uint16_t*)(p + 16) = lb;
  if (c == 0) bout[row] = bsrc[row];
}

// ------- fold W to fp16 plane(s): Wh = f16(g*W*s), Wl = f16((..-Wh)*1024) -------
__global__ __launch_bounds__(512) void fold_w_plane(const float* __restrict__ Wsrc,
                                                    const float* __restrict__ bsrc,
                                                    const float* __restrict__ sv,
                                                    const float* __restrict__ tv,
                                                    const float* __restrict__ gamp,
                                                    uint16_t* __restrict__ Wh,
                                                    uint16_t* __restrict__ Wl,
                                                    float* __restrict__ bout) {
  const int row = blockIdx.x, c = threadIdx.x;
  __shared__ float red[512];
  const float wv = Wsrc[(size_t)row * 512 + c];
  const float g = gamp ? gamp[0] : 1.0f;
  const float fv = g * wv * sv[c];
  const uint16_t hb = f2h_bits(fv);
  Wh[(size_t)row * 512 + c] = hb;
  if (Wl) Wl[(size_t)row * 512 + c] = f2h_bits((fv - h2f_bits(hb)) * 1024.0f);
  red[c] = wv * tv[c];
  __syncthreads();
#pragma unroll
  for (int off = 256; off > 0; off >>= 1) {
    if (c < off) red[c] += red[c + off];
    __syncthreads();
  }
  if (c == 0) bout[row] = g * (bsrc[row] + red[0]);
}

// ---------------- gemm1: h0 = x @ Wt.T + bt (r12 structure, fp16-plane out + stats) ---------
__global__ __launch_bounds__(512, 1) void gemm1(const char* __restrict__ A,
                                                const char* __restrict__ Wio,
                                                const float* __restrict__ bias,
                                                uint16_t* __restrict__ outh,
                                                float* __restrict__ part) {
  constexpr int A_BYTES = 224 * 128;
  constexpr int PER_BUF = A_BYTES + 256 * 128;
  __shared__ __align__(16) char lds[2 * PER_BUF];
  __shared__ float sred[2][2][256];
  const int tid = threadIdx.x, w = tid >> 6, l = tid & 63;

  const int nwgx = gridDim.x;
  const int raw = blockIdx.y * nwgx + blockIdx.x;
  const int cpx = (nwgx * gridDim.y) >> 3;
  const int work = (raw & 7) * cpx + (raw >> 3);
  const int bmidx = work / nwgx;
  const int bm = bmidx * 224;
  const int bn = (work % nwgx) * 256;

  const int ssl = ((((l >> 1) & 3) ^ ((l >> 3) & 3)) << 5) | (((l & 1) ^ ((l >> 5) & 1)) << 4);
  const char* Asrc = A + (size_t)(bm + (l >> 3)) * 2048 + ssl;
  const char* Bsrc = Wio + (size_t)(bn + (l >> 3)) * 2048 + ssl;

  const int lrow = l & 15, lk = l >> 4;
  const int wr = w >> 2, wc = w & 3;
  const int sw32 = (lk ^ (lrow & 3)) * 32;
  const int hi16 = ((lrow >> 2) & 1) * 16;
  const int afr = (wr * 112 + lrow) * 128 + sw32;
  const int bfr = A_BYTES + (wc * 64 + lrow) * 128 + sw32;

  f32x4 acc[7][4] = {};

  auto stage_a = [&](int buf, int t) {
    char* dst = lds + buf * PER_BUF;
    const char* src = Asrc + (size_t)t * 128;
#pragma unroll
    for (int k = 0; k < 4; ++k) {
      const int i = w + k * 8;
      if (k < 3 || w < 4) gload16(src + (size_t)i * 16384, dst + i * 1024);
    }
  };
  auto stage_b = [&](int buf, int t) {
    char* dst = lds + buf * PER_BUF + A_BYTES;
    const char* src = Bsrc + (size_t)t * 128;
#pragma unroll
    for (int k = 0; k < 4; ++k) {
      const int i = w + k * 8;
      gload16(src + (size_t)i * 16384, dst + i * 1024);
    }
  };

#define LOADA(BASE, CNT)                                                         \
  {                                                                              \
    _Pragma("unroll") for (int u = 0; u < (CNT); ++u) {                          \
      const int mi = (BASE) + u;                                                 \
      float4 f0 = *(const float4*)(bp + afr + mi * 2048 + hi16);                 \
      float4 f1 = *(const float4*)(bp + afr + mi * 2048 + (hi16 ^ 16));          \
      const float fv[8] = {f0.x, f0.y, f0.z, f0.w, f1.x, f1.y, f1.z, f1.w};      \
      _Pragma("unroll") for (int e = 0; e < 8; ++e) {                            \
        uint16_t hb, lb;                                                         \
        split2(fv[e], hb, lb);                                                   \
        ah[u][e] = (short)hb;                                                    \
        al[u][e] = (short)lb;                                                    \
      }                                                                          \
    }                                                                            \
  }

#define MFMAC(BASE, CNT)                                                         \
  {                                                                              \
    __builtin_amdgcn_s_setprio(1);                                               \
    _Pragma("unroll") for (int u = 0; u < (CNT); ++u)                            \
      _Pragma("unroll") for (int ni = 0; ni < 4; ++ni)                           \
        acc[(BASE) + u][ni] = __builtin_amdgcn_mfma_f32_16x16x32_bf16(           \
            ah[u], bh[ni], acc[(BASE) + u][ni], 0, 0, 0);                        \
    _Pragma("unroll") for (int u = 0; u < (CNT); ++u)                            \
      _Pragma("unroll") for (int ni = 0; ni < 4; ++ni)                           \
        acc[(BASE) + u][ni] = __builtin_amdgcn_mfma_f32_16x16x32_bf16(           \
            ah[u], bl[ni], acc[(BASE) + u][ni], 0, 0, 0);                        \
    _Pragma("unroll") for (int u = 0; u < (CNT); ++u)                            \
      _Pragma("unroll") for (int ni = 0; ni < 4; ++ni)                           \
        acc[(BASE) + u][ni] = __builtin_amdgcn_mfma_f32_16x16x32_bf16(           \
            al[u], bh[ni], acc[(BASE) + u][ni], 0, 0, 0);                        \
    __builtin_amdgcn_s_setprio(0);                                               \
  }

  stage_a(0, 0);
  stage_b(0, 0);
  int cur = 0;
#pragma unroll 2
  for (int t = 0; t < 16; ++t) {
    asm volatile("s_waitcnt vmcnt(0)" ::: "memory");
    __builtin_amdgcn_s_barrier();
    asm volatile("" ::: "memory");

    const char* bp = lds + cur * PER_BUF;
    if (t < 15) stage_a(cur ^ 1, t + 1);

    short8 bh[4], bl[4];
#pragma unroll
    for (int ni = 0; ni < 4; ++ni) {
      bh[ni] = *(const short8*)(bp + bfr + ni * 2048 + hi16);
      bl[ni] = *(const short8*)(bp + bfr + ni * 2048 + (hi16 ^ 16));
    }
    short8 ah[4], al[4];
    LOADA(0, 4)
    MFMAC(0, 4)
    if (t < 15) stage_b(cur ^ 1, t + 1);
    LOADA(4, 3)
    MFMAC(4, 3)
    cur ^= 1;
  }
#undef LOADA
#undef MFMAC

  float sni[4] = {}, qni[4] = {};
#pragma unroll
  for (int mi = 0; mi < 7; ++mi) {
    const int row = bm + wr * 112 + mi * 16 + lk * 4;
#pragma unroll
    for (int ni = 0; ni < 4; ++ni) {
      const int col = bn + wc * 64 + ni * 16 + lrow;
      const float bc = bias[col];
#pragma unroll
      for (int j = 0; j < 4; ++j) {
        const float vv = acc[mi][ni][j] + bc;
        outh[(size_t)(row + j) * 512 + col] = f2h_bits(vv);
        sni[ni] += vv;
        qni[ni] += vv * vv;
      }
    }
  }
#pragma unroll
  for (int ni = 0; ni < 4; ++ni) {
    float s = sni[ni], q = qni[ni];
    s += __shfl_xor(s, 16); q += __shfl_xor(q, 16);
    s += __shfl_xor(s, 32); q += __shfl_xor(q, 32);
    if (lk == 0) {
      sred[0][wr][wc * 64 + ni * 16 + lrow] = s;
      sred[1][wr][wc * 64 + ni * 16 + lrow] = q;
    }
  }
  __syncthreads();
  if (tid < 256) {
    part[(size_t)bmidx * 1024 + bn + tid] = sred[0][0][tid] + sred[0][1][tid];
    part[(size_t)bmidx * 1024 + 512 + bn + tid] = sred[1][0][tid] + sred[1][1][tid];
  }
}

// ---------------- sgemm64: fp16 A-plane, BK=64, 8 barriers ----------------
// NPASS 1: W single plane. NPASS 2: W pair planes (lo x1024 -> acc2).
// EPI 0: f32 out pitch N (+acc2/1024). EPI 2: fp16 plane out pitch 512.
template <int EPI, int NPASS, int BN>
__global__ __launch_bounds__(512, 1) void sgemm64(const uint16_t* __restrict__ A,
                                                  const uint16_t* __restrict__ Wh,
                                                  const uint16_t* __restrict__ Wl,
                                                  const float* __restrict__ bias,
                                                  float* __restrict__ outf,
                                                  uint16_t* __restrict__ outh, int N) {
  constexpr int NFR = BN / 64;
  constexpr int A_BYTES = 224 * 128;
  constexpr int BPL = BN * 128;
  constexpr int PER_BUF = A_BYTES + BPL * NPASS;
  __shared__ __align__(16) char lds[2 * PER_BUF];
  const int tid = threadIdx.x, w = tid >> 6, l = tid & 63;

  const int nwgx = gridDim.x;
  const int raw = blockIdx.y * nwgx + blockIdx.x;
  const int cpx = (nwgx * gridDim.y) >> 3;
  const int work = (raw & 7) * cpx + (raw >> 3);
  const int bmidx = work / nwgx;
  const int bm = bmidx * 224;
  const int bn = (work % nwgx) * BN;

  // 8-way 16B-piece XOR swizzle: LDS (row, p) holds global (row, p ^ (row&7))
  const int sp = (((l & 7) ^ ((l >> 3) & 7)) << 4);
  const char* Asrc = (const char*)A + (size_t)(bm + (l >> 3)) * 1024 + sp;
  const char* Bhs = (const char*)Wh + (size_t)(bn + (l >> 3)) * 1024 + sp;
  const char* Bls = (const char*)Wl + (size_t)(bn + (l >> 3)) * 1024 + sp;

  const int lrow = l & 15, lk = l >> 4;
  const int wr = w >> 2, wc = w & 3;

  f32x4 acc[7][NFR] = {};
  f32x4 acc2[NPASS == 2 ? 7 : 1][NFR] = {};

  auto stage_a = [&](int buf, int t) {
    char* dst = lds + buf * PER_BUF;
    const char* src = Asrc + t * 128;
#pragma unroll
    for (int k = 0; k < 4; ++k) {
      const int i = w + k * 8;  // 28 chunks of 8 rows
      if (k < 3 || w < 4) gload16(src + (size_t)i * 8192, dst + i * 1024);
    }
  };
  auto stage_b = [&](int buf, int t) {
    char* dst = lds + buf * PER_BUF + A_BYTES;
#pragma unroll
    for (int k = 0; k < BN / 64; ++k) {
      const int i = w + k * 8;
      gload16(Bhs + t * 128 + (size_t)i * 8192, dst + i * 1024);
      if constexpr (NPASS == 2)
        gload16(Bls + t * 128 + (size_t)i * 8192, dst + BPL + i * 1024);
    }
  };

#define AFR(mi, kc) \
  ((wr * 112 + (mi)*16 + lrow) * 128 + ((((kc)*4 + lk) ^ (lrow & 7)) << 4))
#define BFR(ni, kc) \
  (A_BYTES + (wc * (BN / 4) + (ni)*16 + lrow) * 128 + ((((kc)*4 + lk) ^ (lrow & 7)) << 4))

#define KHALF(kc)                                                                \
  {                                                                              \
    short8 bh[NFR], bl2[NFR];                                                    \
    _Pragma("unroll") for (int ni = 0; ni < NFR; ++ni) {                         \
      bh[ni] = *(const short8*)(bp + BFR(ni, kc));                               \
      if constexpr (NPASS == 2) bl2[ni] = *(const short8*)(bp + BPL + BFR(ni, kc)); \
    }                                                                            \
    short8 ah[7];                                                                \
    _Pragma("unroll") for (int mi = 0; mi < 7; ++mi)                             \
        ah[mi] = *(const short8*)(bp + AFR(mi, kc));                             \
    __builtin_amdgcn_s_setprio(1);                                               \
    _Pragma("unroll") for (int mi = 0; mi < 7; ++mi)                             \
      _Pragma("unroll") for (int ni = 0; ni < NFR; ++ni)                         \
        acc[mi][ni] = __builtin_amdgcn_mfma_f32_16x16x32_f16(                    \
            __builtin_bit_cast(f16x8, ah[mi]), __builtin_bit_cast(f16x8, bh[ni]), \
            acc[mi][ni], 0, 0, 0);                                               \
    if constexpr (NPASS == 2) {                                                  \
      _Pragma("unroll") for (int mi = 0; mi < 7; ++mi)                           \
        _Pragma("unroll") for (int ni = 0; ni < NFR; ++ni)                       \
          acc2[mi][ni] = __builtin_amdgcn_mfma_f32_16x16x32_f16(                 \
              __builtin_bit_cast(f16x8, ah[mi]), __builtin_bit_cast(f16x8, bl2[ni]), \
              acc2[mi][ni], 0, 0, 0);                                            \
    }                                                                            \
    __builtin_amdgcn_s_setprio(0);                                               \
  }

  stage_a(0, 0);
  stage_b(0, 0);
  int cur = 0;
  for (int t = 0; t < 8; ++t) {
    asm volatile("s_waitcnt vmcnt(0)" ::: "memory");
    __builtin_amdgcn_s_barrier();
    asm volatile("" ::: "memory");
    const char* bp = lds + cur * PER_BUF;
    if (t < 7) stage_a(cur ^ 1, t + 1);
    KHALF(0)
    if (t < 7) stage_b(cur ^ 1, t + 1);
    KHALF(1)
    cur ^= 1;
  }
#undef KHALF
#undef AFR
#undef BFR

#pragma unroll
  for (int mi = 0; mi < 7; ++mi) {
    const int row = bm + wr * 112 + mi * 16 + lk * 4;
#pragma unroll
    for (int ni = 0; ni < NFR; ++ni) {
      const int col = bn + wc * (BN / 4) + ni * 16 + lrow;
      const float bc = bias[col];
#pragma unroll
      for (int j = 0; j < 4; ++j) {
        float vv = acc[mi][ni][j] + bc;
        if constexpr (NPASS == 2) vv += acc2[mi][ni][j] * (1.0f / 1024.0f);
        if constexpr (EPI == 0)
          outf[(size_t)(row + j) * N + col] = vv;
        else
          outh[(size_t)(row + j) * 512 + col] = f2h_bits(vv);
      }
    }
  }
}

// ---------------- stats reduce ----------------
__global__ __launch_bounds__(64) void reduce_stats(const float* __restrict__ part, int n,
                                                   const float* __restrict__ g,
                                                   const float* __restrict__ bb,
                                                   float* __restrict__ sv,
                                                   float* __restrict__ tv) {
  const int c = blockIdx.x, k = threadIdx.x;
  float sum = 0.f, sq = 0.f;
  for (int i = k; i < n; i += 64) {
    const float* p = part + (size_t)i * 1024;
    sum += p[c];
    sq += p[512 + c];
  }
#pragma unroll
  for (int o = 32; o; o >>= 1) {
    sum += __shfl_xor(sum, o);
    sq += __shfl_xor(sq, o);
  }
  if (k == 0) {
    const float mean = sum * (1.0f / 114688.0f);
    const float var = sq * (1.0f / 114688.0f) - mean * mean;
    const float sc = g[c] * rsqrtf(var + 1e-5f);
    sv[c] = sc;
    tv[c] = bb[c] - mean * sc;
  }
}

// ---------------- fused attention + residual + relu (+ stats), single fp16 plane ------------
template <bool STATS>
__global__ __launch_bounds__(256) void attn_relu(const float* __restrict__ qkf,
                                                 const uint16_t* __restrict__ V,
                                                 uint16_t* __restrict__ Hs,
                                                 const float* __restrict__ sv,
                                                 const float* __restrict__ tv,
                                                 float* __restrict__ part) {
  __shared__ float smS[4][512], smQ[4][512];
  const int w = threadIdx.x >> 6, l = threadIdx.x & 63;
  const int b = blockIdx.x * 4 + w;
  const size_t base = (size_t)b * 7;

  float qv[7], kv[7];
#pragma unroll
  for (int i = 0; i < 7; ++i) {
    qv[i] = qkf[(base + i) * 128 + l];
    kv[i] = qkf[(base + i) * 128 + 64 + l];
  }
  float att[7][7];
#pragma unroll
  for (int i = 0; i < 7; ++i)
#pragma unroll
    for (int j = 0; j < 7; ++j) {
      float p = qv[i] * kv[j];
#pragma unroll
      for (int o = 32; o; o >>= 1) p += __shfl_xor(p, o);
      att[i][j] = p;
    }
#pragma unroll
  for (int i = 0; i < 7; ++i) {
    float m = att[i][0];
#pragma unroll
    for (int j = 1; j < 7; ++j) m = fmaxf(m, att[i][j]);
    float sum = 0.f;
#pragma unroll
    for (int j = 0; j < 7; ++j) {
      att[i][j] = expf(att[i][j] - m);
      sum += att[i][j];
    }
    const float inv = 1.0f / sum;
#pragma unroll
    for (int j = 0; j < 7; ++j) att[i][j] *= inv;
  }

  const float4 s0 = *(const float4*)&sv[l * 8], s1 = *(const float4*)&sv[l * 8 + 4];
  const float4 t0 = *(const float4*)&tv[l * 8], t1 = *(const float4*)&tv[l * 8 + 4];
  const float sarr[8] = {s0.x, s0.y, s0.z, s0.w, s1.x, s1.y, s1.z, s1.w};
  const float tarr[8] = {t0.x, t0.y, t0.z, t0.w, t1.x, t1.y, t1.z, t1.w};

  uint4 vpk[7];
#pragma unroll
  for (int j = 0; j < 7; ++j)
    vpk[j] = *(const uint4*)((const char*)V + (base + j) * 1024 + l * 16);

  float s8[8] = {}, q8[8] = {};
#pragma unroll
  for (int i = 0; i < 7; ++i) {
    char* hp = (char*)Hs + (base + i) * 1024 + l * 16;
    uint4 hh = *(const uint4*)hp;
    float o[8] = {};
#pragma unroll
    for (int j = 0; j < 7; ++j) {
      const float a = att[i][j];
#pragma unroll
      for (int e = 0; e < 8; ++e) o[e] += a * g16(vpk[j], e);
    }
    uint16_t oh[8];
#pragma unroll
    for (int e = 0; e < 8; ++e) {
      const float xn = g16(hh, e) * sarr[e] + tarr[e];
      const float rr = fmaxf(o[e] + xn, 0.f);
      if constexpr (STATS) { s8[e] += rr; q8[e] += rr * rr; }
      oh[e] = f2h_bits(rr);
    }
    uint4 ph;
#pragma unroll
    for (int k2 = 0; k2 < 4; ++k2)
      ((uint32_t*)&ph)[k2] = (uint32_t)oh[2 * k2] | ((uint32_t)oh[2 * k2 + 1] << 16);
    *(uint4*)hp = ph;
  }

  if constexpr (STATS) {
#pragma unroll
    for (int e = 0; e < 8; ++e) {
      smS[w][l * 8 + e] = s8[e];
      smQ[w][l * 8 + e] = q8[e];
    }
    __syncthreads();
    const int c = threadIdx.x * 2;
#pragma unroll
    for (int cc = 0; cc < 2; ++cc) {
      const int c2 = c + cc;
      part[(size_t)blockIdx.x * 1024 + c2] =
          smS[0][c2] + smS[1][c2] + smS[2][c2] + smS[3][c2];
      part[(size_t)blockIdx.x * 1024 + 512 + c2] =
          smQ[0][c2] + smQ[1][c2] + smQ[2][c2] + smQ[3][c2];
    }
  }
}

extern "C" void kernel_launch(void* const* d_in, const int* in_sizes, int n_in,
                              void* d_out, int out_size, void* d_ws, size_t ws_size,
                              hipStream_t stream) {
  const float* x  = (const float*)d_in[0];
  const float* Wt = (const float*)d_in[1];
  const float* bt = (const float*)d_in[2];
  const float *bng[3], *bnb[3], *Wq[3], *bq[3], *Wk[3], *bk[3], *Wv[3], *bv[3], *gam[3];
  for (int i = 0; i < 3; ++i) {
    int o = 3 + 9 * i;
    bng[i] = (const float*)d_in[o + 0];
    bnb[i] = (const float*)d_in[o + 1];
    Wq[i]  = (const float*)d_in[o + 2];
    bq[i]  = (const float*)d_in[o + 3];
    Wk[i]  = (const float*)d_in[o + 4];
    bk[i]  = (const float*)d_in[o + 5];
    Wv[i]  = (const float*)d_in[o + 6];
    bv[i]  = (const float*)d_in[o + 7];
    gam[i] = (const float*)d_in[o + 8];
  }
  const float* Wb = (const float*)d_in[30];
  const float* bb = (const float*)d_in[31];

  char* ws = (char*)d_ws;
  uint16_t* Hs    = (uint16_t*)(ws);                  // 117,440,512 (114688 x 1KB)
  uint16_t* V     = (uint16_t*)(ws + 117440512);      // 117,440,512
  float*    part  = (float*)(ws + 234881024);         // 16,777,216
  float*    sv    = (float*)(ws + 251658240);         // 2,048
  float*    tv    = (float*)(ws + 251660288);         // 2,048
  uint16_t* WqkH  = (uint16_t*)(ws + 251662336);      // 131,072
  uint16_t* WqkL  = (uint16_t*)(ws + 251793408);      // 131,072
  float*    bqkf  = (float*)(ws + 251924480);         // 2,048
  uint16_t* WvH   = (uint16_t*)(ws + 251926528);      // 524,288
  float*    bvf   = (float*)(ws + 252450816);         // 2,048
  char*     WtIo  = ws + 252452864;                   // 1,048,576
  float*    btf   = (float*)(ws + 253501440);         // 2,048
  uint16_t* WbH   = (uint16_t*)(ws + 253503488);      // 262,144
  float*    qkf   = (float*)d_out;                    // 58.7 MB <= out bytes

  // weight prep
  cvt4h<<<128, 256, 0, stream>>>(Wb, WbH, 32768);
  fold_w_io<<<512, 512, 0, stream>>>(Wt, bt, WtIo, btf);

  // h0 = x @ Wt.T + bt  (bf16 3-pass exact-grade; fp16 plane out + stats)
  gemm1<<<dim3(2, 512), 512, 0, stream>>>((const char*)x, WtIo, btf, Hs, part);

  for (int i = 0; i < 3; ++i) {
    reduce_stats<<<512, 64, 0, stream>>>(part, i == 0 ? 512 : 4096,
                                         bng[i], bnb[i], sv, tv);
    fold_w_plane<<<64, 512, 0, stream>>>(Wq[i], bq[i], sv, tv, nullptr,
                                         WqkH, WqkL, bqkf);
    fold_w_plane<<<64, 512, 0, stream>>>(Wk[i], bk[i], sv, tv, nullptr,
                                         WqkH + (size_t)64 * 512, WqkL + (size_t)64 * 512,
                                         bqkf + 64);
    fold_w_plane<<<512, 512, 0, stream>>>(Wv[i], bv[i], sv, tv, gam[i],
                                          WvH, nullptr, bvf);
    // q|k = h @ Wqk'.T + b'  (W-pair 2-pass, lo x1024 -> acc2; f32 out on d_out)
    sgemm64<0, 2, 128><<<dim3(1, 512), 512, 0, stream>>>(Hs, WqkH, WqkL, bqkf,
                                                         qkf, nullptr, 128);
    // v' = h @ (gam*Wv*s)'.T + b''  (1-pass fp16; fp16 plane out)
    sgemm64<2, 1, 256><<<dim3(2, 512), 512, 0, stream>>>(Hs, WvH, nullptr, bvf,
                                                         nullptr, V, 512);
    // h = relu(att@v' + h*s + t) in place (+ stats partials for next layer)
    if (i < 2)
      attn_relu<true><<<4096, 256, 0, stream>>>(qkf, V, Hs, sv, tv, part);
    else
      attn_relu<false><<<4096, 256, 0, stream>>>(qkf, V, Hs, sv, tv, nullptr);
  }

  // out = h3 @ Wb.T + bb  (1-pass fp16; f32 out)
  sgemm64<0, 1, 256><<<dim3(1, 512), 512, 0, stream>>>(Hs, WbH, nullptr, bb,
                                                       (float*)d_out, nullptr, 256);
}

// Round 14
// 954.126 us; speedup vs baseline: 3.0378x; 1.2108x over previous
//
#include <hip/hip_runtime.h>
#include <hip/hip_bf16.h>
#include <stdint.h>

// LevelReasoning on MI355X — round 14: fuse qk-GEMM + attention.
// r13 base (single-fp16 h, BK=64). New qkattn kernel: sgemm64<NPASS=2,BN=128>
// main loop, then q|k -> LDS f32 (114KB, reuses GEMM dbuf region), then per-wave
// attention (4 groups/wave) + residual + relu + stats, all in one dispatch.
// Removes qkf global traffic (2x58MB/layer) + attn dispatch + 4096-row partials.

using bf16 = __hip_bfloat16;
typedef __attribute__((ext_vector_type(8))) short short8;
typedef __attribute__((ext_vector_type(4))) float f32x4;
typedef _Float16 f16x8 __attribute__((ext_vector_type(8)));

__device__ inline uint16_t f2b_bits(float f) {
  bf16 h = __float2bfloat16(f);
  return __builtin_bit_cast(uint16_t, h);
}
__device__ inline float b2f_bits(uint16_t u) { return __uint_as_float(((uint32_t)u) << 16); }
__device__ inline void split2(float v, uint16_t& hi, uint16_t& lo) {
  hi = f2b_bits(v);
  lo = f2b_bits(v - b2f_bits(hi));
}
__device__ inline uint16_t f2h_bits(float f) {
  _Float16 h = (_Float16)f;
  return __builtin_bit_cast(uint16_t, h);
}
__device__ inline float h2f_bits(uint16_t u) {
  return (float)__builtin_bit_cast(_Float16, u);
}
__device__ inline float g16(const uint4& u, int e) {
  uint32_t wrd = ((const uint32_t*)&u)[e >> 1];
  return h2f_bits((uint16_t)((e & 1) ? (wrd >> 16) : (wrd & 0xffffu)));
}

typedef const __attribute__((address_space(1))) void* gas_ptr;
typedef __attribute__((address_space(3))) void* las_ptr;
__device__ inline void gload16(const void* g, void* l) {
  __builtin_amdgcn_global_load_lds((gas_ptr)g, (las_ptr)l, 16, 0, 0);
}

// ---------------- f32 -> fp16 plain (Wb) ----------------
__global__ __launch_bounds__(256) void cvt4h(const float* __restrict__ in,
                                             uint16_t* __restrict__ out, int n4) {
  int i = blockIdx.x * 256 + threadIdx.x;
  const int stride = gridDim.x * 256;
  for (; i < n4; i += stride) {
    float4 v = ((const float4*)in)[i];
    uint32_t lo = (uint32_t)f2h_bits(v.x) | ((uint32_t)f2h_bits(v.y) << 16);
    uint32_t hi = (uint32_t)f2h_bits(v.z) | ((uint32_t)f2h_bits(v.w) << 16);
    ((uint2*)out)[i] = make_uint2(lo, hi);
  }
}

// ------- fold Wt to bf16-pair io (2KB rows) for gemm1 -------
__global__ __launch_bounds__(512) void fold_w_io(const float* __restrict__ Wsrc,
                                                 const float* __restrict__ bsrc,
                                                 char* __restrict__ Wio,
                                                 float* __restrict__ bout) {
  const int row = blockIdx.x, c = threadIdx.x;
  const float wv = Wsrc[(size_t)row * 512 + c];
  uint16_t hb, lb;
  split2(wv, hb, lb);
  char* p = Wio + (size_t)row * 2048 + (c >> 3) * 32 + (c & 7) * 2;
  *(uint16_t*)p = hb;
  *(uint16_t*)(p + 16) = lb;
  if (c == 0) bout[row] = bsrc[row];
}

// ------- fold W to fp16 plane(s): Wh = f16(g*W*s), Wl = f16((..-Wh)*1024) -------
__global__ __launch_bounds__(512) void fold_w_plane(const float* __restrict__ Wsrc,
                                                    const float* __restrict__ bsrc,
                                                    const float* __restrict__ sv,
                                                    const float* __restrict__ tv,
                                                    const float* __restrict__ gamp,
                                                    uint16_t* __restrict__ Wh,
                                                    uint16_t* __restrict__ Wl,
                                                    float* __restrict__ bout) {
  const int row = blockIdx.x, c = threadIdx.x;
  __shared__ float red[512];
  const float wv = Wsrc[(size_t)row * 512 + c];
  const float g = gamp ? gamp[0] : 1.0f;
  const float fv = g * wv * sv[c];
  const uint16_t hb = f2h_bits(fv);
  Wh[(size_t)row * 512 + c] = hb;
  if (Wl) Wl[(size_t)row * 512 + c] = f2h_bits((fv - h2f_bits(hb)) * 1024.0f);
  red[c] = wv * tv[c];
  __syncthreads();
#pragma unroll
  for (int off = 256; off > 0; off >>= 1) {
    if (c < off) red[c] += red[c + off];
    __syncthreads();
  }
  if (c == 0) bout[row] = g * (bsrc[row] + red[0]);
}

// ---------------- gemm1: h0 = x @ Wt.T + bt (bf16 3-pass, fp16-plane out + stats) ---------
__global__ __launch_bounds__(512, 1) void gemm1(const char* __restrict__ A,
                                                const char* __restrict__ Wio,
                                                const float* __restrict__ bias,
                                                uint16_t* __restrict__ outh,
                                                float* __restrict__ part) {
  constexpr int A_BYTES = 224 * 128;
  constexpr int PER_BUF = A_BYTES + 256 * 128;
  __shared__ __align__(16) char lds[2 * PER_BUF];
  __shared__ float sred[2][2][256];
  const int tid = threadIdx.x, w = tid >> 6, l = tid & 63;

  const int nwgx = gridDim.x;
  const int raw = blockIdx.y * nwgx + blockIdx.x;
  const int cpx = (nwgx * gridDim.y) >> 3;
  const int work = (raw & 7) * cpx + (raw >> 3);
  const int bmidx = work / nwgx;
  const int bm = bmidx * 224;
  const int bn = (work % nwgx) * 256;

  const int ssl = ((((l >> 1) & 3) ^ ((l >> 3) & 3)) << 5) | (((l & 1) ^ ((l >> 5) & 1)) << 4);
  const char* Asrc = A + (size_t)(bm + (l >> 3)) * 2048 + ssl;
  const char* Bsrc = Wio + (size_t)(bn + (l >> 3)) * 2048 + ssl;

  const int lrow = l & 15, lk = l >> 4;
  const int wr = w >> 2, wc = w & 3;
  const int sw32 = (lk ^ (lrow & 3)) * 32;
  const int hi16 = ((lrow >> 2) & 1) * 16;
  const int afr = (wr * 112 + lrow) * 128 + sw32;
  const int bfr = A_BYTES + (wc * 64 + lrow) * 128 + sw32;

  f32x4 acc[7][4] = {};

  auto stage_a = [&](int buf, int t) {
    char* dst = lds + buf * PER_BUF;
    const char* src = Asrc + (size_t)t * 128;
#pragma unroll
    for (int k = 0; k < 4; ++k) {
      const int i = w + k * 8;
      if (k < 3 || w < 4) gload16(src + (size_t)i * 16384, dst + i * 1024);
    }
  };
  auto stage_b = [&](int buf, int t) {
    char* dst = lds + buf * PER_BUF + A_BYTES;
    const char* src = Bsrc + (size_t)t * 128;
#pragma unroll
    for (int k = 0; k < 4; ++k) {
      const int i = w + k * 8;
      gload16(src + (size_t)i * 16384, dst + i * 1024);
    }
  };

#define LOADA(BASE, CNT)                                                         \
  {                                                                              \
    _Pragma("unroll") for (int u = 0; u < (CNT); ++u) {                          \
      const int mi = (BASE) + u;                                                 \
      float4 f0 = *(const float4*)(bp + afr + mi * 2048 + hi16);                 \
      float4 f1 = *(const float4*)(bp + afr + mi * 2048 + (hi16 ^ 16));          \
      const float fv[8] = {f0.x, f0.y, f0.z, f0.w, f1.x, f1.y, f1.z, f1.w};      \
      _Pragma("unroll") for (int e = 0; e < 8; ++e) {                            \
        uint16_t hb, lb;                                                         \
        split2(fv[e], hb, lb);                                                   \
        ah[u][e] = (short)hb;                                                    \
        al[u][e] = (short)lb;                                                    \
      }                                                                          \
    }                                                                            \
  }

#define MFMAC(BASE, CNT)                                                         \
  {                                                                              \
    __builtin_amdgcn_s_setprio(1);                                               \
    _Pragma("unroll") for (int u = 0; u < (CNT); ++u)                            \
      _Pragma("unroll") for (int ni = 0; ni < 4; ++ni)                           \
        acc[(BASE) + u][ni] = __builtin_amdgcn_mfma_f32_16x16x32_bf16(           \
            ah[u], bh[ni], acc[(BASE) + u][ni], 0, 0, 0);                        \
    _Pragma("unroll") for (int u = 0; u < (CNT); ++u)                            \
      _Pragma("unroll") for (int ni = 0; ni < 4; ++ni)                           \
        acc[(BASE) + u][ni] = __builtin_amdgcn_mfma_f32_16x16x32_bf16(           \
            ah[u], bl[ni], acc[(BASE) + u][ni], 0, 0, 0);                        \
    _Pragma("unroll") for (int u = 0; u < (CNT); ++u)                            \
      _Pragma("unroll") for (int ni = 0; ni < 4; ++ni)                           \
        acc[(BASE) + u][ni] = __builtin_amdgcn_mfma_f32_16x16x32_bf16(           \
            al[u], bh[ni], acc[(BASE) + u][ni], 0, 0, 0);                        \
    __builtin_amdgcn_s_setprio(0);                                               \
  }

  stage_a(0, 0);
  stage_b(0, 0);
  int cur = 0;
#pragma unroll 2
  for (int t = 0; t < 16; ++t) {
    asm volatile("s_waitcnt vmcnt(0)" ::: "memory");
    __builtin_amdgcn_s_barrier();
    asm volatile("" ::: "memory");

    const char* bp = lds + cur * PER_BUF;
    if (t < 15) stage_a(cur ^ 1, t + 1);

    short8 bh[4], bl[4];
#pragma unroll
    for (int ni = 0; ni < 4; ++ni) {
      bh[ni] = *(const short8*)(bp + bfr + ni * 2048 + hi16);
      bl[ni] = *(const short8*)(bp + bfr + ni * 2048 + (hi16 ^ 16));
    }
    short8 ah[4], al[4];
    LOADA(0, 4)
    MFMAC(0, 4)
    if (t < 15) stage_b(cur ^ 1, t + 1);
    LOADA(4, 3)
    MFMAC(4, 3)
    cur ^= 1;
  }
#undef LOADA
#undef MFMAC

  float sni[4] = {}, qni[4] = {};
#pragma unroll
  for (int mi = 0; mi < 7; ++mi) {
    const int row = bm + wr * 112 + mi * 16 + lk * 4;
#pragma unroll
    for (int ni = 0; ni < 4; ++ni) {
      const int col = bn + wc * 64 + ni * 16 + lrow;
      const float bc = bias[col];
#pragma unroll
      for (int j = 0; j < 4; ++j) {
        const float vv = acc[mi][ni][j] + bc;
        outh[(size_t)(row + j) * 512 + col] = f2h_bits(vv);
        sni[ni] += vv;
        qni[ni] += vv * vv;
      }
    }
  }
#pragma unroll
  for (int ni = 0; ni < 4; ++ni) {
    float s = sni[ni], q = qni[ni];
    s += __shfl_xor(s, 16); q += __shfl_xor(q, 16);
    s += __shfl_xor(s, 32); q += __shfl_xor(q, 32);
    if (lk == 0) {
      sred[0][wr][wc * 64 + ni * 16 + lrow] = s;
      sred[1][wr][wc * 64 + ni * 16 + lrow] = q;
    }
  }
  __syncthreads();
  if (tid < 256) {
    part[(size_t)bmidx * 1024 + bn + tid] = sred[0][0][tid] + sred[0][1][tid];
    part[(size_t)bmidx * 1024 + 512 + bn + tid] = sred[1][0][tid] + sred[1][1][tid];
  }
}

// ---------------- sgemm64: fp16 A-plane, BK=64 (v-GEMM and final) ----------------
// NPASS 1: W single plane. EPI 0: f32 out pitch N. EPI 2: fp16 plane out pitch 512.
template <int EPI, int BN>
__global__ __launch_bounds__(512, 1) void sgemm64(const uint16_t* __restrict__ A,
                                                  const uint16_t* __restrict__ Wh,
                                                  const float* __restrict__ bias,
                                                  float* __restrict__ outf,
                                                  uint16_t* __restrict__ outh, int N) {
  constexpr int NFR = BN / 64;
  constexpr int A_BYTES = 224 * 128;
  constexpr int PER_BUF = A_BYTES + BN * 128;
  __shared__ __align__(16) char lds[2 * PER_BUF];
  const int tid = threadIdx.x, w = tid >> 6, l = tid & 63;

  const int nwgx = gridDim.x;
  const int raw = blockIdx.y * nwgx + blockIdx.x;
  const int cpx = (nwgx * gridDim.y) >> 3;
  const int work = (raw & 7) * cpx + (raw >> 3);
  const int bmidx = work / nwgx;
  const int bm = bmidx * 224;
  const int bn = (work % nwgx) * BN;

  const int sp = (((l & 7) ^ ((l >> 3) & 7)) << 4);
  const char* Asrc = (const char*)A + (size_t)(bm + (l >> 3)) * 1024 + sp;
  const char* Bhs = (const char*)Wh + (size_t)(bn + (l >> 3)) * 1024 + sp;

  const int lrow = l & 15, lk = l >> 4;
  const int wr = w >> 2, wc = w & 3;

  f32x4 acc[7][NFR] = {};

  auto stage_a = [&](int buf, int t) {
    char* dst = lds + buf * PER_BUF;
    const char* src = Asrc + t * 128;
#pragma unroll
    for (int k = 0; k < 4; ++k) {
      const int i = w + k * 8;
      if (k < 3 || w < 4) gload16(src + (size_t)i * 8192, dst + i * 1024);
    }
  };
  auto stage_b = [&](int buf, int t) {
    char* dst = lds + buf * PER_BUF + A_BYTES;
#pragma unroll
    for (int k = 0; k < BN / 64; ++k) {
      const int i = w + k * 8;
      gload16(Bhs + t * 128 + (size_t)i * 8192, dst + i * 1024);
    }
  };

#define AFR(mi, kc) \
  ((wr * 112 + (mi)*16 + lrow) * 128 + ((((kc)*4 + lk) ^ (lrow & 7)) << 4))
#define BFR(ni, kc) \
  (A_BYTES + (wc * (BN / 4) + (ni)*16 + lrow) * 128 + ((((kc)*4 + lk) ^ (lrow & 7)) << 4))

#define KHALF(kc)                                                                \
  {                                                                              \
    short8 bh[NFR];                                                              \
    _Pragma("unroll") for (int ni = 0; ni < NFR; ++ni)                           \
        bh[ni] = *(const short8*)(bp + BFR(ni, kc));                             \
    short8 ah[7];                                                                \
    _Pragma("unroll") for (int mi = 0; mi < 7; ++mi)                             \
        ah[mi] = *(const short8*)(bp + AFR(mi, kc));                             \
    __builtin_amdgcn_s_setprio(1);                                               \
    _Pragma("unroll") for (int mi = 0; mi < 7; ++mi)                             \
      _Pragma("unroll") for (int ni = 0; ni < NFR; ++ni)                         \
        acc[mi][ni] = __builtin_amdgcn_mfma_f32_16x16x32_f16(                    \
            __builtin_bit_cast(f16x8, ah[mi]), __builtin_bit_cast(f16x8, bh[ni]), \
            acc[mi][ni], 0, 0, 0);                                               \
    __builtin_amdgcn_s_setprio(0);                                               \
  }

  stage_a(0, 0);
  stage_b(0, 0);
  int cur = 0;
  for (int t = 0; t < 8; ++t) {
    asm volatile("s_waitcnt vmcnt(0)" ::: "memory");
    __builtin_amdgcn_s_barrier();
    asm volatile("" ::: "memory");
    const char* bp = lds + cur * PER_BUF;
    if (t < 7) stage_a(cur ^ 1, t + 1);
    KHALF(0)
    if (t < 7) stage_b(cur ^ 1, t + 1);
    KHALF(1)
    cur ^= 1;
  }
#undef KHALF
#undef AFR
#undef BFR

#pragma unroll
  for (int mi = 0; mi < 7; ++mi) {
    const int row = bm + wr * 112 + mi * 16 + lk * 4;
#pragma unroll
    for (int ni = 0; ni < NFR; ++ni) {
      const int col = bn + wc * (BN / 4) + ni * 16 + lrow;
      const float bc = bias[col];
#pragma unroll
      for (int j = 0; j < 4; ++j) {
        const float vv = acc[mi][ni][j] + bc;
        if constexpr (EPI == 0)
          outf[(size_t)(row + j) * N + col] = vv;
        else
          outh[(size_t)(row + j) * 512 + col] = f2h_bits(vv);
      }
    }
  }
}

// ---------------- qkattn: qk-GEMM (W-pair, acc2) + attention fused ----------------
template <bool STATS>
__global__ __launch_bounds__(512, 1) void qkattn(const uint16_t* __restrict__ A,
                                                 const uint16_t* __restrict__ Wh,
                                                 const uint16_t* __restrict__ Wl,
                                                 const float* __restrict__ bias,
                                                 const uint16_t* __restrict__ V,
                                                 uint16_t* __restrict__ Hs,
                                                 const float* __restrict__ sv,
                                                 const float* __restrict__ tv,
                                                 float* __restrict__ part) {
  constexpr int A_BYTES = 224 * 128;
  constexpr int BPL = 128 * 128;                 // 16384
  constexpr int PER_BUF = A_BYTES + 2 * BPL;     // 61440
  __shared__ __align__(16) char lds[131072];     // loop: 2*PER_BUF=122880 | attn: qk 114688 + sred 16384
  const int tid = threadIdx.x, w = tid >> 6, l = tid & 63;

  const int raw = blockIdx.y;                    // grid (1, 512)
  const int cpx = gridDim.y >> 3;
  const int bmidx = (raw & 7) * cpx + (raw >> 3);
  const int bm = bmidx * 224;

  const int sp = (((l & 7) ^ ((l >> 3) & 7)) << 4);
  const char* Asrc = (const char*)A + (size_t)(bm + (l >> 3)) * 1024 + sp;
  const char* Bhs = (const char*)Wh + (size_t)(l >> 3) * 1024 + sp;
  const char* Bls = (const char*)Wl + (size_t)(l >> 3) * 1024 + sp;

  const int lrow = l & 15, lk = l >> 4;
  const int wr = w >> 2, wc = w & 3;

  f32x4 acc[7][2] = {};
  f32x4 acc2[7][2] = {};

  auto stage_a = [&](int buf, int t) {
    char* dst = lds + buf * PER_BUF;
    const char* src = Asrc + t * 128;
#pragma unroll
    for (int k = 0; k < 4; ++k) {
      const int i = w + k * 8;
      if (k < 3 || w < 4) gload16(src + (size_t)i * 8192, dst + i * 1024);
    }
  };
  auto stage_b = [&](int buf, int t) {
    char* dst = lds + buf * PER_BUF + A_BYTES;
#pragma unroll
    for (int k = 0; k < 2; ++k) {
      const int i = w + k * 8;
      gload16(Bhs + t * 128 + (size_t)i * 8192, dst + i * 1024);
      gload16(Bls + t * 128 + (size_t)i * 8192, dst + BPL + i * 1024);
    }
  };

#define AFR(mi, kc) \
  ((wr * 112 + (mi)*16 + lrow) * 128 + ((((kc)*4 + lk) ^ (lrow & 7)) << 4))
#define BFR(ni, kc) \
  (A_BYTES + (wc * 32 + (ni)*16 + lrow) * 128 + ((((kc)*4 + lk) ^ (lrow & 7)) << 4))

#define KHALF(kc)                                                                \
  {                                                                              \
    short8 bh[2], bl2[2];                                                        \
    _Pragma("unroll") for (int ni = 0; ni < 2; ++ni) {                           \
      bh[ni] = *(const short8*)(bp + BFR(ni, kc));                               \
      bl2[ni] = *(const short8*)(bp + BPL + BFR(ni, kc));                        \
    }                                                                            \
    short8 ah[7];                                                                \
    _Pragma("unroll") for (int mi = 0; mi < 7; ++mi)                             \
        ah[mi] = *(const short8*)(bp + AFR(mi, kc));                             \
    __builtin_amdgcn_s_setprio(1);                                               \
    _Pragma("unroll") for (int mi = 0; mi < 7; ++mi)                             \
      _Pragma("unroll") for (int ni = 0; ni < 2; ++ni)                           \
        acc[mi][ni] = __builtin_amdgcn_mfma_f32_16x16x32_f16(                    \
            __builtin_bit_cast(f16x8, ah[mi]), __builtin_bit_cast(f16x8, bh[ni]), \
            acc[mi][ni], 0, 0, 0);                                               \
    _Pragma("unroll") for (int mi = 0; mi < 7; ++mi)                             \
      _Pragma("unroll") for (int ni = 0; ni < 2; ++ni)                           \
        acc2[mi][ni] = __builtin_amdgcn_mfma_f32_16x16x32_f16(                   \
            __builtin_bit_cast(f16x8, ah[mi]), __builtin_bit_cast(f16x8, bl2[ni]), \
            acc2[mi][ni], 0, 0, 0);                                              \
    __builtin_amdgcn_s_setprio(0);                                               \
  }

  stage_a(0, 0);
  stage_b(0, 0);
  int cur = 0;
  for (int t = 0; t < 8; ++t) {
    asm volatile("s_waitcnt vmcnt(0)" ::: "memory");
    __builtin_amdgcn_s_barrier();
    asm volatile("" ::: "memory");
    const char* bp = lds + cur * PER_BUF;
    if (t < 7) stage_a(cur ^ 1, t + 1);
    KHALF(0)
    if (t < 7) stage_b(cur ^ 1, t + 1);
    KHALF(1)
    cur ^= 1;
  }
#undef KHALF
#undef AFR
#undef BFR

  // ---- phase 2: q|k -> LDS f32, then attention ----
  __syncthreads();  // all waves done reading LDS tiles
  float* qk = (float*)lds;  // [224][128]
#pragma unroll
  for (int mi = 0; mi < 7; ++mi) {
    const int rl = wr * 112 + mi * 16 + lk * 4;
#pragma unroll
    for (int ni = 0; ni < 2; ++ni) {
      const int col = wc * 32 + ni * 16 + lrow;
      const float bc = bias[col];
#pragma unroll
      for (int j = 0; j < 4; ++j)
        qk[(rl + j) * 128 + col] = acc[mi][ni][j] + bc + acc2[mi][ni][j] * (1.0f / 1024.0f);
    }
  }
  __syncthreads();

  const float4 s0 = *(const float4*)&sv[l * 8], s1 = *(const float4*)&sv[l * 8 + 4];
  const float4 t0 = *(const float4*)&tv[l * 8], t1 = *(const float4*)&tv[l * 8 + 4];
  const float sarr[8] = {s0.x, s0.y, s0.z, s0.w, s1.x, s1.y, s1.z, s1.w};
  const float tarr[8] = {t0.x, t0.y, t0.z, t0.w, t1.x, t1.y, t1.z, t1.w};

  float s8[8] = {}, q8[8] = {};
#pragma unroll
  for (int gg = 0; gg < 4; ++gg) {
    const int g = w * 4 + gg;
    const int rl = g * 7;
    const size_t base = (size_t)bm + rl;

    float qv[7], kv[7];
#pragma unroll
    for (int i = 0; i < 7; ++i) {
      qv[i] = qk[(rl + i) * 128 + l];
      kv[i] = qk[(rl + i) * 128 + 64 + l];
    }
    float att[7][7];
#pragma unroll
    for (int i = 0; i < 7; ++i)
#pragma unroll
      for (int j = 0; j < 7; ++j) {
        float p = qv[i] * kv[j];
#pragma unroll
        for (int o = 32; o; o >>= 1) p += __shfl_xor(p, o);
        att[i][j] = p;
      }
#pragma unroll
    for (int i = 0; i < 7; ++i) {
      float m = att[i][0];
#pragma unroll
      for (int j = 1; j < 7; ++j) m = fmaxf(m, att[i][j]);
      float sum = 0.f;
#pragma unroll
      for (int j = 0; j < 7; ++j) {
        att[i][j] = expf(att[i][j] - m);
        sum += att[i][j];
      }
      const float inv = 1.0f / sum;
#pragma unroll
      for (int j = 0; j < 7; ++j) att[i][j] *= inv;
    }

    uint4 vpk[7];
#pragma unroll
    for (int j = 0; j < 7; ++j)
      vpk[j] = *(const uint4*)((const char*)V + (base + j) * 1024 + l * 16);

#pragma unroll
    for (int i = 0; i < 7; ++i) {
      char* hp = (char*)Hs + (base + i) * 1024 + l * 16;
      uint4 hh = *(const uint4*)hp;
      float o[8] = {};
#pragma unroll
      for (int j = 0; j < 7; ++j) {
        const float a = att[i][j];
#pragma unroll
        for (int e = 0; e < 8; ++e) o[e] += a * g16(vpk[j], e);
      }
      uint16_t oh[8];
#pragma unroll
      for (int e = 0; e < 8; ++e) {
        const float xn = g16(hh, e) * sarr[e] + tarr[e];
        const float rr = fmaxf(o[e] + xn, 0.f);
        if constexpr (STATS) { s8[e] += rr; q8[e] += rr * rr; }
        oh[e] = f2h_bits(rr);
      }
      uint4 ph;
#pragma unroll
      for (int k2 = 0; k2 < 4; ++k2)
        ((uint32_t*)&ph)[k2] = (uint32_t)oh[2 * k2] | ((uint32_t)oh[2 * k2 + 1] << 16);
      *(uint4*)hp = ph;
    }
  }

  if constexpr (STATS) {
    float* sred = (float*)(lds + 114688);  // [8][512]
#pragma unroll
    for (int e = 0; e < 8; ++e) sred[w * 512 + l * 8 + e] = s8[e];
    __syncthreads();
    {
      float sum = 0.f;
#pragma unroll
      for (int ww = 0; ww < 8; ++ww) sum += sred[ww * 512 + tid];
      part[(size_t)bmidx * 1024 + tid] = sum;
    }
    __syncthreads();
#pragma unroll
    for (int e = 0; e < 8; ++e) sred[w * 512 + l * 8 + e] = q8[e];
    __syncthreads();
    {
      float sum = 0.f;
#pragma unroll
      for (int ww = 0; ww < 8; ++ww) sum += sred[ww * 512 + tid];
      part[(size_t)bmidx * 1024 + 512 + tid] = sum;
    }
  }
}

// ---------------- stats reduce ----------------
__global__ __launch_bounds__(64) void reduce_stats(const float* __restrict__ part, int n,
                                                   const float* __restrict__ g,
                                                   const float* __restrict__ bb,
                                                   float* __restrict__ sv,
                                                   float* __restrict__ tv) {
  const int c = blockIdx.x, k = threadIdx.x;
  float sum = 0.f, sq = 0.f;
  for (int i = k; i < n; i += 64) {
    const float* p = part + (size_t)i * 1024;
    sum += p[c];
    sq += p[512 + c];
  }
#pragma unroll
  for (int o = 32; o; o >>= 1) {
    sum += __shfl_xor(sum, o);
    sq += __shfl_xor(sq, o);
  }
  if (k == 0) {
    const float mean = sum * (1.0f / 114688.0f);
    const float var = sq * (1.0f / 114688.0f) - mean * mean;
    const float sc = g[c] * rsqrtf(var + 1e-5f);
    sv[c] = sc;
    tv[c] = bb[c] - mean * sc;
  }
}

extern "C" void kernel_launch(void* const* d_in, const int* in_sizes, int n_in,
                              void* d_out, int out_size, void* d_ws, size_t ws_size,
                              hipStream_t stream) {
  const float* x  = (const float*)d_in[0];
  const float* Wt = (const float*)d_in[1];
  const float* bt = (const float*)d_in[2];
  const float *bng[3], *bnb[3], *Wq[3], *bq[3], *Wk[3], *bk[3], *Wv[3], *bv[3], *gam[3];
  for (int i = 0; i < 3; ++i) {
    int o = 3 + 9 * i;
    bng[i] = (const float*)d_in[o + 0];
    bnb[i] = (const float*)d_in[o + 1];
    Wq[i]  = (const float*)d_in[o + 2];
    bq[i]  = (const float*)d_in[o + 3];
    Wk[i]  = (const float*)d_in[o + 4];
    bk[i]  = (const float*)d_in[o + 5];
    Wv[i]  = (const float*)d_in[o + 6];
    bv[i]  = (const float*)d_in[o + 7];
    gam[i] = (const float*)d_in[o + 8];
  }
  const float* Wb = (const float*)d_in[30];
  const float* bb = (const float*)d_in[31];

  char* ws = (char*)d_ws;
  uint16_t* Hs    = (uint16_t*)(ws);                  // 117,440,512
  uint16_t* V     = (uint16_t*)(ws + 117440512);      // 117,440,512
  float*    part  = (float*)(ws + 234881024);         // 2,097,152 (512 x 1024)
  float*    sv    = (float*)(ws + 236978176);         // 2,048
  float*    tv    = (float*)(ws + 236980224);         // 2,048
  uint16_t* WqkH  = (uint16_t*)(ws + 236982272);      // 131,072
  uint16_t* WqkL  = (uint16_t*)(ws + 237113344);      // 131,072
  float*    bqkf  = (float*)(ws + 237244416);         // 2,048
  uint16_t* WvH   = (uint16_t*)(ws + 237246464);      // 524,288
  float*    bvf   = (float*)(ws + 237770752);         // 2,048
  char*     WtIo  = ws + 237772800;                   // 1,048,576
  float*    btf   = (float*)(ws + 238821376);         // 2,048
  uint16_t* WbH   = (uint16_t*)(ws + 238823424);      // 262,144
  // weight prep
  cvt4h<<<128, 256, 0, stream>>>(Wb, WbH, 32768);
  fold_w_io<<<512, 512, 0, stream>>>(Wt, bt, WtIo, btf);

  // h0 = x @ Wt.T + bt  (bf16 3-pass exact-grade; fp16 plane out + stats)
  gemm1<<<dim3(2, 512), 512, 0, stream>>>((const char*)x, WtIo, btf, Hs, part);

  for (int i = 0; i < 3; ++i) {
    reduce_stats<<<512, 64, 0, stream>>>(part, 512, bng[i], bnb[i], sv, tv);
    fold_w_plane<<<64, 512, 0, stream>>>(Wq[i], bq[i], sv, tv, nullptr,
                                         WqkH, WqkL, bqkf);
    fold_w_plane<<<64, 512, 0, stream>>>(Wk[i], bk[i], sv, tv, nullptr,
                                         WqkH + (size_t)64 * 512, WqkL + (size_t)64 * 512,
                                         bqkf + 64);
    fold_w_plane<<<512, 512, 0, stream>>>(Wv[i], bv[i], sv, tv, gam[i],
                                          WvH, nullptr, bvf);
    // v' = h @ (gam*Wv*s)'.T + b''  (1-pass fp16; fp16 plane out)
    sgemm64<2, 256><<<dim3(2, 512), 512, 0, stream>>>(Hs, WvH, bvf, nullptr, V, 512);
    // fused: q|k GEMM (W-pair, acc2) -> LDS -> attention + residual + relu (+ stats)
    if (i < 2)
      qkattn<true><<<dim3(1, 512), 512, 0, stream>>>(Hs, WqkH, WqkL, bqkf, V, Hs,
                                                     sv, tv, part);
    else
      qkattn<false><<<dim3(1, 512), 512, 0, stream>>>(Hs, WqkH, WqkL, bqkf, V, Hs,
                                                      sv, tv, nullptr);
  }

  // out = h3 @ Wb.T + bb  (1-pass fp16; f32 out)
  sgemm64<0, 256><<<dim3(1, 512), 512, 0, stream>>>(Hs, WbH, bb, (float*)d_out,
                                                    nullptr, 256);
}

// Round 15
// 945.955 us; speedup vs baseline: 3.0641x; 1.0086x over previous
//
#include <hip/hip_runtime.h>
#include <hip/hip_bf16.h>
#include <stdint.h>

// LevelReasoning on MI355X — round 15: v-GEMM single-A-read (BM=112, BN=512).
// r14 base. New sgemmV: BM=112 BN=512 BK=64, 8 waves 1x8 (wave 112rows x 64cols),
// acc[7][4], LDS 156KB, grid (1,1024) — each Hs row read ONCE (A traffic halved;
// B is 0.5MB L2-hot). fold_w_plane x3 fused into fold_all. Rest identical to r14.

using bf16 = __hip_bfloat16;
typedef __attribute__((ext_vector_type(8))) short short8;
typedef __attribute__((ext_vector_type(4))) float f32x4;
typedef _Float16 f16x8 __attribute__((ext_vector_type(8)));

__device__ inline uint16_t f2b_bits(float f) {
  bf16 h = __float2bfloat16(f);
  return __builtin_bit_cast(uint16_t, h);
}
__device__ inline float b2f_bits(uint16_t u) { return __uint_as_float(((uint32_t)u) << 16); }
__device__ inline void split2(float v, uint16_t& hi, uint16_t& lo) {
  hi = f2b_bits(v);
  lo = f2b_bits(v - b2f_bits(hi));
}
__device__ inline uint16_t f2h_bits(float f) {
  _Float16 h = (_Float16)f;
  return __builtin_bit_cast(uint16_t, h);
}
__device__ inline float h2f_bits(uint16_t u) {
  return (float)__builtin_bit_cast(_Float16, u);
}
__device__ inline float g16(const uint4& u, int e) {
  uint32_t wrd = ((const uint32_t*)&u)[e >> 1];
  return h2f_bits((uint16_t)((e & 1) ? (wrd >> 16) : (wrd & 0xffffu)));
}

typedef const __attribute__((address_space(1))) void* gas_ptr;
typedef __attribute__((address_space(3))) void* las_ptr;
__device__ inline void gload16(const void* g, void* l) {
  __builtin_amdgcn_global_load_lds((gas_ptr)g, (las_ptr)l, 16, 0, 0);
}

// ---------------- f32 -> fp16 plain (Wb) ----------------
__global__ __launch_bounds__(256) void cvt4h(const float* __restrict__ in,
                                             uint16_t* __restrict__ out, int n4) {
  int i = blockIdx.x * 256 + threadIdx.x;
  const int stride = gridDim.x * 256;
  for (; i < n4; i += stride) {
    float4 v = ((const float4*)in)[i];
    uint32_t lo = (uint32_t)f2h_bits(v.x) | ((uint32_t)f2h_bits(v.y) << 16);
    uint32_t hi = (uint32_t)f2h_bits(v.z) | ((uint32_t)f2h_bits(v.w) << 16);
    ((uint2*)out)[i] = make_uint2(lo, hi);
  }
}

// ------- fold Wt to bf16-pair io (2KB rows) for gemm1 -------
__global__ __launch_bounds__(512) void fold_w_io(const float* __restrict__ Wsrc,
                                                 const float* __restrict__ bsrc,
                                                 char* __restrict__ Wio,
                                                 float* __restrict__ bout) {
  const int row = blockIdx.x, c = threadIdx.x;
  const float wv = Wsrc[(size_t)row * 512 + c];
  uint16_t hb, lb;
  split2(wv, hb, lb);
  char* p = Wio + (size_t)row * 2048 + (c >> 3) * 32 + (c & 7) * 2;
  *(uint16_t*)p = hb;
  *(uint16_t*)(p + 16) = lb;
  if (c == 0) bout[row] = bsrc[row];
}

// ------- fused per-layer weight fold: Wq, Wk (pair, lo x1024), Wv (single, gamma) -------
__global__ __launch_bounds__(512) void fold_all(const float* __restrict__ Wq,
                                                const float* __restrict__ bq,
                                                const float* __restrict__ Wk,
                                                const float* __restrict__ bk,
                                                const float* __restrict__ Wv,
                                                const float* __restrict__ bv,
                                                const float* __restrict__ sv,
                                                const float* __restrict__ tv,
                                                const float* __restrict__ gamp,
                                                uint16_t* __restrict__ WqkH,
                                                uint16_t* __restrict__ WqkL,
                                                float* __restrict__ bqkf,
                                                uint16_t* __restrict__ WvH,
                                                float* __restrict__ bvf) {
  const int b = blockIdx.x, c = threadIdx.x;
  __shared__ float red[512];
  const float* Wsrc;
  const float* bsrc;
  uint16_t *Wh, *Wl;
  float* bout;
  float g;
  int row;
  if (b < 64) {
    Wsrc = Wq; bsrc = bq; Wh = WqkH; Wl = WqkL; bout = bqkf; g = 1.0f; row = b;
  } else if (b < 128) {
    Wsrc = Wk; bsrc = bk; Wh = WqkH + (size_t)64 * 512; Wl = WqkL + (size_t)64 * 512;
    bout = bqkf + 64; g = 1.0f; row = b - 64;
  } else {
    Wsrc = Wv; bsrc = bv; Wh = WvH; Wl = nullptr; bout = bvf; g = gamp[0]; row = b - 128;
  }
  const float wv = Wsrc[(size_t)row * 512 + c];
  const float fv = g * wv * sv[c];
  const uint16_t hb = f2h_bits(fv);
  Wh[(size_t)row * 512 + c] = hb;
  if (Wl) Wl[(size_t)row * 512 + c] = f2h_bits((fv - h2f_bits(hb)) * 1024.0f);
  red[c] = wv * tv[c];
  __syncthreads();
#pragma unroll
  for (int off = 256; off > 0; off >>= 1) {
    if (c < off) red[c] += red[c + off];
    __syncthreads();
  }
  if (c == 0) bout[row] = g * (bsrc[row] + red[0]);
}

// ---------------- gemm1: h0 = x @ Wt.T + bt (bf16 3-pass, fp16-plane out + stats) ---------
__global__ __launch_bounds__(512, 1) void gemm1(const char* __restrict__ A,
                                                const char* __restrict__ Wio,
                                                const float* __restrict__ bias,
                                                uint16_t* __restrict__ outh,
                                                float* __restrict__ part) {
  constexpr int A_BYTES = 224 * 128;
  constexpr int PER_BUF = A_BYTES + 256 * 128;
  __shared__ __align__(16) char lds[2 * PER_BUF];
  __shared__ float sred[2][2][256];
  const int tid = threadIdx.x, w = tid >> 6, l = tid & 63;

  const int nwgx = gridDim.x;
  const int raw = blockIdx.y * nwgx + blockIdx.x;
  const int cpx = (nwgx * gridDim.y) >> 3;
  const int work = (raw & 7) * cpx + (raw >> 3);
  const int bmidx = work / nwgx;
  const int bm = bmidx * 224;
  const int bn = (work % nwgx) * 256;

  const int ssl = ((((l >> 1) & 3) ^ ((l >> 3) & 3)) << 5) | (((l & 1) ^ ((l >> 5) & 1)) << 4);
  const char* Asrc = A + (size_t)(bm + (l >> 3)) * 2048 + ssl;
  const char* Bsrc = Wio + (size_t)(bn + (l >> 3)) * 2048 + ssl;

  const int lrow = l & 15, lk = l >> 4;
  const int wr = w >> 2, wc = w & 3;
  const int sw32 = (lk ^ (lrow & 3)) * 32;
  const int hi16 = ((lrow >> 2) & 1) * 16;
  const int afr = (wr * 112 + lrow) * 128 + sw32;
  const int bfr = A_BYTES + (wc * 64 + lrow) * 128 + sw32;

  f32x4 acc[7][4] = {};

  auto stage_a = [&](int buf, int t) {
    char* dst = lds + buf * PER_BUF;
    const char* src = Asrc + (size_t)t * 128;
#pragma unroll
    for (int k = 0; k < 4; ++k) {
      const int i = w + k * 8;
      if (k < 3 || w < 4) gload16(src + (size_t)i * 16384, dst + i * 1024);
    }
  };
  auto stage_b = [&](int buf, int t) {
    char* dst = lds + buf * PER_BUF + A_BYTES;
    const char* src = Bsrc + (size_t)t * 128;
#pragma unroll
    for (int k = 0; k < 4; ++k) {
      const int i = w + k * 8;
      gload16(src + (size_t)i * 16384, dst + i * 1024);
    }
  };

#define LOADA(BASE, CNT)                                                         \
  {                                                                              \
    _Pragma("unroll") for (int u = 0; u < (CNT); ++u) {                          \
      const int mi = (BASE) + u;                                                 \
      float4 f0 = *(const float4*)(bp + afr + mi * 2048 + hi16);                 \
      float4 f1 = *(const float4*)(bp + afr + mi * 2048 + (hi16 ^ 16));          \
      const float fv[8] = {f0.x, f0.y, f0.z, f0.w, f1.x, f1.y, f1.z, f1.w};      \
      _Pragma("unroll") for (int e = 0; e < 8; ++e) {                            \
        uint16_t hb, lb;                                                         \
        split2(fv[e], hb, lb);                                                   \
        ah[u][e] = (short)hb;                                                    \
        al[u][e] = (short)lb;                                                    \
      }                                                                          \
    }                                                                            \
  }

#define MFMAC(BASE, CNT)                                                         \
  {                                                                              \
    __builtin_amdgcn_s_setprio(1);                                               \
    _Pragma("unroll") for (int u = 0; u < (CNT); ++u)                            \
      _Pragma("unroll") for (int ni = 0; ni < 4; ++ni)                           \
        acc[(BASE) + u][ni] = __builtin_amdgcn_mfma_f32_16x16x32_bf16(           \
            ah[u], bh[ni], acc[(BASE) + u][ni], 0, 0, 0);                        \
    _Pragma("unroll") for (int u = 0; u < (CNT); ++u)                            \
      _Pragma("unroll") for (int ni = 0; ni < 4; ++ni)                           \
        acc[(BASE) + u][ni] = __builtin_amdgcn_mfma_f32_16x16x32_bf16(           \
            ah[u], bl[ni], acc[(BASE) + u][ni], 0, 0, 0);                        \
    _Pragma("unroll") for (int u = 0; u < (CNT); ++u)                            \
      _Pragma("unroll") for (int ni = 0; ni < 4; ++ni)                           \
        acc[(BASE) + u][ni] = __builtin_amdgcn_mfma_f32_16x16x32_bf16(           \
            al[u], bh[ni], acc[(BASE) + u][ni], 0, 0, 0);                        \
    __builtin_amdgcn_s_setprio(0);                                               \
  }

  stage_a(0, 0);
  stage_b(0, 0);
  int cur = 0;
#pragma unroll 2
  for (int t = 0; t < 16; ++t) {
    asm volatile("s_waitcnt vmcnt(0)" ::: "memory");
    __builtin_amdgcn_s_barrier();
    asm volatile("" ::: "memory");

    const char* bp = lds + cur * PER_BUF;
    if (t < 15) stage_a(cur ^ 1, t + 1);

    short8 bh[4], bl[4];
#pragma unroll
    for (int ni = 0; ni < 4; ++ni) {
      bh[ni] = *(const short8*)(bp + bfr + ni * 2048 + hi16);
      bl[ni] = *(const short8*)(bp + bfr + ni * 2048 + (hi16 ^ 16));
    }
    short8 ah[4], al[4];
    LOADA(0, 4)
    MFMAC(0, 4)
    if (t < 15) stage_b(cur ^ 1, t + 1);
    LOADA(4, 3)
    MFMAC(4, 3)
    cur ^= 1;
  }
#undef LOADA
#undef MFMAC

  float sni[4] = {}, qni[4] = {};
#pragma unroll
  for (int mi = 0; mi < 7; ++mi) {
    const int row = bm + wr * 112 + mi * 16 + lk * 4;
#pragma unroll
    for (int ni = 0; ni < 4; ++ni) {
      const int col = bn + wc * 64 + ni * 16 + lrow;
      const float bc = bias[col];
#pragma unroll
      for (int j = 0; j < 4; ++j) {
        const float vv = acc[mi][ni][j] + bc;
        outh[(size_t)(row + j) * 512 + col] = f2h_bits(vv);
        sni[ni] += vv;
        qni[ni] += vv * vv;
      }
    }
  }
#pragma unroll
  for (int ni = 0; ni < 4; ++ni) {
    float s = sni[ni], q = qni[ni];
    s += __shfl_xor(s, 16); q += __shfl_xor(q, 16);
    s += __shfl_xor(s, 32); q += __shfl_xor(q, 32);
    if (lk == 0) {
      sred[0][wr][wc * 64 + ni * 16 + lrow] = s;
      sred[1][wr][wc * 64 + ni * 16 + lrow] = q;
    }
  }
  __syncthreads();
  if (tid < 256) {
    part[(size_t)bmidx * 1024 + bn + tid] = sred[0][0][tid] + sred[0][1][tid];
    part[(size_t)bmidx * 1024 + 512 + bn + tid] = sred[1][0][tid] + sred[1][1][tid];
  }
}

// ---------------- sgemmV: v-GEMM, BM=112, BN=512, BK=64, A read once ----------------
__global__ __launch_bounds__(512, 1) void sgemmV(const uint16_t* __restrict__ A,
                                                 const uint16_t* __restrict__ Wh,
                                                 const float* __restrict__ bias,
                                                 uint16_t* __restrict__ outh) {
  constexpr int A_BYTES = 112 * 128;   // 14336
  constexpr int B_BYTES = 512 * 128;   // 65536
  constexpr int PER_BUF = A_BYTES + B_BYTES;  // 79872
  __shared__ __align__(16) char lds[2 * PER_BUF];  // 159744
  const int tid = threadIdx.x, w = tid >> 6, l = tid & 63;

  const int raw = blockIdx.y;          // grid (1, 1024)
  const int cpx = gridDim.y >> 3;
  const int bmidx = (raw & 7) * cpx + (raw >> 3);
  const int bm = bmidx * 112;

  const int sp = (((l & 7) ^ ((l >> 3) & 7)) << 4);
  const char* Asrc = (const char*)A + (size_t)(bm + (l >> 3)) * 1024 + sp;
  const char* Bhs = (const char*)Wh + (size_t)(l >> 3) * 1024 + sp;

  const int lrow = l & 15, lk = l >> 4;

  f32x4 acc[7][4] = {};

  auto stage_a = [&](int buf, int t) {
    char* dst = lds + buf * PER_BUF;
    const char* src = Asrc + t * 128;
#pragma unroll
    for (int k = 0; k < 2; ++k) {
      const int i = w + k * 8;  // 14 chunks of 8 rows
      if (k < 1 || w < 6) gload16(src + (size_t)i * 8192, dst + i * 1024);
    }
  };
  auto stage_b = [&](int buf, int t) {
    char* dst = lds + buf * PER_BUF + A_BYTES;
#pragma unroll
    for (int k = 0; k < 8; ++k) {  // 64 chunks of 8 rows
      const int i = w + k * 8;
      gload16(Bhs + t * 128 + (size_t)i * 8192, dst + i * 1024);
    }
  };

#define AFR(mi, kc) \
  (((mi)*16 + lrow) * 128 + ((((kc)*4 + lk) ^ (lrow & 7)) << 4))
#define BFR(ni, kc) \
  (A_BYTES + (w * 64 + (ni)*16 + lrow) * 128 + ((((kc)*4 + lk) ^ (lrow & 7)) << 4))

#define KHALF(kc)                                                                \
  {                                                                              \
    short8 bh[4];                                                                \
    _Pragma("unroll") for (int ni = 0; ni < 4; ++ni)                             \
        bh[ni] = *(const short8*)(bp + BFR(ni, kc));                             \
    short8 ah[7];                                                                \
    _Pragma("unroll") for (int mi = 0; mi < 7; ++mi)                             \
        ah[mi] = *(const short8*)(bp + AFR(mi, kc));                             \
    __builtin_amdgcn_s_setprio(1);                                               \
    _Pragma("unroll") for (int mi = 0; mi < 7; ++mi)                             \
      _Pragma("unroll") for (int ni = 0; ni < 4; ++ni)                           \
        acc[mi][ni] = __builtin_amdgcn_mfma_f32_16x16x32_f16(                    \
            __builtin_bit_cast(f16x8, ah[mi]), __builtin_bit_cast(f16x8, bh[ni]), \
            acc[mi][ni], 0, 0, 0);                                               \
    __builtin_amdgcn_s_setprio(0);                                               \
  }

  stage_a(0, 0);
  stage_b(0, 0);
  int cur = 0;
  for (int t = 0; t < 8; ++t) {
    asm volatile("s_waitcnt vmcnt(0)" ::: "memory");
    __builtin_amdgcn_s_barrier();
    asm volatile("" ::: "memory");
    const char* bp = lds + cur * PER_BUF;
    if (t < 7) stage_a(cur ^ 1, t + 1);
    KHALF(0)
    if (t < 7) stage_b(cur ^ 1, t + 1);
    KHALF(1)
    cur ^= 1;
  }
#undef KHALF
#undef AFR
#undef BFR

#pragma unroll
  for (int mi = 0; mi < 7; ++mi) {
    const int row = bm + mi * 16 + lk * 4;
#pragma unroll
    for (int ni = 0; ni < 4; ++ni) {
      const int col = w * 64 + ni * 16 + lrow;
      const float bc = bias[col];
#pragma unroll
      for (int j = 0; j < 4; ++j)
        outh[(size_t)(row + j) * 512 + col] = f2h_bits(acc[mi][ni][j] + bc);
    }
  }
}

// ---------------- sgemm64: final GEMM (fp16 A, BN=256, f32 out) ----------------
__global__ __launch_bounds__(512, 1) void sgemm64(const uint16_t* __restrict__ A,
                                                  const uint16_t* __restrict__ Wh,
                                                  const float* __restrict__ bias,
                                                  float* __restrict__ outf, int N) {
  constexpr int BN = 256;
  constexpr int NFR = BN / 64;
  constexpr int A_BYTES = 224 * 128;
  constexpr int PER_BUF = A_BYTES + BN * 128;
  __shared__ __align__(16) char lds[2 * PER_BUF];
  const int tid = threadIdx.x, w = tid >> 6, l = tid & 63;

  const int nwgx = gridDim.x;
  const int raw = blockIdx.y * nwgx + blockIdx.x;
  const int cpx = (nwgx * gridDim.y) >> 3;
  const int work = (raw & 7) * cpx + (raw >> 3);
  const int bmidx = work / nwgx;
  const int bm = bmidx * 224;
  const int bn = (work % nwgx) * BN;

  const int sp = (((l & 7) ^ ((l >> 3) & 7)) << 4);
  const char* Asrc = (const char*)A + (size_t)(bm + (l >> 3)) * 1024 + sp;
  const char* Bhs = (const char*)Wh + (size_t)(bn + (l >> 3)) * 1024 + sp;

  const int lrow = l & 15, lk = l >> 4;
  const int wr = w >> 2, wc = w & 3;

  f32x4 acc[7][NFR] = {};

  auto stage_a = [&](int buf, int t) {
    char* dst = lds + buf * PER_BUF;
    const char* src = Asrc + t * 128;
#pragma unroll
    for (int k = 0; k < 4; ++k) {
      const int i = w + k * 8;
      if (k < 3 || w < 4) gload16(src + (size_t)i * 8192, dst + i * 1024);
    }
  };
  auto stage_b = [&](int buf, int t) {
    char* dst = lds + buf * PER_BUF + A_BYTES;
#pragma unroll
    for (int k = 0; k < BN / 64; ++k) {
      const int i = w + k * 8;
      gload16(Bhs + t * 128 + (size_t)i * 8192, dst + i * 1024);
    }
  };

#define AFR(mi, kc) \
  ((wr * 112 + (mi)*16 + lrow) * 128 + ((((kc)*4 + lk) ^ (lrow & 7)) << 4))
#define BFR(ni, kc) \
  (A_BYTES + (wc * (BN / 4) + (ni)*16 + lrow) * 128 + ((((kc)*4 + lk) ^ (lrow & 7)) << 4))

#define KHALF(kc)                                                                \
  {                                                                              \
    short8 bh[NFR];                                                              \
    _Pragma("unroll") for (int ni = 0; ni < NFR; ++ni)                           \
        bh[ni] = *(const short8*)(bp + BFR(ni, kc));                             \
    short8 ah[7];                                                                \
    _Pragma("unroll") for (int mi = 0; mi < 7; ++mi)                             \
        ah[mi] = *(const short8*)(bp + AFR(mi, kc));                             \
    __builtin_amdgcn_s_setprio(1);                                               \
    _Pragma("unroll") for (int mi = 0; mi < 7; ++mi)                             \
      _Pragma("unroll") for (int ni = 0; ni < NFR; ++ni)                         \
        acc[mi][ni] = __builtin_amdgcn_mfma_f32_16x16x32_f16(                    \
            __builtin_bit_cast(f16x8, ah[mi]), __builtin_bit_cast(f16x8, bh[ni]), \
            acc[mi][ni], 0, 0, 0);                                               \
    __builtin_amdgcn_s_setprio(0);                                               \
  }

  stage_a(0, 0);
  stage_b(0, 0);
  int cur = 0;
  for (int t = 0; t < 8; ++t) {
    asm volatile("s_waitcnt vmcnt(0)" ::: "memory");
    __builtin_amdgcn_s_barrier();
    asm volatile("" ::: "memory");
    const char* bp = lds + cur * PER_BUF;
    if (t < 7) stage_a(cur ^ 1, t + 1);
    KHALF(0)
    if (t < 7) stage_b(cur ^ 1, t + 1);
    KHALF(1)
    cur ^= 1;
  }
#undef KHALF
#undef AFR
#undef BFR

#pragma unroll
  for (int mi = 0; mi < 7; ++mi) {
    const int row = bm + wr * 112 + mi * 16 + lk * 4;
#pragma unroll
    for (int ni = 0; ni < NFR; ++ni) {
      const int col = bn + wc * (BN / 4) + ni * 16 + lrow;
      const float bc = bias[col];
#pragma unroll
      for (int j = 0; j < 4; ++j)
        outf[(size_t)(row + j) * N + col] = acc[mi][ni][j] + bc;
    }
  }
}

// ---------------- qkattn: qk-GEMM (W-pair, acc2) + attention fused ----------------
template <bool STATS>
__global__ __launch_bounds__(512, 1) void qkattn(const uint16_t* __restrict__ A,
                                                 const uint16_t* __restrict__ Wh,
                                                 const uint16_t* __restrict__ Wl,
                                                 const float* __restrict__ bias,
                                                 const uint16_t* __restrict__ V,
                                                 uint16_t* __restrict__ Hs,
                                                 const float* __restrict__ sv,
                                                 const float* __restrict__ tv,
                                                 float* __restrict__ part) {
  constexpr int A_BYTES = 224 * 128;
  constexpr int BPL = 128 * 128;
  constexpr int PER_BUF = A_BYTES + 2 * BPL;
  __shared__ __align__(16) char lds[131072];
  const int tid = threadIdx.x, w = tid >> 6, l = tid & 63;

  const int raw = blockIdx.y;
  const int cpx = gridDim.y >> 3;
  const int bmidx = (raw & 7) * cpx + (raw >> 3);
  const int bm = bmidx * 224;

  const int sp = (((l & 7) ^ ((l >> 3) & 7)) << 4);
  const char* Asrc = (const char*)A + (size_t)(bm + (l >> 3)) * 1024 + sp;
  const char* Bhs = (const char*)Wh + (size_t)(l >> 3) * 1024 + sp;
  const char* Bls = (const char*)Wl + (size_t)(l >> 3) * 1024 + sp;

  const int lrow = l & 15, lk = l >> 4;
  const int wr = w >> 2, wc = w & 3;

  f32x4 acc[7][2] = {};
  f32x4 acc2[7][2] = {};

  auto stage_a = [&](int buf, int t) {
    char* dst = lds + buf * PER_BUF;
    const char* src = Asrc + t * 128;
#pragma unroll
    for (int k = 0; k < 4; ++k) {
      const int i = w + k * 8;
      if (k < 3 || w < 4) gload16(src + (size_t)i * 8192, dst + i * 1024);
    }
  };
  auto stage_b = [&](int buf, int t) {
    char* dst = lds + buf * PER_BUF + A_BYTES;
#pragma unroll
    for (int k = 0; k < 2; ++k) {
      const int i = w + k * 8;
      gload16(Bhs + t * 128 + (size_t)i * 8192, dst + i * 1024);
      gload16(Bls + t * 128 + (size_t)i * 8192, dst + BPL + i * 1024);
    }
  };

#define AFR(mi, kc) \
  ((wr * 112 + (mi)*16 + lrow) * 128 + ((((kc)*4 + lk) ^ (lrow & 7)) << 4))
#define BFR(ni, kc) \
  (A_BYTES + (wc * 32 + (ni)*16 + lrow) * 128 + ((((kc)*4 + lk) ^ (lrow & 7)) << 4))

#define KHALF(kc)                                                                \
  {                                                                              \
    short8 bh[2], bl2[2];                                                        \
    _Pragma("unroll") for (int ni = 0; ni < 2; ++ni) {                           \
      bh[ni] = *(const short8*)(bp + BFR(ni, kc));                               \
      bl2[ni] = *(const short8*)(bp + BPL + BFR(ni, kc));                        \
    }                                                                            \
    short8 ah[7];                                                                \
    _Pragma("unroll") for (int mi = 0; mi < 7; ++mi)                             \
        ah[mi] = *(const short8*)(bp + AFR(mi, kc));                             \
    __builtin_amdgcn_s_setprio(1);                                               \
    _Pragma("unroll") for (int mi = 0; mi < 7; ++mi)                             \
      _Pragma("unroll") for (int ni = 0; ni < 2; ++ni)                           \
        acc[mi][ni] = __builtin_amdgcn_mfma_f32_16x16x32_f16(                    \
            __builtin_bit_cast(f16x8, ah[mi]), __builtin_bit_cast(f16x8, bh[ni]), \
            acc[mi][ni], 0, 0, 0);                                               \
    _Pragma("unroll") for (int mi = 0; mi < 7; ++mi)                             \
      _Pragma("unroll") for (int ni = 0; ni < 2; ++ni)                           \
        acc2[mi][ni] = __builtin_amdgcn_mfma_f32_16x16x32_f16(                   \
            __builtin_bit_cast(f16x8, ah[mi]), __builtin_bit_cast(f16x8, bl2[ni]), \
            acc2[mi][ni], 0, 0, 0);                                              \
    __builtin_amdgcn_s_setprio(0);                                               \
  }

  stage_a(0, 0);
  stage_b(0, 0);
  int cur = 0;
  for (int t = 0; t < 8; ++t) {
    asm volatile("s_waitcnt vmcnt(0)" ::: "memory");
    __builtin_amdgcn_s_barrier();
    asm volatile("" ::: "memory");
    const char* bp = lds + cur * PER_BUF;
    if (t < 7) stage_a(cur ^ 1, t + 1);
    KHALF(0)
    if (t < 7) stage_b(cur ^ 1, t + 1);
    KHALF(1)
    cur ^= 1;
  }
#undef KHALF
#undef AFR
#undef BFR

  // ---- phase 2: q|k -> LDS f32, then attention ----
  __syncthreads();
  float* qk = (float*)lds;  // [224][128]
#pragma unroll
  for (int mi = 0; mi < 7; ++mi) {
    const int rl = wr * 112 + mi * 16 + lk * 4;
#pragma unroll
    for (int ni = 0; ni < 2; ++ni) {
      const int col = wc * 32 + ni * 16 + lrow;
      const float bc = bias[col];
#pragma unroll
      for (int j = 0; j < 4; ++j)
        qk[(rl + j) * 128 + col] = acc[mi][ni][j] + bc + acc2[mi][ni][j] * (1.0f / 1024.0f);
    }
  }
  __syncthreads();

  const float4 s0 = *(const float4*)&sv[l * 8], s1 = *(const float4*)&sv[l * 8 + 4];
  const float4 t0 = *(const float4*)&tv[l * 8], t1 = *(const float4*)&tv[l * 8 + 4];
  const float sarr[8] = {s0.x, s0.y, s0.z, s0.w, s1.x, s1.y, s1.z, s1.w};
  const float tarr[8] = {t0.x, t0.y, t0.z, t0.w, t1.x, t1.y, t1.z, t1.w};

  float s8[8] = {}, q8[8] = {};
#pragma unroll
  for (int gg = 0; gg < 4; ++gg) {
    const int g = w * 4 + gg;
    const int rl = g * 7;
    const size_t base = (size_t)bm + rl;

    float qv[7], kv[7];
#pragma unroll
    for (int i = 0; i < 7; ++i) {
      qv[i] = qk[(rl + i) * 128 + l];
      kv[i] = qk[(rl + i) * 128 + 64 + l];
    }
    float att[7][7];
#pragma unroll
    for (int i = 0; i < 7; ++i)
#pragma unroll
      for (int j = 0; j < 7; ++j) {
        float p = qv[i] * kv[j];
#pragma unroll
        for (int o = 32; o; o >>= 1) p += __shfl_xor(p, o);
        att[i][j] = p;
      }
#pragma unroll
    for (int i = 0; i < 7; ++i) {
      float m = att[i][0];
#pragma unroll
      for (int j = 1; j < 7; ++j) m = fmaxf(m, att[i][j]);
      float sum = 0.f;
#pragma unroll
      for (int j = 0; j < 7; ++j) {
        att[i][j] = expf(att[i][j] - m);
        sum += att[i][j];
      }
      const float inv = 1.0f / sum;
#pragma unroll
      for (int j = 0; j < 7; ++j) att[i][j] *= inv;
    }

    uint4 vpk[7];
#pragma unroll
    for (int j = 0; j < 7; ++j)
      vpk[j] = *(const uint4*)((const char*)V + (base + j) * 1024 + l * 16);

#pragma unroll
    for (int i = 0; i < 7; ++i) {
      char* hp = (char*)Hs + (base + i) * 1024 + l * 16;
      uint4 hh = *(const uint4*)hp;
      float o[8] = {};
#pragma unroll
      for (int j = 0; j < 7; ++j) {
        const float a = att[i][j];
#pragma unroll
        for (int e = 0; e < 8; ++e) o[e] += a * g16(vpk[j], e);
      }
      uint16_t oh[8];
#pragma unroll
      for (int e = 0; e < 8; ++e) {
        const float xn = g16(hh, e) * sarr[e] + tarr[e];
        const float rr = fmaxf(o[e] + xn, 0.f);
        if constexpr (STATS) { s8[e] += rr; q8[e] += rr * rr; }
        oh[e] = f2h_bits(rr);
      }
      uint4 ph;
#pragma unroll
      for (int k2 = 0; k2 < 4; ++k2)
        ((uint32_t*)&ph)[k2] = (uint32_t)oh[2 * k2] | ((uint32_t)oh[2 * k2 + 1] << 16);
      *(uint4*)hp = ph;
    }
  }

  if constexpr (STATS) {
    float* sred = (float*)(lds + 114688);  // [8][512]
#pragma unroll
    for (int e = 0; e < 8; ++e) sred[w * 512 + l * 8 + e] = s8[e];
    __syncthreads();
    {
      float sum = 0.f;
#pragma unroll
      for (int ww = 0; ww < 8; ++ww) sum += sred[ww * 512 + tid];
      part[(size_t)bmidx * 1024 + tid] = sum;
    }
    __syncthreads();
#pragma unroll
    for (int e = 0; e < 8; ++e) sred[w * 512 + l * 8 + e] = q8[e];
    __syncthreads();
    {
      float sum = 0.f;
#pragma unroll
      for (int ww = 0; ww < 8; ++ww) sum += sred[ww * 512 + tid];
      part[(size_t)bmidx * 1024 + 512 + tid] = sum;
    }
  }
}

// ---------------- stats reduce ----------------
__global__ __launch_bounds__(64) void reduce_stats(const float* __restrict__ part, int n,
                                                   const float* __restrict__ g,
                                                   const float* __restrict__ bb,
                                                   float* __restrict__ sv,
                                                   float* __restrict__ tv) {
  const int c = blockIdx.x, k = threadIdx.x;
  float sum = 0.f, sq = 0.f;
  for (int i = k; i < n; i += 64) {
    const float* p = part + (size_t)i * 1024;
    sum += p[c];
    sq += p[512 + c];
  }
#pragma unroll
  for (int o = 32; o; o >>= 1) {
    sum += __shfl_xor(sum, o);
    sq += __shfl_xor(sq, o);
  }
  if (k == 0) {
    const float mean = sum * (1.0f / 114688.0f);
    const float var = sq * (1.0f / 114688.0f) - mean * mean;
    const float sc = g[c] * rsqrtf(var + 1e-5f);
    sv[c] = sc;
    tv[c] = bb[c] - mean * sc;
  }
}

extern "C" void kernel_launch(void* const* d_in, const int* in_sizes, int n_in,
                              void* d_out, int out_size, void* d_ws, size_t ws_size,
                              hipStream_t stream) {
  const float* x  = (const float*)d_in[0];
  const float* Wt = (const float*)d_in[1];
  const float* bt = (const float*)d_in[2];
  const float *bng[3], *bnb[3], *Wq[3], *bq[3], *Wk[3], *bk[3], *Wv[3], *bv[3], *gam[3];
  for (int i = 0; i < 3; ++i) {
    int o = 3 + 9 * i;
    bng[i] = (const float*)d_in[o + 0];
    bnb[i] = (const float*)d_in[o + 1];
    Wq[i]  = (const float*)d_in[o + 2];
    bq[i]  = (const float*)d_in[o + 3];
    Wk[i]  = (const float*)d_in[o + 4];
    bk[i]  = (const float*)d_in[o + 5];
    Wv[i]  = (const float*)d_in[o + 6];
    bv[i]  = (const float*)d_in[o + 7];
    gam[i] = (const float*)d_in[o + 8];
  }
  const float* Wb = (const float*)d_in[30];
  const float* bb = (const float*)d_in[31];

  char* ws = (char*)d_ws;
  uint16_t* Hs    = (uint16_t*)(ws);                  // 117,440,512
  uint16_t* V     = (uint16_t*)(ws + 117440512);      // 117,440,512
  float*    part  = (float*)(ws + 234881024);         // 2,097,152 (512 x 1024)
  float*    sv    = (float*)(ws + 236978176);         // 2,048
  float*    tv    = (float*)(ws + 236980224);         // 2,048
  uint16_t* WqkH  = (uint16_t*)(ws + 236982272);      // 131,072
  uint16_t* WqkL  = (uint16_t*)(ws + 237113344);      // 131,072
  float*    bqkf  = (float*)(ws + 237244416);         // 2,048
  uint16_t* WvH   = (uint16_t*)(ws + 237246464);      // 524,288
  float*    bvf   = (float*)(ws + 237770752);         // 2,048
  char*     WtIo  = ws + 237772800;                   // 1,048,576
  float*    btf   = (float*)(ws + 238821376);         // 2,048
  uint16_t* WbH   = (uint16_t*)(ws + 238823424);      // 262,144

  // weight prep
  cvt4h<<<128, 256, 0, stream>>>(Wb, WbH, 32768);
  fold_w_io<<<512, 512, 0, stream>>>(Wt, bt, WtIo, btf);

  // h0 = x @ Wt.T + bt  (bf16 3-pass exact-grade; fp16 plane out + stats)
  gemm1<<<dim3(2, 512), 512, 0, stream>>>((const char*)x, WtIo, btf, Hs, part);

  for (int i = 0; i < 3; ++i) {
    reduce_stats<<<512, 64, 0, stream>>>(part, 512, bng[i], bnb[i], sv, tv);
    fold_all<<<640, 512, 0, stream>>>(Wq[i], bq[i], Wk[i], bk[i], Wv[i], bv[i],
                                      sv, tv, gam[i], WqkH, WqkL, bqkf, WvH, bvf);
    // v' = h @ (gam*Wv*s)'.T + b''  (1-pass fp16, A read once; fp16 plane out)
    sgemmV<<<dim3(1, 1024), 512, 0, stream>>>(Hs, WvH, bvf, V);
    // fused: q|k GEMM (W-pair, acc2) -> LDS -> attention + residual + relu (+ stats)
    if (i < 2)
      qkattn<true><<<dim3(1, 512), 512, 0, stream>>>(Hs, WqkH, WqkL, bqkf, V, Hs,
                                                     sv, tv, part);
    else
      qkattn<false><<<dim3(1, 512), 512, 0, stream>>>(Hs, WqkH, WqkL, bqkf, V, Hs,
                                                      sv, tv, nullptr);
  }

  // out = h3 @ Wb.T + bb  (1-pass fp16; f32 out)
  sgemm64<<<dim3(1, 512), 512, 0, stream>>>(Hs, WbH, bb, (float*)d_out, 256);
}

// Round 17
// 915.769 us; speedup vs baseline: 3.1651x; 1.0330x over previous
//
#include <hip/hip_runtime.h>
#include <hip/hip_bf16.h>
#include <stdint.h>

// LevelReasoning on MI355X — round 17: V eliminated from global memory.
// gemm1 reverted to r15 exact bf16 3-pass (r16's fp16 1-pass failed 0.172).
// New split: qkgemm (fp16 q|k out, 29MB on d_out scratch) + vattn (v-GEMM whose
// acc -> LDS [16g][8r][512c] fp16, then per-wave attention+residual+relu+stats).
// Saves V write+read (234 MB/layer) at cost of qk round-trip (59 MB/layer).

using bf16 = __hip_bfloat16;
typedef __attribute__((ext_vector_type(8))) short short8;
typedef __attribute__((ext_vector_type(4))) float f32x4;
typedef _Float16 f16x8 __attribute__((ext_vector_type(8)));

__device__ inline uint16_t f2b_bits(float f) {
  bf16 h = __float2bfloat16(f);
  return __builtin_bit_cast(uint16_t, h);
}
__device__ inline float b2f_bits(uint16_t u) { return __uint_as_float(((uint32_t)u) << 16); }
__device__ inline void split2(float v, uint16_t& hi, uint16_t& lo) {
  hi = f2b_bits(v);
  lo = f2b_bits(v - b2f_bits(hi));
}
__device__ inline uint16_t f2h_bits(float f) {
  _Float16 h = (_Float16)f;
  return __builtin_bit_cast(uint16_t, h);
}
__device__ inline float h2f_bits(uint16_t u) {
  return (float)__builtin_bit_cast(_Float16, u);
}
__device__ inline float g16(const uint4& u, int e) {
  uint32_t wrd = ((const uint32_t*)&u)[e >> 1];
  return h2f_bits((uint16_t)((e & 1) ? (wrd >> 16) : (wrd & 0xffffu)));
}

typedef const __attribute__((address_space(1))) void* gas_ptr;
typedef __attribute__((address_space(3))) void* las_ptr;
__device__ inline void gload16(const void* g, void* l) {
  __builtin_amdgcn_global_load_lds((gas_ptr)g, (las_ptr)l, 16, 0, 0);
}

// ---------------- f32 -> fp16 plain (Wb) ----------------
__global__ __launch_bounds__(256) void cvt4h(const float* __restrict__ in,
                                             uint16_t* __restrict__ out, int n4) {
  int i = blockIdx.x * 256 + threadIdx.x;
  const int stride = gridDim.x * 256;
  for (; i < n4; i += stride) {
    float4 v = ((const float4*)in)[i];
    uint32_t lo = (uint32_t)f2h_bits(v.x) | ((uint32_t)f2h_bits(v.y) << 16);
    uint32_t hi = (uint32_t)f2h_bits(v.z) | ((uint32_t)f2h_bits(v.w) << 16);
    ((uint2*)out)[i] = make_uint2(lo, hi);
  }
}

// ------- fold Wt to bf16-pair io (2KB rows) for gemm1 -------
__global__ __launch_bounds__(512) void fold_w_io(const float* __restrict__ Wsrc,
                                                 const float* __restrict__ bsrc,
                                                 char* __restrict__ Wio,
                                                 float* __restrict__ bout) {
  const int row = blockIdx.x, c = threadIdx.x;
  const float wv = Wsrc[(size_t)row * 512 + c];
  uint16_t hb, lb;
  split2(wv, hb, lb);
  char* p = Wio + (size_t)row * 2048 + (c >> 3) * 32 + (c & 7) * 2;
  *(uint16_t*)p = hb;
  *(uint16_t*)(p + 16) = lb;
  if (c == 0) bout[row] = bsrc[row];
}

// ------- fused per-layer weight fold: Wq, Wk (pair, lo x1024), Wv (single, gamma) -------
__global__ __launch_bounds__(512) void fold_all(const float* __restrict__ Wq,
                                                const float* __restrict__ bq,
                                                const float* __restrict__ Wk,
                                                const float* __restrict__ bk,
                                                const float* __restrict__ Wv,
                                                const float* __restrict__ bv,
                                                const float* __restrict__ sv,
                                                const float* __restrict__ tv,
                                                const float* __restrict__ gamp,
                                                uint16_t* __restrict__ WqkH,
                                                uint16_t* __restrict__ WqkL,
                                                float* __restrict__ bqkf,
                                                uint16_t* __restrict__ WvH,
                                                float* __restrict__ bvf) {
  const int b = blockIdx.x, c = threadIdx.x;
  __shared__ float red[512];
  const float* Wsrc;
  const float* bsrc;
  uint16_t *Wh, *Wl;
  float* bout;
  float g;
  int row;
  if (b < 64) {
    Wsrc = Wq; bsrc = bq; Wh = WqkH; Wl = WqkL; bout = bqkf; g = 1.0f; row = b;
  } else if (b < 128) {
    Wsrc = Wk; bsrc = bk; Wh = WqkH + (size_t)64 * 512; Wl = WqkL + (size_t)64 * 512;
    bout = bqkf + 64; g = 1.0f; row = b - 64;
  } else {
    Wsrc = Wv; bsrc = bv; Wh = WvH; Wl = nullptr; bout = bvf; g = gamp[0]; row = b - 128;
  }
  const float wv = Wsrc[(size_t)row * 512 + c];
  const float fv = g * wv * sv[c];
  const uint16_t hb = f2h_bits(fv);
  Wh[(size_t)row * 512 + c] = hb;
  if (Wl) Wl[(size_t)row * 512 + c] = f2h_bits((fv - h2f_bits(hb)) * 1024.0f);
  red[c] = wv * tv[c];
  __syncthreads();
#pragma unroll
  for (int off = 256; off > 0; off >>= 1) {
    if (c < off) red[c] += red[c + off];
    __syncthreads();
  }
  if (c == 0) bout[row] = g * (bsrc[row] + red[0]);
}

// ---------------- gemm1: h0 = x @ Wt.T + bt (bf16 3-pass exact, fp16-plane out + stats) -----
__global__ __launch_bounds__(512, 1) void gemm1(const char* __restrict__ A,
                                                const char* __restrict__ Wio,
                                                const float* __restrict__ bias,
                                                uint16_t* __restrict__ outh,
                                                float* __restrict__ part) {
  constexpr int A_BYTES = 224 * 128;
  constexpr int PER_BUF = A_BYTES + 256 * 128;
  __shared__ __align__(16) char lds[2 * PER_BUF];
  __shared__ float sred[2][2][256];
  const int tid = threadIdx.x, w = tid >> 6, l = tid & 63;

  const int nwgx = gridDim.x;
  const int raw = blockIdx.y * nwgx + blockIdx.x;
  const int cpx = (nwgx * gridDim.y) >> 3;
  const int work = (raw & 7) * cpx + (raw >> 3);
  const int bmidx = work / nwgx;
  const int bm = bmidx * 224;
  const int bn = (work % nwgx) * 256;

  const int ssl = ((((l >> 1) & 3) ^ ((l >> 3) & 3)) << 5) | (((l & 1) ^ ((l >> 5) & 1)) << 4);
  const char* Asrc = A + (size_t)(bm + (l >> 3)) * 2048 + ssl;
  const char* Bsrc = Wio + (size_t)(bn + (l >> 3)) * 2048 + ssl;

  const int lrow = l & 15, lk = l >> 4;
  const int wr = w >> 2, wc = w & 3;
  const int sw32 = (lk ^ (lrow & 3)) * 32;
  const int hi16 = ((lrow >> 2) & 1) * 16;
  const int afr = (wr * 112 + lrow) * 128 + sw32;
  const int bfr = A_BYTES + (wc * 64 + lrow) * 128 + sw32;

  f32x4 acc[7][4] = {};

  auto stage_a = [&](int buf, int t) {
    char* dst = lds + buf * PER_BUF;
    const char* src = Asrc + (size_t)t * 128;
#pragma unroll
    for (int k = 0; k < 4; ++k) {
      const int i = w + k * 8;
      if (k < 3 || w < 4) gload16(src + (size_t)i * 16384, dst + i * 1024);
    }
  };
  auto stage_b = [&](int buf, int t) {
    char* dst = lds + buf * PER_BUF + A_BYTES;
    const char* src = Bsrc + (size_t)t * 128;
#pragma unroll
    for (int k = 0; k < 4; ++k) {
      const int i = w + k * 8;
      gload16(src + (size_t)i * 16384, dst + i * 1024);
    }
  };

#define LOADA(BASE, CNT)                                                         \
  {                                                                              \
    _Pragma("unroll") for (int u = 0; u < (CNT); ++u) {                          \
      const int mi = (BASE) + u;                                                 \
      float4 f0 = *(const float4*)(bp + afr + mi * 2048 + hi16);                 \
      float4 f1 = *(const float4*)(bp + afr + mi * 2048 + (hi16 ^ 16));          \
      const float fv[8] = {f0.x, f0.y, f0.z, f0.w, f1.x, f1.y, f1.z, f1.w};      \
      _Pragma("unroll") for (int e = 0; e < 8; ++e) {                            \
        uint16_t hb, lb;                                                         \
        split2(fv[e], hb, lb);                                                   \
        ah[u][e] = (short)hb;                                                    \
        al[u][e] = (short)lb;                                                    \
      }                                                                          \
    }                                                                            \
  }

#define MFMAC(BASE, CNT)                                                         \
  {                                                                              \
    __builtin_amdgcn_s_setprio(1);                                               \
    _Pragma("unroll") for (int u = 0; u < (CNT); ++u)                            \
      _Pragma("unroll") for (int ni = 0; ni < 4; ++ni)                           \
        acc[(BASE) + u][ni] = __builtin_amdgcn_mfma_f32_16x16x32_bf16(           \
            ah[u], bh[ni], acc[(BASE) + u][ni], 0, 0, 0);                        \
    _Pragma("unroll") for (int u = 0; u < (CNT); ++u)                            \
      _Pragma("unroll") for (int ni = 0; ni < 4; ++ni)                           \
        acc[(BASE) + u][ni] = __builtin_amdgcn_mfma_f32_16x16x32_bf16(           \
            ah[u], bl[ni], acc[(BASE) + u][ni], 0, 0, 0);                        \
    _Pragma("unroll") for (int u = 0; u < (CNT); ++u)                            \
      _Pragma("unroll") for (int ni = 0; ni < 4; ++ni)                           \
        acc[(BASE) + u][ni] = __builtin_amdgcn_mfma_f32_16x16x32_bf16(           \
            al[u], bh[ni], acc[(BASE) + u][ni], 0, 0, 0);                        \
    __builtin_amdgcn_s_setprio(0);                                               \
  }

  stage_a(0, 0);
  stage_b(0, 0);
  int cur = 0;
#pragma unroll 2
  for (int t = 0; t < 16; ++t) {
    asm volatile("s_waitcnt vmcnt(0)" ::: "memory");
    __builtin_amdgcn_s_barrier();
    asm volatile("" ::: "memory");

    const char* bp = lds + cur * PER_BUF;
    if (t < 15) stage_a(cur ^ 1, t + 1);

    short8 bh[4], bl[4];
#pragma unroll
    for (int ni = 0; ni < 4; ++ni) {
      bh[ni] = *(const short8*)(bp + bfr + ni * 2048 + hi16);
      bl[ni] = *(const short8*)(bp + bfr + ni * 2048 + (hi16 ^ 16));
    }
    short8 ah[4], al[4];
    LOADA(0, 4)
    MFMAC(0, 4)
    if (t < 15) stage_b(cur ^ 1, t + 1);
    LOADA(4, 3)
    MFMAC(4, 3)
    cur ^= 1;
  }
#undef LOADA
#undef MFMAC

  float sni[4] = {}, qni[4] = {};
#pragma unroll
  for (int mi = 0; mi < 7; ++mi) {
    const int row = bm + wr * 112 + mi * 16 + lk * 4;
#pragma unroll
    for (int ni = 0; ni < 4; ++ni) {
      const int col = bn + wc * 64 + ni * 16 + lrow;
      const float bc = bias[col];
#pragma unroll
      for (int j = 0; j < 4; ++j) {
        const float vv = acc[mi][ni][j] + bc;
        outh[(size_t)(row + j) * 512 + col] = f2h_bits(vv);
        sni[ni] += vv;
        qni[ni] += vv * vv;
      }
    }
  }
#pragma unroll
  for (int ni = 0; ni < 4; ++ni) {
    float s = sni[ni], q = qni[ni];
    s += __shfl_xor(s, 16); q += __shfl_xor(q, 16);
    s += __shfl_xor(s, 32); q += __shfl_xor(q, 32);
    if (lk == 0) {
      sred[0][wr][wc * 64 + ni * 16 + lrow] = s;
      sred[1][wr][wc * 64 + ni * 16 + lrow] = q;
    }
  }
  __syncthreads();
  if (tid < 256) {
    part[(size_t)bmidx * 1024 + bn + tid] = sred[0][0][tid] + sred[0][1][tid];
    part[(size_t)bmidx * 1024 + 512 + bn + tid] = sred[1][0][tid] + sred[1][1][tid];
  }
}

// ---------------- qkgemm: q|k = h @ Wqk'.T + b' (W-pair, acc2); fp16 out pitch 128 ----------
__global__ __launch_bounds__(512, 1) void qkgemm(const uint16_t* __restrict__ A,
                                                 const uint16_t* __restrict__ Wh,
                                                 const uint16_t* __restrict__ Wl,
                                                 const float* __restrict__ bias,
                                                 uint16_t* __restrict__ qkh) {
  constexpr int A_BYTES = 224 * 128;
  constexpr int BPL = 128 * 128;
  constexpr int PER_BUF = A_BYTES + 2 * BPL;
  __shared__ __align__(16) char lds[2 * PER_BUF];
  const int tid = threadIdx.x, w = tid >> 6, l = tid & 63;

  const int raw = blockIdx.y;
  const int cpx = gridDim.y >> 3;
  const int bmidx = (raw & 7) * cpx + (raw >> 3);
  const int bm = bmidx * 224;

  const int sp = (((l & 7) ^ ((l >> 3) & 7)) << 4);
  const char* Asrc = (const char*)A + (size_t)(bm + (l >> 3)) * 1024 + sp;
  const char* Bhs = (const char*)Wh + (size_t)(l >> 3) * 1024 + sp;
  const char* Bls = (const char*)Wl + (size_t)(l >> 3) * 1024 + sp;

  const int lrow = l & 15, lk = l >> 4;
  const int wr = w >> 2, wc = w & 3;

  f32x4 acc[7][2] = {};
  f32x4 acc2[7][2] = {};

  auto stage_a = [&](int buf, int t) {
    char* dst = lds + buf * PER_BUF;
    const char* src = Asrc + t * 128;
#pragma unroll
    for (int k = 0; k < 4; ++k) {
      const int i = w + k * 8;
      if (k < 3 || w < 4) gload16(src + (size_t)i * 8192, dst + i * 1024);
    }
  };
  auto stage_b = [&](int buf, int t) {
    char* dst = lds + buf * PER_BUF + A_BYTES;
#pragma unroll
    for (int k = 0; k < 2; ++k) {
      const int i = w + k * 8;
      gload16(Bhs + t * 128 + (size_t)i * 8192, dst + i * 1024);
      gload16(Bls + t * 128 + (size_t)i * 8192, dst + BPL + i * 1024);
    }
  };

#define AFR(mi, kc) \
  ((wr * 112 + (mi)*16 + lrow) * 128 + ((((kc)*4 + lk) ^ (lrow & 7)) << 4))
#define BFR(ni, kc) \
  (A_BYTES + (wc * 32 + (ni)*16 + lrow) * 128 + ((((kc)*4 + lk) ^ (lrow & 7)) << 4))

#define KHALF(kc)                                                                \
  {                                                                              \
    short8 bh[2], bl2[2];                                                        \
    _Pragma("unroll") for (int ni = 0; ni < 2; ++ni) {                           \
      bh[ni] = *(const short8*)(bp + BFR(ni, kc));                               \
      bl2[ni] = *(const short8*)(bp + BPL + BFR(ni, kc));                        \
    }                                                                            \
    short8 ah[7];                                                                \
    _Pragma("unroll") for (int mi = 0; mi < 7; ++mi)                             \
        ah[mi] = *(const short8*)(bp + AFR(mi, kc));                             \
    __builtin_amdgcn_s_setprio(1);                                               \
    _Pragma("unroll") for (int mi = 0; mi < 7; ++mi)                             \
      _Pragma("unroll") for (int ni = 0; ni < 2; ++ni)                           \
        acc[mi][ni] = __builtin_amdgcn_mfma_f32_16x16x32_f16(                    \
            __builtin_bit_cast(f16x8, ah[mi]), __builtin_bit_cast(f16x8, bh[ni]), \
            acc[mi][ni], 0, 0, 0);                                               \
    _Pragma("unroll") for (int mi = 0; mi < 7; ++mi)                             \
      _Pragma("unroll") for (int ni = 0; ni < 2; ++ni)                           \
        acc2[mi][ni] = __builtin_amdgcn_mfma_f32_16x16x32_f16(                   \
            __builtin_bit_cast(f16x8, ah[mi]), __builtin_bit_cast(f16x8, bl2[ni]), \
            acc2[mi][ni], 0, 0, 0);                                              \
    __builtin_amdgcn_s_setprio(0);                                               \
  }

  stage_a(0, 0);
  stage_b(0, 0);
  int cur = 0;
  for (int t = 0; t < 8; ++t) {
    asm volatile("s_waitcnt vmcnt(0)" ::: "memory");
    __builtin_amdgcn_s_barrier();
    asm volatile("" ::: "memory");
    const char* bp = lds + cur * PER_BUF;
    if (t < 7) stage_a(cur ^ 1, t + 1);
    KHALF(0)
    if (t < 7) stage_b(cur ^ 1, t + 1);
    KHALF(1)
    cur ^= 1;
  }
#undef KHALF
#undef AFR
#undef BFR

#pragma unroll
  for (int mi = 0; mi < 7; ++mi) {
    const int row = bm + wr * 112 + mi * 16 + lk * 4;
#pragma unroll
    for (int ni = 0; ni < 2; ++ni) {
      const int col = wc * 32 + ni * 16 + lrow;
      const float bc = bias[col];
#pragma unroll
      for (int j = 0; j < 4; ++j)
        qkh[(size_t)(row + j) * 128 + col] =
            f2h_bits(acc[mi][ni][j] + bc + acc2[mi][ni][j] * (1.0f / 1024.0f));
    }
  }
}

// ---------------- vattn: v-GEMM (acc -> LDS) + attention + residual + relu + stats ----------
template <bool STATS>
__global__ __launch_bounds__(512, 1) void vattn(const uint16_t* __restrict__ A,
                                                const uint16_t* __restrict__ Wh,
                                                const float* __restrict__ bias,
                                                const uint16_t* __restrict__ qkh,
                                                uint16_t* __restrict__ Hs,
                                                const float* __restrict__ sv,
                                                const float* __restrict__ tv,
                                                float* __restrict__ part) {
  constexpr int A_BYTES = 112 * 128;   // 14336
  constexpr int B_BYTES = 512 * 128;   // 65536
  constexpr int PER_BUF = A_BYTES + B_BYTES;  // 79872
  __shared__ __align__(16) char lds[2 * PER_BUF];  // 159744; reused post-loop
  const int tid = threadIdx.x, w = tid >> 6, l = tid & 63;

  const int raw = blockIdx.y;          // grid (1, 1024)
  const int cpx = gridDim.y >> 3;
  const int bmidx = (raw & 7) * cpx + (raw >> 3);
  const int bm = bmidx * 112;

  const int sp = (((l & 7) ^ ((l >> 3) & 7)) << 4);
  const char* Asrc = (const char*)A + (size_t)(bm + (l >> 3)) * 1024 + sp;
  const char* Bhs = (const char*)Wh + (size_t)(l >> 3) * 1024 + sp;

  const int lrow = l & 15, lk = l >> 4;

  f32x4 acc[7][4] = {};

  auto stage_a = [&](int buf, int t) {
    char* dst = lds + buf * PER_BUF;
    const char* src = Asrc + t * 128;
#pragma unroll
    for (int k = 0; k < 2; ++k) {
      const int i = w + k * 8;
      if (k < 1 || w < 6) gload16(src + (size_t)i * 8192, dst + i * 1024);
    }
  };
  auto stage_b = [&](int buf, int t) {
    char* dst = lds + buf * PER_BUF + A_BYTES;
#pragma unroll
    for (int k = 0; k < 8; ++k) {
      const int i = w + k * 8;
      gload16(Bhs + t * 128 + (size_t)i * 8192, dst + i * 1024);
    }
  };

#define AFR(mi, kc) \
  (((mi)*16 + lrow) * 128 + ((((kc)*4 + lk) ^ (lrow & 7)) << 4))
#define BFR(ni, kc) \
  (A_BYTES + (w * 64 + (ni)*16 + lrow) * 128 + ((((kc)*4 + lk) ^ (lrow & 7)) << 4))

#define KHALF(kc)                                                                \
  {                                                                              \
    short8 bh[4];                                                                \
    _Pragma("unroll") for (int ni = 0; ni < 4; ++ni)                             \
        bh[ni] = *(const short8*)(bp + BFR(ni, kc));                             \
    short8 ah[7];                                                                \
    _Pragma("unroll") for (int mi = 0; mi < 7; ++mi)                             \
        ah[mi] = *(const short8*)(bp + AFR(mi, kc));                             \
    __builtin_amdgcn_s_setprio(1);                                               \
    _Pragma("unroll") for (int mi = 0; mi < 7; ++mi)                             \
      _Pragma("unroll") for (int ni = 0; ni < 4; ++ni)                           \
        acc[mi][ni] = __builtin_amdgcn_mfma_f32_16x16x32_f16(                    \
            __builtin_bit_cast(f16x8, ah[mi]), __builtin_bit_cast(f16x8, bh[ni]), \
            acc[mi][ni], 0, 0, 0);                                               \
    __builtin_amdgcn_s_setprio(0);                                               \
  }

  stage_a(0, 0);
  stage_b(0, 0);
  int cur = 0;
  for (int t = 0; t < 8; ++t) {
    asm volatile("s_waitcnt vmcnt(0)" ::: "memory");
    __builtin_amdgcn_s_barrier();
    asm volatile("" ::: "memory");
    const char* bp = lds + cur * PER_BUF;
    if (t < 7) stage_a(cur ^ 1, t + 1);
    KHALF(0)
    if (t < 7) stage_b(cur ^ 1, t + 1);
    KHALF(1)
    cur ^= 1;
  }
#undef KHALF
#undef AFR
#undef BFR

  // ---- phase 2: v = acc + bias -> LDS [g][j][c] fp16 (g*8192 + j*1024 + c*2 bytes) ----
  __syncthreads();  // all GEMM LDS reads complete before overwrite
  {
    uint16_t* vl = (uint16_t*)lds;
#pragma unroll
    for (int mi = 0; mi < 7; ++mi)
#pragma unroll
      for (int ni = 0; ni < 4; ++ni) {
        const int col = w * 64 + ni * 16 + lrow;
        const float bc = bias[col];
#pragma unroll
        for (int j = 0; j < 4; ++j) {
          const int row = mi * 16 + lk * 4 + j;  // 0..111
          const int g = row / 7, jj = row - g * 7;
          vl[g * 4096 + jj * 512 + col] = f2h_bits(acc[mi][ni][j] + bc);
        }
      }
  }
  __syncthreads();

  // ---- phase 3: attention; wave w handles groups 2w, 2w+1; lane owns cols l*8..l*8+7 ----
  const float4 s0 = *(const float4*)&sv[l * 8], s1 = *(const float4*)&sv[l * 8 + 4];
  const float4 t0 = *(const float4*)&tv[l * 8], t1 = *(const float4*)&tv[l * 8 + 4];
  const float sarr[8] = {s0.x, s0.y, s0.z, s0.w, s1.x, s1.y, s1.z, s1.w};
  const float tarr[8] = {t0.x, t0.y, t0.z, t0.w, t1.x, t1.y, t1.z, t1.w};

  float s8[8] = {}, q8[8] = {};
#pragma unroll
  for (int gg = 0; gg < 2; ++gg) {
    const int g = w * 2 + gg;
    const size_t grow = (size_t)bm + g * 7;

    float qv[7], kv[7];
#pragma unroll
    for (int i = 0; i < 7; ++i) {
      qv[i] = h2f_bits(qkh[(grow + i) * 128 + l]);
      kv[i] = h2f_bits(qkh[(grow + i) * 128 + 64 + l]);
    }
    float att[7][7];
#pragma unroll
    for (int i = 0; i < 7; ++i)
#pragma unroll
      for (int j = 0; j < 7; ++j) {
        float p = qv[i] * kv[j];
#pragma unroll
        for (int o = 32; o; o >>= 1) p += __shfl_xor(p, o);
        att[i][j] = p;
      }
#pragma unroll
    for (int i = 0; i < 7; ++i) {
      float m = att[i][0];
#pragma unroll
      for (int j = 1; j < 7; ++j) m = fmaxf(m, att[i][j]);
      float sum = 0.f;
#pragma unroll
      for (int j = 0; j < 7; ++j) {
        att[i][j] = expf(att[i][j] - m);
        sum += att[i][j];
      }
      const float inv = 1.0f / sum;
#pragma unroll
      for (int j = 0; j < 7; ++j) att[i][j] *= inv;
    }

    uint4 vpk[7];
#pragma unroll
    for (int j = 0; j < 7; ++j)
      vpk[j] = *(const uint4*)(lds + g * 8192 + j * 1024 + l * 16);

#pragma unroll
    for (int i = 0; i < 7; ++i) {
      char* hp = (char*)Hs + (grow + i) * 1024 + l * 16;
      uint4 hh = *(const uint4*)hp;
      float o[8] = {};
#pragma unroll
      for (int j = 0; j < 7; ++j) {
        const float a = att[i][j];
#pragma unroll
        for (int e = 0; e < 8; ++e) o[e] += a * g16(vpk[j], e);
      }
      uint16_t oh[8];
#pragma unroll
      for (int e = 0; e < 8; ++e) {
        const float xn = g16(hh, e) * sarr[e] + tarr[e];
        const float rr = fmaxf(o[e] + xn, 0.f);
        if constexpr (STATS) { s8[e] += rr; q8[e] += rr * rr; }
        oh[e] = f2h_bits(rr);
      }
      uint4 ph;
#pragma unroll
      for (int k2 = 0; k2 < 4; ++k2)
        ((uint32_t*)&ph)[k2] = (uint32_t)oh[2 * k2] | ((uint32_t)oh[2 * k2 + 1] << 16);
      *(uint4*)hp = ph;
    }
  }

  if constexpr (STATS) {
    __syncthreads();  // all v reads done before reuse
    float* sred = (float*)lds;  // [8][512]
#pragma unroll
    for (int e = 0; e < 8; ++e) sred[w * 512 + l * 8 + e] = s8[e];
    __syncthreads();
    {
      float sum = 0.f;
#pragma unroll
      for (int ww = 0; ww < 8; ++ww) sum += sred[ww * 512 + tid];
      part[(size_t)bmidx * 1024 + tid] = sum;
    }
    __syncthreads();
#pragma unroll
    for (int e = 0; e < 8; ++e) sred[w * 512 + l * 8 + e] = q8[e];
    __syncthreads();
    {
      float sum = 0.f;
#pragma unroll
      for (int ww = 0; ww < 8; ++ww) sum += sred[ww * 512 + tid];
      part[(size_t)bmidx * 1024 + 512 + tid] = sum;
    }
  }
}

// ---------------- sgemm64: final GEMM (fp16 A, BN=256, f32 out) ----------------
__global__ __launch_bounds__(512, 1) void sgemm64(const uint16_t* __restrict__ A,
                                                  const uint16_t* __restrict__ Wh,
                                                  const float* __restrict__ bias,
                                                  float* __restrict__ outf, int N) {
  constexpr int BN = 256;
  constexpr int NFR = BN / 64;
  constexpr int A_BYTES = 224 * 128;
  constexpr int PER_BUF = A_BYTES + BN * 128;
  __shared__ __align__(16) char lds[2 * PER_BUF];
  const int tid = threadIdx.x, w = tid >> 6, l = tid & 63;

  const int raw = blockIdx.y;
  const int cpx = gridDim.y >> 3;
  const int bmidx = (raw & 7) * cpx + (raw >> 3);
  const int bm = bmidx * 224;
  const int bn = 0;

  const int sp = (((l & 7) ^ ((l >> 3) & 7)) << 4);
  const char* Asrc = (const char*)A + (size_t)(bm + (l >> 3)) * 1024 + sp;
  const char* Bhs = (const char*)Wh + (size_t)(bn + (l >> 3)) * 1024 + sp;

  const int lrow = l & 15, lk = l >> 4;
  const int wr = w >> 2, wc = w & 3;

  f32x4 acc[7][NFR] = {};

  auto stage_a = [&](int buf, int t) {
    char* dst = lds + buf * PER_BUF;
    const char* src = Asrc + t * 128;
#pragma unroll
    for (int k = 0; k < 4; ++k) {
      const int i = w + k * 8;
      if (k < 3 || w < 4) gload16(src + (size_t)i * 8192, dst + i * 1024);
    }
  };
  auto stage_b = [&](int buf, int t) {
    char* dst = lds + buf * PER_BUF + A_BYTES;
#pragma unroll
    for (int k = 0; k < BN / 64; ++k) {
      const int i = w + k * 8;
      gload16(Bhs + t * 128 + (size_t)i * 8192, dst + i * 1024);
    }
  };

#define AFR(mi, kc) \
  ((wr * 112 + (mi)*16 + lrow) * 128 + ((((kc)*4 + lk) ^ (lrow & 7)) << 4))
#define BFR(ni, kc) \
  (A_BYTES + (wc * (BN / 4) + (ni)*16 + lrow) * 128 + ((((kc)*4 + lk) ^ (lrow & 7)) << 4))

#define KHALF(kc)                                                                \
  {                                                                              \
    short8 bh[NFR];                                                              \
    _Pragma("unroll") for (int ni = 0; ni < NFR; ++ni)                           \
        bh[ni] = *(const short8*)(bp + BFR(ni, kc));                             \
    short8 ah[7];                                                                \
    _Pragma("unroll") for (int mi = 0; mi < 7; ++mi)                             \
        ah[mi] = *(const short8*)(bp + AFR(mi, kc));                             \
    __builtin_amdgcn_s_setprio(1);                                               \
    _Pragma("unroll") for (int mi = 0; mi < 7; ++mi)                             \
      _Pragma("unroll") for (int ni = 0; ni < NFR; ++ni)                         \
        acc[mi][ni] = __builtin_amdgcn_mfma_f32_16x16x32_f16(                    \
            __builtin_bit_cast(f16x8, ah[mi]), __builtin_bit_cast(f16x8, bh[ni]), \
            acc[mi][ni], 0, 0, 0);                                               \
    __builtin_amdgcn_s_setprio(0);                                               \
  }

  stage_a(0, 0);
  stage_b(0, 0);
  int cur = 0;
  for (int t = 0; t < 8; ++t) {
    asm volatile("s_waitcnt vmcnt(0)" ::: "memory");
    __builtin_amdgcn_s_barrier();
    asm volatile("" ::: "memory");
    const char* bp = lds + cur * PER_BUF;
    if (t < 7) stage_a(cur ^ 1, t + 1);
    KHALF(0)
    if (t < 7) stage_b(cur ^ 1, t + 1);
    KHALF(1)
    cur ^= 1;
  }
#undef KHALF
#undef AFR
#undef BFR

#pragma unroll
  for (int mi = 0; mi < 7; ++mi) {
    const int row = bm + wr * 112 + mi * 16 + lk * 4;
#pragma unroll
    for (int ni = 0; ni < NFR; ++ni) {
      const int col = bn + wc * (BN / 4) + ni * 16 + lrow;
      const float bc = bias[col];
#pragma unroll
      for (int j = 0; j < 4; ++j)
        outf[(size_t)(row + j) * N + col] = acc[mi][ni][j] + bc;
    }
  }
}

// ---------------- stats reduce ----------------
__global__ __launch_bounds__(64) void reduce_stats(const float* __restrict__ part, int n,
                                                   const float* __restrict__ g,
                                                   const float* __restrict__ bb,
                                                   float* __restrict__ sv,
                                                   float* __restrict__ tv) {
  const int c = blockIdx.x, k = threadIdx.x;
  float sum = 0.f, sq = 0.f;
  for (int i = k; i < n; i += 64) {
    const float* p = part + (size_t)i * 1024;
    sum += p[c];
    sq += p[512 + c];
  }
#pragma unroll
  for (int o = 32; o; o >>= 1) {
    sum += __shfl_xor(sum, o);
    sq += __shfl_xor(sq, o);
  }
  if (k == 0) {
    const float mean = sum * (1.0f / 114688.0f);
    const float var = sq * (1.0f / 114688.0f) - mean * mean;
    const float sc = g[c] * rsqrtf(var + 1e-5f);
    sv[c] = sc;
    tv[c] = bb[c] - mean * sc;
  }
}

extern "C" void kernel_launch(void* const* d_in, const int* in_sizes, int n_in,
                              void* d_out, int out_size, void* d_ws, size_t ws_size,
                              hipStream_t stream) {
  const float* x  = (const float*)d_in[0];
  const float* Wt = (const float*)d_in[1];
  const float* bt = (const float*)d_in[2];
  const float *bng[3], *bnb[3], *Wq[3], *bq[3], *Wk[3], *bk[3], *Wv[3], *bv[3], *gam[3];
  for (int i = 0; i < 3; ++i) {
    int o = 3 + 9 * i;
    bng[i] = (const float*)d_in[o + 0];
    bnb[i] = (const float*)d_in[o + 1];
    Wq[i]  = (const float*)d_in[o + 2];
    bq[i]  = (const float*)d_in[o + 3];
    Wk[i]  = (const float*)d_in[o + 4];
    bk[i]  = (const float*)d_in[o + 5];
    Wv[i]  = (const float*)d_in[o + 6];
    bv[i]  = (const float*)d_in[o + 7];
    gam[i] = (const float*)d_in[o + 8];
  }
  const float* Wb = (const float*)d_in[30];
  const float* bb = (const float*)d_in[31];

  char* ws = (char*)d_ws;
  uint16_t* Hs    = (uint16_t*)(ws);                  // 117,440,512
  float*    part  = (float*)(ws + 117440512);         // 4,194,304 (1024 x 1024)
  float*    sv    = (float*)(ws + 121634816);         // 2,048
  float*    tv    = (float*)(ws + 121636864);         // 2,048
  uint16_t* WqkH  = (uint16_t*)(ws + 121638912);      // 131,072
  uint16_t* WqkL  = (uint16_t*)(ws + 121769984);      // 131,072
  float*    bqkf  = (float*)(ws + 121901056);         // 2,048
  uint16_t* WvH   = (uint16_t*)(ws + 121903104);      // 524,288
  float*    bvf   = (float*)(ws + 122427392);         // 2,048
  char*     WtIo  = ws + 122429440;                   // 1,048,576
  float*    btf   = (float*)(ws + 123478016);         // 2,048
  uint16_t* WbH   = (uint16_t*)(ws + 123480064);      // 262,144
  uint16_t* qkh   = (uint16_t*)d_out;                 // 29.4 MB scratch on d_out

  // weight prep
  cvt4h<<<128, 256, 0, stream>>>(Wb, WbH, 32768);
  fold_w_io<<<512, 512, 0, stream>>>(Wt, bt, WtIo, btf);

  // h0 = x @ Wt.T + bt  (bf16 3-pass exact-grade; fp16 plane out + stats)
  gemm1<<<dim3(2, 512), 512, 0, stream>>>((const char*)x, WtIo, btf, Hs, part);

  for (int i = 0; i < 3; ++i) {
    reduce_stats<<<512, 64, 0, stream>>>(part, i == 0 ? 512 : 1024,
                                         bng[i], bnb[i], sv, tv);
    fold_all<<<640, 512, 0, stream>>>(Wq[i], bq[i], Wk[i], bk[i], Wv[i], bv[i],
                                      sv, tv, gam[i], WqkH, WqkL, bqkf, WvH, bvf);
    // q|k = h @ Wqk'.T + b'  (W-pair 2-acc; fp16 out on d_out scratch)
    qkgemm<<<dim3(1, 512), 512, 0, stream>>>(Hs, WqkH, WqkL, bqkf, qkh);
    // v-GEMM -> LDS + attention + residual + relu (+ stats); Hs in place
    if (i < 2)
      vattn<true><<<dim3(1, 1024), 512, 0, stream>>>(Hs, WvH, bvf, qkh, Hs,
                                                     sv, tv, part);
    else
      vattn<false><<<dim3(1, 1024), 512, 0, stream>>>(Hs, WvH, bvf, qkh, Hs,
                                                      sv, tv, nullptr);
  }

  // out = h3 @ Wb.T + bb  (1-pass fp16; f32 out, overwrites qkh scratch)
  sgemm64<<<dim3(1, 512), 512, 0, stream>>>(Hs, WbH, bb, (float*)d_out, 256);
}

// Round 18
// 910.664 us; speedup vs baseline: 3.1828x; 1.0056x over previous
//
#include <hip/hip_runtime.h>
#include <hip/hip_bf16.h>
#include <stdint.h>

// LevelReasoning on MI355X — round 18: restore f32 q|k round-trip (margin de-risk).
// r17 structure (V-in-LDS vattn, fused stats, exact bf16 3-pass gemm1) with qkh
// stored f32 on d_out (58.7MB). absmax margin restored to ~0.0625 vs threshold
// 0.136 (r17's fp16 qk ran at 0.119 — too close). Stats epilogue: 2 syncs.

using bf16 = __hip_bfloat16;
typedef __attribute__((ext_vector_type(8))) short short8;
typedef __attribute__((ext_vector_type(4))) float f32x4;
typedef _Float16 f16x8 __attribute__((ext_vector_type(8)));

__device__ inline uint16_t f2b_bits(float f) {
  bf16 h = __float2bfloat16(f);
  return __builtin_bit_cast(uint16_t, h);
}
__device__ inline float b2f_bits(uint16_t u) { return __uint_as_float(((uint32_t)u) << 16); }
__device__ inline void split2(float v, uint16_t& hi, uint16_t& lo) {
  hi = f2b_bits(v);
  lo = f2b_bits(v - b2f_bits(hi));
}
__device__ inline uint16_t f2h_bits(float f) {
  _Float16 h = (_Float16)f;
  return __builtin_bit_cast(uint16_t, h);
}
__device__ inline float h2f_bits(uint16_t u) {
  return (float)__builtin_bit_cast(_Float16, u);
}
__device__ inline float g16(const uint4& u, int e) {
  uint32_t wrd = ((const uint32_t*)&u)[e >> 1];
  return h2f_bits((uint16_t)((e & 1) ? (wrd >> 16) : (wrd & 0xffffu)));
}

typedef const __attribute__((address_space(1))) void* gas_ptr;
typedef __attribute__((address_space(3))) void* las_ptr;
__device__ inline void gload16(const void* g, void* l) {
  __builtin_amdgcn_global_load_lds((gas_ptr)g, (las_ptr)l, 16, 0, 0);
}

// ---------------- f32 -> fp16 plain (Wb) ----------------
__global__ __launch_bounds__(256) void cvt4h(const float* __restrict__ in,
                                             uint16_t* __restrict__ out, int n4) {
  int i = blockIdx.x * 256 + threadIdx.x;
  const int stride = gridDim.x * 256;
  for (; i < n4; i += stride) {
    float4 v = ((const float4*)in)[i];
    uint32_t lo = (uint32_t)f2h_bits(v.x) | ((uint32_t)f2h_bits(v.y) << 16);
    uint32_t hi = (uint32_t)f2h_bits(v.z) | ((uint32_t)f2h_bits(v.w) << 16);
    ((uint2*)out)[i] = make_uint2(lo, hi);
  }
}

// ------- fold Wt to bf16-pair io (2KB rows) for gemm1 -------
__global__ __launch_bounds__(512) void fold_w_io(const float* __restrict__ Wsrc,
                                                 const float* __restrict__ bsrc,
                                                 char* __restrict__ Wio,
                                                 float* __restrict__ bout) {
  const int row = blockIdx.x, c = threadIdx.x;
  const float wv = Wsrc[(size_t)row * 512 + c];
  uint16_t hb, lb;
  split2(wv, hb, lb);
  char* p = Wio + (size_t)row * 2048 + (c >> 3) * 32 + (c & 7) * 2;
  *(uint16_t*)p = hb;
  *(uint16_t*)(p + 16) = lb;
  if (c == 0) bout[row] = bsrc[row];
}

// ------- fused per-layer weight fold: Wq, Wk (pair, lo x1024), Wv (single, gamma) -------
__global__ __launch_bounds__(512) void fold_all(const float* __restrict__ Wq,
                                                const float* __restrict__ bq,
                                                const float* __restrict__ Wk,
                                                const float* __restrict__ bk,
                                                const float* __restrict__ Wv,
                                                const float* __restrict__ bv,
                                                const float* __restrict__ sv,
                                                const float* __restrict__ tv,
                                                const float* __restrict__ gamp,
                                                uint16_t* __restrict__ WqkH,
                                                uint16_t* __restrict__ WqkL,
                                                float* __restrict__ bqkf,
                                                uint16_t* __restrict__ WvH,
                                                float* __restrict__ bvf) {
  const int b = blockIdx.x, c = threadIdx.x;
  __shared__ float red[512];
  const float* Wsrc;
  const float* bsrc;
  uint16_t *Wh, *Wl;
  float* bout;
  float g;
  int row;
  if (b < 64) {
    Wsrc = Wq; bsrc = bq; Wh = WqkH; Wl = WqkL; bout = bqkf; g = 1.0f; row = b;
  } else if (b < 128) {
    Wsrc = Wk; bsrc = bk; Wh = WqkH + (size_t)64 * 512; Wl = WqkL + (size_t)64 * 512;
    bout = bqkf + 64; g = 1.0f; row = b - 64;
  } else {
    Wsrc = Wv; bsrc = bv; Wh = WvH; Wl = nullptr; bout = bvf; g = gamp[0]; row = b - 128;
  }
  const float wv = Wsrc[(size_t)row * 512 + c];
  const float fv = g * wv * sv[c];
  const uint16_t hb = f2h_bits(fv);
  Wh[(size_t)row * 512 + c] = hb;
  if (Wl) Wl[(size_t)row * 512 + c] = f2h_bits((fv - h2f_bits(hb)) * 1024.0f);
  red[c] = wv * tv[c];
  __syncthreads();
#pragma unroll
  for (int off = 256; off > 0; off >>= 1) {
    if (c < off) red[c] += red[c + off];
    __syncthreads();
  }
  if (c == 0) bout[row] = g * (bsrc[row] + red[0]);
}

// ---------------- gemm1: h0 = x @ Wt.T + bt (bf16 3-pass exact, fp16-plane out + stats) -----
__global__ __launch_bounds__(512, 1) void gemm1(const char* __restrict__ A,
                                                const char* __restrict__ Wio,
                                                const float* __restrict__ bias,
                                                uint16_t* __restrict__ outh,
                                                float* __restrict__ part) {
  constexpr int A_BYTES = 224 * 128;
  constexpr int PER_BUF = A_BYTES + 256 * 128;
  __shared__ __align__(16) char lds[2 * PER_BUF];
  __shared__ float sred[2][2][256];
  const int tid = threadIdx.x, w = tid >> 6, l = tid & 63;

  const int nwgx = gridDim.x;
  const int raw = blockIdx.y * nwgx + blockIdx.x;
  const int cpx = (nwgx * gridDim.y) >> 3;
  const int work = (raw & 7) * cpx + (raw >> 3);
  const int bmidx = work / nwgx;
  const int bm = bmidx * 224;
  const int bn = (work % nwgx) * 256;

  const int ssl = ((((l >> 1) & 3) ^ ((l >> 3) & 3)) << 5) | (((l & 1) ^ ((l >> 5) & 1)) << 4);
  const char* Asrc = A + (size_t)(bm + (l >> 3)) * 2048 + ssl;
  const char* Bsrc = Wio + (size_t)(bn + (l >> 3)) * 2048 + ssl;

  const int lrow = l & 15, lk = l >> 4;
  const int wr = w >> 2, wc = w & 3;
  const int sw32 = (lk ^ (lrow & 3)) * 32;
  const int hi16 = ((lrow >> 2) & 1) * 16;
  const int afr = (wr * 112 + lrow) * 128 + sw32;
  const int bfr = A_BYTES + (wc * 64 + lrow) * 128 + sw32;

  f32x4 acc[7][4] = {};

  auto stage_a = [&](int buf, int t) {
    char* dst = lds + buf * PER_BUF;
    const char* src = Asrc + (size_t)t * 128;
#pragma unroll
    for (int k = 0; k < 4; ++k) {
      const int i = w + k * 8;
      if (k < 3 || w < 4) gload16(src + (size_t)i * 16384, dst + i * 1024);
    }
  };
  auto stage_b = [&](int buf, int t) {
    char* dst = lds + buf * PER_BUF + A_BYTES;
    const char* src = Bsrc + (size_t)t * 128;
#pragma unroll
    for (int k = 0; k < 4; ++k) {
      const int i = w + k * 8;
      gload16(src + (size_t)i * 16384, dst + i * 1024);
    }
  };

#define LOADA(BASE, CNT)                                                         \
  {                                                                              \
    _Pragma("unroll") for (int u = 0; u < (CNT); ++u) {                          \
      const int mi = (BASE) + u;                                                 \
      float4 f0 = *(const float4*)(bp + afr + mi * 2048 + hi16);                 \
      float4 f1 = *(const float4*)(bp + afr + mi * 2048 + (hi16 ^ 16));          \
      const float fv[8] = {f0.x, f0.y, f0.z, f0.w, f1.x, f1.y, f1.z, f1.w};      \
      _Pragma("unroll") for (int e = 0; e < 8; ++e) {                            \
        uint16_t hb, lb;                                                         \
        split2(fv[e], hb, lb);                                                   \
        ah[u][e] = (short)hb;                                                    \
        al[u][e] = (short)lb;                                                    \
      }                                                                          \
    }                                                                            \
  }

#define MFMAC(BASE, CNT)                                                         \
  {                                                                              \
    __builtin_amdgcn_s_setprio(1);                                               \
    _Pragma("unroll") for (int u = 0; u < (CNT); ++u)                            \
      _Pragma("unroll") for (int ni = 0; ni < 4; ++ni)                           \
        acc[(BASE) + u][ni] = __builtin_amdgcn_mfma_f32_16x16x32_bf16(           \
            ah[u], bh[ni], acc[(BASE) + u][ni], 0, 0, 0);                        \
    _Pragma("unroll") for (int u = 0; u < (CNT); ++u)                            \
      _Pragma("unroll") for (int ni = 0; ni < 4; ++ni)                           \
        acc[(BASE) + u][ni] = __builtin_amdgcn_mfma_f32_16x16x32_bf16(           \
            ah[u], bl[ni], acc[(BASE) + u][ni], 0, 0, 0);                        \
    _Pragma("unroll") for (int u = 0; u < (CNT); ++u)                            \
      _Pragma("unroll") for (int ni = 0; ni < 4; ++ni)                           \
        acc[(BASE) + u][ni] = __builtin_amdgcn_mfma_f32_16x16x32_bf16(           \
            al[u], bh[ni], acc[(BASE) + u][ni], 0, 0, 0);                        \
    __builtin_amdgcn_s_setprio(0);                                               \
  }

  stage_a(0, 0);
  stage_b(0, 0);
  int cur = 0;
#pragma unroll 2
  for (int t = 0; t < 16; ++t) {
    asm volatile("s_waitcnt vmcnt(0)" ::: "memory");
    __builtin_amdgcn_s_barrier();
    asm volatile("" ::: "memory");

    const char* bp = lds + cur * PER_BUF;
    if (t < 15) stage_a(cur ^ 1, t + 1);

    short8 bh[4], bl[4];
#pragma unroll
    for (int ni = 0; ni < 4; ++ni) {
      bh[ni] = *(const short8*)(bp + bfr + ni * 2048 + hi16);
      bl[ni] = *(const short8*)(bp + bfr + ni * 2048 + (hi16 ^ 16));
    }
    short8 ah[4], al[4];
    LOADA(0, 4)
    MFMAC(0, 4)
    if (t < 15) stage_b(cur ^ 1, t + 1);
    LOADA(4, 3)
    MFMAC(4, 3)
    cur ^= 1;
  }
#undef LOADA
#undef MFMAC

  float sni[4] = {}, qni[4] = {};
#pragma unroll
  for (int mi = 0; mi < 7; ++mi) {
    const int row = bm + wr * 112 + mi * 16 + lk * 4;
#pragma unroll
    for (int ni = 0; ni < 4; ++ni) {
      const int col = bn + wc * 64 + ni * 16 + lrow;
      const float bc = bias[col];
#pragma unroll
      for (int j = 0; j < 4; ++j) {
        const float vv = acc[mi][ni][j] + bc;
        outh[(size_t)(row + j) * 512 + col] = f2h_bits(vv);
        sni[ni] += vv;
        qni[ni] += vv * vv;
      }
    }
  }
#pragma unroll
  for (int ni = 0; ni < 4; ++ni) {
    float s = sni[ni], q = qni[ni];
    s += __shfl_xor(s, 16); q += __shfl_xor(q, 16);
    s += __shfl_xor(s, 32); q += __shfl_xor(q, 32);
    if (lk == 0) {
      sred[0][wr][wc * 64 + ni * 16 + lrow] = s;
      sred[1][wr][wc * 64 + ni * 16 + lrow] = q;
    }
  }
  __syncthreads();
  if (tid < 256) {
    part[(size_t)bmidx * 1024 + bn + tid] = sred[0][0][tid] + sred[0][1][tid];
    part[(size_t)bmidx * 1024 + 512 + bn + tid] = sred[1][0][tid] + sred[1][1][tid];
  }
}

// ---------------- qkgemm: q|k = h @ Wqk'.T + b' (W-pair, acc2); f32 out pitch 128 ----------
__global__ __launch_bounds__(512, 1) void qkgemm(const uint16_t* __restrict__ A,
                                                 const uint16_t* __restrict__ Wh,
                                                 const uint16_t* __restrict__ Wl,
                                                 const float* __restrict__ bias,
                                                 float* __restrict__ qkf) {
  constexpr int A_BYTES = 224 * 128;
  constexpr int BPL = 128 * 128;
  constexpr int PER_BUF = A_BYTES + 2 * BPL;
  __shared__ __align__(16) char lds[2 * PER_BUF];
  const int tid = threadIdx.x, w = tid >> 6, l = tid & 63;

  const int raw = blockIdx.y;
  const int cpx = gridDim.y >> 3;
  const int bmidx = (raw & 7) * cpx + (raw >> 3);
  const int bm = bmidx * 224;

  const int sp = (((l & 7) ^ ((l >> 3) & 7)) << 4);
  const char* Asrc = (const char*)A + (size_t)(bm + (l >> 3)) * 1024 + sp;
  const char* Bhs = (const char*)Wh + (size_t)(l >> 3) * 1024 + sp;
  const char* Bls = (const char*)Wl + (size_t)(l >> 3) * 1024 + sp;

  const int lrow = l & 15, lk = l >> 4;
  const int wr = w >> 2, wc = w & 3;

  f32x4 acc[7][2] = {};
  f32x4 acc2[7][2] = {};

  auto stage_a = [&](int buf, int t) {
    char* dst = lds + buf * PER_BUF;
    const char* src = Asrc + t * 128;
#pragma unroll
    for (int k = 0; k < 4; ++k) {
      const int i = w + k * 8;
      if (k < 3 || w < 4) gload16(src + (size_t)i * 8192, dst + i * 1024);
    }
  };
  auto stage_b = [&](int buf, int t) {
    char* dst = lds + buf * PER_BUF + A_BYTES;
#pragma unroll
    for (int k = 0; k < 2; ++k) {
      const int i = w + k * 8;
      gload16(Bhs + t * 128 + (size_t)i * 8192, dst + i * 1024);
      gload16(Bls + t * 128 + (size_t)i * 8192, dst + BPL + i * 1024);
    }
  };

#define AFR(mi, kc) \
  ((wr * 112 + (mi)*16 + lrow) * 128 + ((((kc)*4 + lk) ^ (lrow & 7)) << 4))
#define BFR(ni, kc) \
  (A_BYTES + (wc * 32 + (ni)*16 + lrow) * 128 + ((((kc)*4 + lk) ^ (lrow & 7)) << 4))

#define KHALF(kc)                                                                \
  {                                                                              \
    short8 bh[2], bl2[2];                                                        \
    _Pragma("unroll") for (int ni = 0; ni < 2; ++ni) {                           \
      bh[ni] = *(const short8*)(bp + BFR(ni, kc));                               \
      bl2[ni] = *(const short8*)(bp + BPL + BFR(ni, kc));                        \
    }                                                                            \
    short8 ah[7];                                                                \
    _Pragma("unroll") for (int mi = 0; mi < 7; ++mi)                             \
        ah[mi] = *(const short8*)(bp + AFR(mi, kc));                             \
    __builtin_amdgcn_s_setprio(1);                                               \
    _Pragma("unroll") for (int mi = 0; mi < 7; ++mi)                             \
      _Pragma("unroll") for (int ni = 0; ni < 2; ++ni)                           \
        acc[mi][ni] = __builtin_amdgcn_mfma_f32_16x16x32_f16(                    \
            __builtin_bit_cast(f16x8, ah[mi]), __builtin_bit_cast(f16x8, bh[ni]), \
            acc[mi][ni], 0, 0, 0);                                               \
    _Pragma("unroll") for (int mi = 0; mi < 7; ++mi)                             \
      _Pragma("unroll") for (int ni = 0; ni < 2; ++ni)                           \
        acc2[mi][ni] = __builtin_amdgcn_mfma_f32_16x16x32_f16(                   \
            __builtin_bit_cast(f16x8, ah[mi]), __builtin_bit_cast(f16x8, bl2[ni]), \
            acc2[mi][ni], 0, 0, 0);                                              \
    __builtin_amdgcn_s_setprio(0);                                               \
  }

  stage_a(0, 0);
  stage_b(0, 0);
  int cur = 0;
  for (int t = 0; t < 8; ++t) {
    asm volatile("s_waitcnt vmcnt(0)" ::: "memory");
    __builtin_amdgcn_s_barrier();
    asm volatile("" ::: "memory");
    const char* bp = lds + cur * PER_BUF;
    if (t < 7) stage_a(cur ^ 1, t + 1);
    KHALF(0)
    if (t < 7) stage_b(cur ^ 1, t + 1);
    KHALF(1)
    cur ^= 1;
  }
#undef KHALF
#undef AFR
#undef BFR

#pragma unroll
  for (int mi = 0; mi < 7; ++mi) {
    const int row = bm + wr * 112 + mi * 16 + lk * 4;
#pragma unroll
    for (int ni = 0; ni < 2; ++ni) {
      const int col = wc * 32 + ni * 16 + lrow;
      const float bc = bias[col];
#pragma unroll
      for (int j = 0; j < 4; ++j)
        qkf[(size_t)(row + j) * 128 + col] =
            acc[mi][ni][j] + bc + acc2[mi][ni][j] * (1.0f / 1024.0f);
    }
  }
}

// ---------------- vattn: v-GEMM (acc -> LDS) + attention + residual + relu + stats ----------
template <bool STATS>
__global__ __launch_bounds__(512, 1) void vattn(const uint16_t* __restrict__ A,
                                                const uint16_t* __restrict__ Wh,
                                                const float* __restrict__ bias,
                                                const float* __restrict__ qkf,
                                                uint16_t* __restrict__ Hs,
                                                const float* __restrict__ sv,
                                                const float* __restrict__ tv,
                                                float* __restrict__ part) {
  constexpr int A_BYTES = 112 * 128;   // 14336
  constexpr int B_BYTES = 512 * 128;   // 65536
  constexpr int PER_BUF = A_BYTES + B_BYTES;  // 79872
  __shared__ __align__(16) char lds[2 * PER_BUF];  // 159744; reused post-loop
  const int tid = threadIdx.x, w = tid >> 6, l = tid & 63;

  const int raw = blockIdx.y;          // grid (1, 1024)
  const int cpx = gridDim.y >> 3;
  const int bmidx = (raw & 7) * cpx + (raw >> 3);
  const int bm = bmidx * 112;

  const int sp = (((l & 7) ^ ((l >> 3) & 7)) << 4);
  const char* Asrc = (const char*)A + (size_t)(bm + (l >> 3)) * 1024 + sp;
  const char* Bhs = (const char*)Wh + (size_t)(l >> 3) * 1024 + sp;

  const int lrow = l & 15, lk = l >> 4;

  f32x4 acc[7][4] = {};

  auto stage_a = [&](int buf, int t) {
    char* dst = lds + buf * PER_BUF;
    const char* src = Asrc + t * 128;
#pragma unroll
    for (int k = 0; k < 2; ++k) {
      const int i = w + k * 8;
      if (k < 1 || w < 6) gload16(src + (size_t)i * 8192, dst + i * 1024);
    }
  };
  auto stage_b = [&](int buf, int t) {
    char* dst = lds + buf * PER_BUF + A_BYTES;
#pragma unroll
    for (int k = 0; k < 8; ++k) {
      const int i = w + k * 8;
      gload16(Bhs + t * 128 + (size_t)i * 8192, dst + i * 1024);
    }
  };

#define AFR(mi, kc) \
  (((mi)*16 + lrow) * 128 + ((((kc)*4 + lk) ^ (lrow & 7)) << 4))
#define BFR(ni, kc) \
  (A_BYTES + (w * 64 + (ni)*16 + lrow) * 128 + ((((kc)*4 + lk) ^ (lrow & 7)) << 4))

#define KHALF(kc)                                                                \
  {                                                                              \
    short8 bh[4];                                                                \
    _Pragma("unroll") for (int ni = 0; ni < 4; ++ni)                             \
        bh[ni] = *(const short8*)(bp + BFR(ni, kc));                             \
    short8 ah[7];                                                                \
    _Pragma("unroll") for (int mi = 0; mi < 7; ++mi)                             \
        ah[mi] = *(const short8*)(bp + AFR(mi, kc));                             \
    __builtin_amdgcn_s_setprio(1);                                               \
    _Pragma("unroll") for (int mi = 0; mi < 7; ++mi)                             \
      _Pragma("unroll") for (int ni = 0; ni < 4; ++ni)                           \
        acc[mi][ni] = __builtin_amdgcn_mfma_f32_16x16x32_f16(                    \
            __builtin_bit_cast(f16x8, ah[mi]), __builtin_bit_cast(f16x8, bh[ni]), \
            acc[mi][ni], 0, 0, 0);                                               \
    __builtin_amdgcn_s_setprio(0);                                               \
  }

  stage_a(0, 0);
  stage_b(0, 0);
  int cur = 0;
  for (int t = 0; t < 8; ++t) {
    asm volatile("s_waitcnt vmcnt(0)" ::: "memory");
    __builtin_amdgcn_s_barrier();
    asm volatile("" ::: "memory");
    const char* bp = lds + cur * PER_BUF;
    if (t < 7) stage_a(cur ^ 1, t + 1);
    KHALF(0)
    if (t < 7) stage_b(cur ^ 1, t + 1);
    KHALF(1)
    cur ^= 1;
  }
#undef KHALF
#undef AFR
#undef BFR

  // ---- phase 2: v = acc + bias -> LDS [g][j][c] fp16 (g*8192 + j*1024 + c*2 bytes) ----
  __syncthreads();  // all GEMM LDS reads complete before overwrite
  {
    uint16_t* vl = (uint16_t*)lds;
#pragma unroll
    for (int mi = 0; mi < 7; ++mi)
#pragma unroll
      for (int ni = 0; ni < 4; ++ni) {
        const int col = w * 64 + ni * 16 + lrow;
        const float bc = bias[col];
#pragma unroll
        for (int j = 0; j < 4; ++j) {
          const int row = mi * 16 + lk * 4 + j;  // 0..111
          const int g = row / 7, jj = row - g * 7;
          vl[g * 4096 + jj * 512 + col] = f2h_bits(acc[mi][ni][j] + bc);
        }
      }
  }
  __syncthreads();

  // ---- phase 3: attention; wave w handles groups 2w, 2w+1; lane owns cols l*8..l*8+7 ----
  const float4 s0 = *(const float4*)&sv[l * 8], s1 = *(const float4*)&sv[l * 8 + 4];
  const float4 t0 = *(const float4*)&tv[l * 8], t1 = *(const float4*)&tv[l * 8 + 4];
  const float sarr[8] = {s0.x, s0.y, s0.z, s0.w, s1.x, s1.y, s1.z, s1.w};
  const float tarr[8] = {t0.x, t0.y, t0.z, t0.w, t1.x, t1.y, t1.z, t1.w};

  float s8[8] = {}, q8[8] = {};
#pragma unroll
  for (int gg = 0; gg < 2; ++gg) {
    const int g = w * 2 + gg;
    const size_t grow = (size_t)bm + g * 7;

    float qv[7], kv[7];
#pragma unroll
    for (int i = 0; i < 7; ++i) {
      qv[i] = qkf[(grow + i) * 128 + l];
      kv[i] = qkf[(grow + i) * 128 + 64 + l];
    }
    float att[7][7];
#pragma unroll
    for (int i = 0; i < 7; ++i)
#pragma unroll
      for (int j = 0; j < 7; ++j) {
        float p = qv[i] * kv[j];
#pragma unroll
        for (int o = 32; o; o >>= 1) p += __shfl_xor(p, o);
        att[i][j] = p;
      }
#pragma unroll
    for (int i = 0; i < 7; ++i) {
      float m = att[i][0];
#pragma unroll
      for (int j = 1; j < 7; ++j) m = fmaxf(m, att[i][j]);
      float sum = 0.f;
#pragma unroll
      for (int j = 0; j < 7; ++j) {
        att[i][j] = expf(att[i][j] - m);
        sum += att[i][j];
      }
      const float inv = 1.0f / sum;
#pragma unroll
      for (int j = 0; j < 7; ++j) att[i][j] *= inv;
    }

    uint4 vpk[7];
#pragma unroll
    for (int j = 0; j < 7; ++j)
      vpk[j] = *(const uint4*)(lds + g * 8192 + j * 1024 + l * 16);

#pragma unroll
    for (int i = 0; i < 7; ++i) {
      char* hp = (char*)Hs + (grow + i) * 1024 + l * 16;
      uint4 hh = *(const uint4*)hp;
      float o[8] = {};
#pragma unroll
      for (int j = 0; j < 7; ++j) {
        const float a = att[i][j];
#pragma unroll
        for (int e = 0; e < 8; ++e) o[e] += a * g16(vpk[j], e);
      }
      uint16_t oh[8];
#pragma unroll
      for (int e = 0; e < 8; ++e) {
        const float xn = g16(hh, e) * sarr[e] + tarr[e];
        const float rr = fmaxf(o[e] + xn, 0.f);
        if constexpr (STATS) { s8[e] += rr; q8[e] += rr * rr; }
        oh[e] = f2h_bits(rr);
      }
      uint4 ph;
#pragma unroll
      for (int k2 = 0; k2 < 4; ++k2)
        ((uint32_t*)&ph)[k2] = (uint32_t)oh[2 * k2] | ((uint32_t)oh[2 * k2 + 1] << 16);
      *(uint4*)hp = ph;
    }
  }

  if constexpr (STATS) {
    __syncthreads();  // all v reads done before reuse
    float* sred = (float*)lds;  // [8][1024]: s plane at +0, q plane at +512
#pragma unroll
    for (int e = 0; e < 8; ++e) {
      sred[w * 1024 + l * 8 + e] = s8[e];
      sred[w * 1024 + 512 + l * 8 + e] = q8[e];
    }
    __syncthreads();
    {
      float sum = 0.f, sq = 0.f;
#pragma unroll
      for (int ww = 0; ww < 8; ++ww) {
        sum += sred[ww * 1024 + tid];
        sq += sred[ww * 1024 + 512 + tid];
      }
      part[(size_t)bmidx * 1024 + tid] = sum;
      part[(size_t)bmidx * 1024 + 512 + tid] = sq;
    }
  }
}

// ---------------- sgemm64: final GEMM (fp16 A, BN=256, f32 out) ----------------
__global__ __launch_bounds__(512, 1) void sgemm64(const uint16_t* __restrict__ A,
                                                  const uint16_t* __restrict__ Wh,
                                                  const float* __restrict__ bias,
                                                  float* __restrict__ outf, int N) {
  constexpr int BN = 256;
  constexpr int NFR = BN / 64;
  constexpr int A_BYTES = 224 * 128;
  constexpr int PER_BUF = A_BYTES + BN * 128;
  __shared__ __align__(16) char lds[2 * PER_BUF];
  const int tid = threadIdx.x, w = tid >> 6, l = tid & 63;

  const int raw = blockIdx.y;
  const int cpx = gridDim.y >> 3;
  const int bmidx = (raw & 7) * cpx + (raw >> 3);
  const int bm = bmidx * 224;
  const int bn = 0;

  const int sp = (((l & 7) ^ ((l >> 3) & 7)) << 4);
  const char* Asrc = (const char*)A + (size_t)(bm + (l >> 3)) * 1024 + sp;
  const char* Bhs = (const char*)Wh + (size_t)(bn + (l >> 3)) * 1024 + sp;

  const int lrow = l & 15, lk = l >> 4;
  const int wr = w >> 2, wc = w & 3;

  f32x4 acc[7][NFR] = {};

  auto stage_a = [&](int buf, int t) {
    char* dst = lds + buf * PER_BUF;
    const char* src = Asrc + t * 128;
#pragma unroll
    for (int k = 0; k < 4; ++k) {
      const int i = w + k * 8;
      if (k < 3 || w < 4) gload16(src + (size_t)i * 8192, dst + i * 1024);
    }
  };
  auto stage_b = [&](int buf, int t) {
    char* dst = lds + buf * PER_BUF + A_BYTES;
#pragma unroll
    for (int k = 0; k < BN / 64; ++k) {
      const int i = w + k * 8;
      gload16(Bhs + t * 128 + (size_t)i * 8192, dst + i * 1024);
    }
  };

#define AFR(mi, kc) \
  ((wr * 112 + (mi)*16 + lrow) * 128 + ((((kc)*4 + lk) ^ (lrow & 7)) << 4))
#define BFR(ni, kc) \
  (A_BYTES + (wc * (BN / 4) + (ni)*16 + lrow) * 128 + ((((kc)*4 + lk) ^ (lrow & 7)) << 4))

#define KHALF(kc)                                                                \
  {                                                                              \
    short8 bh[NFR];                                                              \
    _Pragma("unroll") for (int ni = 0; ni < NFR; ++ni)                           \
        bh[ni] = *(const short8*)(bp + BFR(ni, kc));                             \
    short8 ah[7];                                                                \
    _Pragma("unroll") for (int mi = 0; mi < 7; ++mi)                             \
        ah[mi] = *(const short8*)(bp + AFR(mi, kc));                             \
    __builtin_amdgcn_s_setprio(1);                                               \
    _Pragma("unroll") for (int mi = 0; mi < 7; ++mi)                             \
      _Pragma("unroll") for (int ni = 0; ni < NFR; ++ni)                         \
        acc[mi][ni] = __builtin_amdgcn_mfma_f32_16x16x32_f16(                    \
            __builtin_bit_cast(f16x8, ah[mi]), __builtin_bit_cast(f16x8, bh[ni]), \
            acc[mi][ni], 0, 0, 0);                                               \
    __builtin_amdgcn_s_setprio(0);                                               \
  }

  stage_a(0, 0);
  stage_b(0, 0);
  int cur = 0;
  for (int t = 0; t < 8; ++t) {
    asm volatile("s_waitcnt vmcnt(0)" ::: "memory");
    __builtin_amdgcn_s_barrier();
    asm volatile("" ::: "memory");
    const char* bp = lds + cur * PER_BUF;
    if (t < 7) stage_a(cur ^ 1, t + 1);
    KHALF(0)
    if (t < 7) stage_b(cur ^ 1, t + 1);
    KHALF(1)
    cur ^= 1;
  }
#undef KHALF
#undef AFR
#undef BFR

#pragma unroll
  for (int mi = 0; mi < 7; ++mi) {
    const int row = bm + wr * 112 + mi * 16 + lk * 4;
#pragma unroll
    for (int ni = 0; ni < NFR; ++ni) {
      const int col = bn + wc * (BN / 4) + ni * 16 + lrow;
      const float bc = bias[col];
#pragma unroll
      for (int j = 0; j < 4; ++j)
        outf[(size_t)(row + j) * N + col] = acc[mi][ni][j] + bc;
    }
  }
}

// ---------------- stats reduce ----------------
__global__ __launch_bounds__(64) void reduce_stats(const float* __restrict__ part, int n,
                                                   const float* __restrict__ g,
                                                   const float* __restrict__ bb,
                                                   float* __restrict__ sv,
                                                   float* __restrict__ tv) {
  const int c = blockIdx.x, k = threadIdx.x;
  float sum = 0.f, sq = 0.f;
  for (int i = k; i < n; i += 64) {
    const float* p = part + (size_t)i * 1024;
    sum += p[c];
    sq += p[512 + c];
  }
#pragma unroll
  for (int o = 32; o; o >>= 1) {
    sum += __shfl_xor(sum, o);
    sq += __shfl_xor(sq, o);
  }
  if (k == 0) {
    const float mean = sum * (1.0f / 114688.0f);
    const float var = sq * (1.0f / 114688.0f) - mean * mean;
    const float sc = g[c] * rsqrtf(var + 1e-5f);
    sv[c] = sc;
    tv[c] = bb[c] - mean * sc;
  }
}

extern "C" void kernel_launch(void* const* d_in, const int* in_sizes, int n_in,
                              void* d_out, int out_size, void* d_ws, size_t ws_size,
                              hipStream_t stream) {
  const float* x  = (const float*)d_in[0];
  const float* Wt = (const float*)d_in[1];
  const float* bt = (const float*)d_in[2];
  const float *bng[3], *bnb[3], *Wq[3], *bq[3], *Wk[3], *bk[3], *Wv[3], *bv[3], *gam[3];
  for (int i = 0; i < 3; ++i) {
    int o = 3 + 9 * i;
    bng[i] = (const float*)d_in[o + 0];
    bnb[i] = (const float*)d_in[o + 1];
    Wq[i]  = (const float*)d_in[o + 2];
    bq[i]  = (const float*)d_in[o + 3];
    Wk[i]  = (const float*)d_in[o + 4];
    bk[i]  = (const float*)d_in[o + 5];
    Wv[i]  = (const float*)d_in[o + 6];
    bv[i]  = (const float*)d_in[o + 7];
    gam[i] = (const float*)d_in[o + 8];
  }
  const float* Wb = (const float*)d_in[30];
  const float* bb = (const float*)d_in[31];

  char* ws = (char*)d_ws;
  uint16_t* Hs    = (uint16_t*)(ws);                  // 117,440,512
  float*    part  = (float*)(ws + 117440512);         // 4,194,304 (1024 x 1024)
  float*    sv    = (float*)(ws + 121634816);         // 2,048
  float*    tv    = (float*)(ws + 121636864);         // 2,048
  uint16_t* WqkH  = (uint16_t*)(ws + 121638912);      // 131,072
  uint16_t* WqkL  = (uint16_t*)(ws + 121769984);      // 131,072
  float*    bqkf  = (float*)(ws + 121901056);         // 2,048
  uint16_t* WvH   = (uint16_t*)(ws + 121903104);      // 524,288
  float*    bvf   = (float*)(ws + 122427392);         // 2,048
  char*     WtIo  = ws + 122429440;                   // 1,048,576
  float*    btf   = (float*)(ws + 123478016);         // 2,048
  uint16_t* WbH   = (uint16_t*)(ws + 123480064);      // 262,144
  float*    qkf   = (float*)d_out;                    // 58.7 MB scratch on d_out

  // weight prep
  cvt4h<<<128, 256, 0, stream>>>(Wb, WbH, 32768);
  fold_w_io<<<512, 512, 0, stream>>>(Wt, bt, WtIo, btf);

  // h0 = x @ Wt.T + bt  (bf16 3-pass exact-grade; fp16 plane out + stats)
  gemm1<<<dim3(2, 512), 512, 0, stream>>>((const char*)x, WtIo, btf, Hs, part);

  for (int i = 0; i < 3; ++i) {
    reduce_stats<<<512, 64, 0, stream>>>(part, i == 0 ? 512 : 1024,
                                         bng[i], bnb[i], sv, tv);
    fold_all<<<640, 512, 0, stream>>>(Wq[i], bq[i], Wk[i], bk[i], Wv[i], bv[i],
                                      sv, tv, gam[i], WqkH, WqkL, bqkf, WvH, bvf);
    // q|k = h @ Wqk'.T + b'  (W-pair 2-acc; f32 out on d_out scratch)
    qkgemm<<<dim3(1, 512), 512, 0, stream>>>(Hs, WqkH, WqkL, bqkf, qkf);
    // v-GEMM -> LDS + attention + residual + relu (+ stats); Hs in place
    if (i < 2)
      vattn<true><<<dim3(1, 1024), 512, 0, stream>>>(Hs, WvH, bvf, qkf, Hs,
                                                     sv, tv, part);
    else
      vattn<false><<<dim3(1, 1024), 512, 0, stream>>>(Hs, WvH, bvf, qkf, Hs,
                                                      sv, tv, nullptr);
  }

  // out = h3 @ Wb.T + bb  (1-pass fp16; f32 out, overwrites qkf scratch)
  sgemm64<<<dim3(1, 512), 512, 0, stream>>>(Hs, WbH, bb, (float*)d_out, 256);
}